// Round 12
// baseline (681.524 us; speedup 1.0000x reference)
//
#include <hip/hip_runtime.h>
#include <hip/hip_bf16.h>
#include <math.h>

#define H 128
#define EPS_BN 1e-5f
#define RSTATS 16

typedef __attribute__((ext_vector_type(8))) short short8;
typedef __attribute__((ext_vector_type(4))) float f32x4;

__device__ __forceinline__ float bf2f(ushort u){
  union { float f; uint v; } x; x.v = ((uint)u) << 16; return x.f;
}
__device__ __forceinline__ ushort f2bf(float f){
  union { float f; uint v; } x; x.f = f;
  uint v = x.v;
  uint r = v + 0x7fff + ((v >> 16) & 1);   // RNE
  return (ushort)(r >> 16);
}

__device__ __forceinline__ void acc8(float* a, uint4 v, float wt){
  a[0] += wt*bf2f((ushort)(v.x & 0xffff)); a[1] += wt*bf2f((ushort)(v.x >> 16));
  a[2] += wt*bf2f((ushort)(v.y & 0xffff)); a[3] += wt*bf2f((ushort)(v.y >> 16));
  a[4] += wt*bf2f((ushort)(v.z & 0xffff)); a[5] += wt*bf2f((ushort)(v.z >> 16));
  a[6] += wt*bf2f((ushort)(v.w & 0xffff)); a[7] += wt*bf2f((ushort)(v.w >> 16));
}

// ---------------- CSR build ----------------

__global__ void k_count(const int* __restrict__ col, int E, int* __restrict__ cnt){
  int i = blockIdx.x*blockDim.x + threadIdx.x;
  if (i < E) atomicAdd(&cnt[col[i]], 1);
}

__global__ void k_scan1(const int* __restrict__ cnt, int* __restrict__ off,
                        int* __restrict__ bsum, float* __restrict__ dinv, int n){
  __shared__ int s[1024];
  int t = threadIdx.x;
  int i = blockIdx.x*1024 + t;
  int v = (i < n) ? cnt[i] : 0;
  if (i < n) dinv[i] = rsqrtf((float)v + 1.0f);   // +1 self-loop
  s[t] = v; __syncthreads();
  for (int d = 1; d < 1024; d <<= 1){
    int x = (t >= d) ? s[t-d] : 0;
    __syncthreads();
    s[t] += x;
    __syncthreads();
  }
  if (i < n) off[i] = s[t] - v;
  if (t == 1023) bsum[blockIdx.x] = s[1023];
}

__global__ void k_scan2(int* bsum, int nb){
  int l = threadIdx.x;           // 64 threads, 1 block
  int carry = 0;
  for (int b0 = 0; b0 < nb; b0 += 64){
    int i = b0 + l;
    int orig = (i < nb) ? bsum[i] : 0;
    int v = orig;
    #pragma unroll
    for (int d = 1; d < 64; d <<= 1){
      int x = __shfl_up(v, d);
      if (l >= d) v += x;
    }
    if (i < nb) bsum[i] = carry + v - orig;   // exclusive
    carry += __shfl(v, 63);
  }
}

__global__ void k_scan3(int* __restrict__ off, int* __restrict__ cursor,
                        const int* __restrict__ bsum, int n, int Etot){
  int i = blockIdx.x*blockDim.x + threadIdx.x;
  if (i < n){ int o = off[i] + bsum[i >> 10]; off[i] = o; cursor[i] = o; }
  if (i == 0) off[n] = Etot;
}

// -------- bucketed fill: 64 target-range buckets, then local scatter --------

__global__ __launch_bounds__(1024) void k_bcount(
    const int* __restrict__ col, int E, int* __restrict__ bh){
  __shared__ int lh[64];
  int t = threadIdx.x;
  if (t < 64) lh[t] = 0;
  __syncthreads();
  int i = blockIdx.x*1024 + t;
  if (i < E){
    int b = col[i] >> 11; if (b > 63) b = 63;
    atomicAdd(&lh[b], 1);
  }
  __syncthreads();
  if (t < 64 && lh[t]) atomicAdd(&bh[t], lh[t]);
}

__global__ void k_bscan(int* __restrict__ bh){   // 1 block, 64 threads
  int l = threadIdx.x;
  int v = bh[l];
  int s = v;
  #pragma unroll
  for (int d = 1; d < 64; d <<= 1){
    int x = __shfl_up(s, d);
    if (l >= d) s += x;
  }
  bh[l] = s - v;   // exclusive; reused as cursor
}

__global__ __launch_bounds__(1024) void k_bucket(
    const int* __restrict__ row, const int* __restrict__ col, int E,
    int* __restrict__ bcur, uint2* __restrict__ tmp){
  __shared__ int lh[64];
  __shared__ int lbase[64];
  int t = threadIdx.x;
  if (t < 64) lh[t] = 0;
  __syncthreads();
  int i = blockIdx.x*1024 + t;
  int b = 0, li = 0, r = 0, c = 0;
  if (i < E){
    r = row[i]; c = col[i];
    b = c >> 11; if (b > 63) b = 63;
    li = atomicAdd(&lh[b], 1);
  }
  __syncthreads();
  if (t < 64){
    int cc = lh[t];
    lbase[t] = cc ? atomicAdd(&bcur[t], cc) : 0;
  }
  __syncthreads();
  if (i < E) tmp[lbase[b] + li] = make_uint2((uint)r, (uint)c);
}

// bucket-ordered stream -> final CSR; XCD-chunk swizzle keeps each bucket
// window (~260KB of edge[]) on one XCD's L2.
__global__ __launch_bounds__(256) void k_fill2(
    const uint2* __restrict__ tmp, int E, const float* __restrict__ dinv,
    int* __restrict__ cursor, uint2* __restrict__ edge, int nwg){
  int bid = blockIdx.x;
  int qq = nwg >> 3, rr = nwg & 7;
  int xcd = bid & 7, idx = bid >> 3;
  int wg = (xcd < rr ? xcd*(qq+1) : rr*(qq+1) + (xcd-rr)*qq) + idx;
  int i = wg*256 + threadIdx.x;
  if (i < E){
    uint2 rc = tmp[i];
    int r = (int)rc.x, c = (int)rc.y;
    int p = atomicAdd(&cursor[c], 1);
    edge[p] = make_uint2(rc.x, __float_as_uint(dinv[r]*dinv[c]));
  }
}

// -------- degree-sort permutation: LDS-aggregated counting sort (256 bins) ----

__global__ __launch_bounds__(1024) void k_dhist(
    const int* __restrict__ cnt, int* __restrict__ dh, int n){
  __shared__ int lh[256];
  int t = threadIdx.x;
  if (t < 256) lh[t] = 0;
  __syncthreads();
  int i = blockIdx.x*1024 + t;
  if (i < n){
    int d = cnt[i]; if (d > 255) d = 255;
    atomicAdd(&lh[d], 1);
  }
  __syncthreads();
  if (t < 256 && lh[t]) atomicAdd(&dh[t], lh[t]);
}

__global__ void k_dscan(int* __restrict__ dh){   // 1 block, 256 threads
  __shared__ int s[256];
  int t = threadIdx.x;
  int v = dh[t];
  s[t] = v; __syncthreads();
  for (int d = 1; d < 256; d <<= 1){
    int x = (t >= d) ? s[t-d] : 0;
    __syncthreads();
    s[t] += x;
    __syncthreads();
  }
  dh[t] = s[t] - v;   // exclusive; reused as cursor
}

__global__ __launch_bounds__(1024) void k_dperm(
    const int* __restrict__ cnt, int* __restrict__ dh,
    int* __restrict__ perm, int n){
  __shared__ int lh[256];
  __shared__ int lbase[256];
  int t = threadIdx.x;
  if (t < 256) lh[t] = 0;
  __syncthreads();
  int i = blockIdx.x*1024 + t;
  int d = 0, li = 0;
  if (i < n){
    d = cnt[i]; if (d > 255) d = 255;
    li = atomicAdd(&lh[d], 1);
  }
  __syncthreads();
  if (t < 256){
    int c = lh[t];
    lbase[t] = c ? atomicAdd(&dh[t], c) : 0;
  }
  __syncthreads();
  if (i < n) perm[lbase[d] + li] = i;
}

// ---------------- weight prep: bf16, transposed, beta-folded ----------------

__global__ void k_prepw(const float* __restrict__ lin0_w, const float* __restrict__ conv_w,
                        ushort* __restrict__ lin0T, ushort* __restrict__ WpT,
                        float b0, float b1, float b2, float b3){
  int i = blockIdx.x*blockDim.x + threadIdx.x;
  if (i < 128*256){
    int nn = i >> 8, k = i & 255;
    lin0T[i] = f2bf(lin0_w[k*128 + nn]);
  } else if (i < 128*256 + 4*128*128){
    int j = i - 128*256;
    int ll = j >> 14, rc = j & 16383;
    int nn = rc >> 7, k = rc & 127;
    float beta = (ll==0)?b0:(ll==1)?b1:(ll==2)?b2:b3;
    float v = beta * conv_w[ll*16384 + k*128 + nn];
    if (k == nn) v += 1.0f - beta;
    WpT[j] = f2bf(v);
  }
}

// ---------------- gather core: edges only; one quad (16 lanes) per node -----

__device__ __forceinline__ void gather_edges(
    float* a, const ushort* __restrict__ zin, const uint2* __restrict__ edge,
    int e0, int e1, int lr){
  int e = e0;
  for (; e + 3 < e1; e += 4){
    uint2 er0 = edge[e],   er1 = edge[e+1];
    uint2 er2 = edge[e+2], er3 = edge[e+3];
    uint4 v0 = *(const uint4*)(zin + (size_t)er0.x*H + lr*8);
    uint4 v1 = *(const uint4*)(zin + (size_t)er1.x*H + lr*8);
    uint4 v2 = *(const uint4*)(zin + (size_t)er2.x*H + lr*8);
    uint4 v3 = *(const uint4*)(zin + (size_t)er3.x*H + lr*8);
    acc8(a, v0, __uint_as_float(er0.y));
    acc8(a, v1, __uint_as_float(er1.y));
    acc8(a, v2, __uint_as_float(er2.y));
    acc8(a, v3, __uint_as_float(er3.y));
  }
  for (; e < e1; ++e){
    uint2 er = edge[e];
    uint4 v = *(const uint4*)(zin + (size_t)er.x*H + lr*8);
    acc8(a, v, __uint_as_float(er.y));
  }
}

// ---------------- input-layer prop: x0 = agg(xw)+b ; quad-per-node (perm) ---

__global__ __launch_bounds__(256) void k_prop0(
    const ushort* __restrict__ h, const int* __restrict__ off,
    const uint2* __restrict__ edge, const float* __restrict__ dinv,
    const float* __restrict__ bias, const int* __restrict__ perm,
    ushort* __restrict__ x0, int n){
  int pq = (blockIdx.x*blockDim.x + threadIdx.x) >> 4;
  if (pq >= n) return;
  int gq = perm[pq];                 // same for all 16 lanes of the quad
  int lr = threadIdx.x & 15;
  float a[8];
  #pragma unroll
  for (int j = 0; j < 8; ++j) a[j] = 0.f;
  float wc = dinv[gq]; wc *= wc;
  uint4 vs = *(const uint4*)(h + (size_t)gq*H + lr*8);
  gather_edges(a, h, edge, off[gq], off[gq+1], lr);
  acc8(a, vs, wc);
  float4 b0 = *(const float4*)(bias + lr*8);
  float4 b1 = *(const float4*)(bias + lr*8 + 4);
  uint4 pk;
  pk.x = (uint)f2bf(a[0]+b0.x) | ((uint)f2bf(a[1]+b0.y) << 16);
  pk.y = (uint)f2bf(a[2]+b0.z) | ((uint)f2bf(a[3]+b0.w) << 16);
  pk.z = (uint)f2bf(a[4]+b1.x) | ((uint)f2bf(a[5]+b1.y) << 16);
  pk.w = (uint)f2bf(a[6]+b1.z) | ((uint)f2bf(a[7]+b1.w) << 16);
  *(uint4*)(x0 + (size_t)gq*H + lr*8) = pk;
}

// ---------------- fused layer: prop -> LDS s-tile -> MFMA GEMM -> z (+stats) --
// block = 256 thr (4 waves) = 32 nodes taken from degree-sorted perm[] so all
// quads have ~equal work (no barrier slack). Outputs written to original rows.

template<bool STATS, bool OUTF32, bool SAMEX0>
__global__ __launch_bounds__(256) void k_layer(
    const ushort* __restrict__ zin, const ushort* __restrict__ x0,
    const int* __restrict__ off, const uint2* __restrict__ edge,
    const float* __restrict__ dinv, const ushort* __restrict__ BT,
    const int* __restrict__ perm,
    void* __restrict__ zout, float* __restrict__ stats, int n)
{
  __shared__ ushort Sm[32*128];   // swizzled s tile: row*128 + ((blk16^(row&15))*8)
  __shared__ int pm[32];
  int t = threadIdx.x;
  int w = t >> 6, l = t & 63;
  int lr = l & 15, q = l >> 4;
  int base = blockIdx.x * 32;
  if (t < 32) pm[t] = (base + t < n) ? perm[base + t] : -1;
  __syncthreads();

  // ---- prop phase: quad-per-node, 2 nodes per quad ----
  #pragma unroll
  for (int g2 = 0; g2 < 2; ++g2){
    int row  = w*8 + g2*4 + q;
    int node = pm[row];
    float a[8];
    #pragma unroll
    for (int j = 0; j < 8; ++j) a[j] = 0.f;
    uint4 pk = make_uint4(0u,0u,0u,0u);
    if (node >= 0){
      float wc = dinv[node]; wc *= wc;
      uint4 vs = *(const uint4*)(zin + (size_t)node*H + lr*8);
      gather_edges(a, zin, edge, off[node], off[node+1], lr);
      acc8(a, vs, wc);
      uint4 xv = SAMEX0 ? vs : *(const uint4*)(x0 + (size_t)node*H + lr*8);
      float s0 = 0.9f*a[0] + 0.1f*bf2f((ushort)(xv.x & 0xffff));
      float s1 = 0.9f*a[1] + 0.1f*bf2f((ushort)(xv.x >> 16));
      float s2 = 0.9f*a[2] + 0.1f*bf2f((ushort)(xv.y & 0xffff));
      float s3 = 0.9f*a[3] + 0.1f*bf2f((ushort)(xv.y >> 16));
      float s4 = 0.9f*a[4] + 0.1f*bf2f((ushort)(xv.z & 0xffff));
      float s5 = 0.9f*a[5] + 0.1f*bf2f((ushort)(xv.z >> 16));
      float s6 = 0.9f*a[6] + 0.1f*bf2f((ushort)(xv.w & 0xffff));
      float s7 = 0.9f*a[7] + 0.1f*bf2f((ushort)(xv.w >> 16));
      pk.x = (uint)f2bf(s0) | ((uint)f2bf(s1) << 16);
      pk.y = (uint)f2bf(s2) | ((uint)f2bf(s3) << 16);
      pk.z = (uint)f2bf(s4) | ((uint)f2bf(s5) << 16);
      pk.w = (uint)f2bf(s6) | ((uint)f2bf(s7) << 16);
    }
    *(uint4*)(&Sm[row*128 + ((lr ^ (row & 15))*8)]) = pk;
  }

  // ---- B fragments (W'^T slice for this wave's 32 cols) ----
  short8 bfr[2][4];
  #pragma unroll
  for (int c = 0; c < 2; ++c)
    #pragma unroll
    for (int ks = 0; ks < 4; ++ks)
      bfr[c][ks] = *(const short8*)(BT + (size_t)(w*32 + c*16 + lr)*H + ks*32 + q*8);

  __syncthreads();

  // ---- GEMM phase: 32 rows x 32 cols per wave ----
  f32x4 acc[2][2];
  #pragma unroll
  for (int rt = 0; rt < 2; ++rt){
    acc[rt][0] = (f32x4){0.f,0.f,0.f,0.f};
    acc[rt][1] = (f32x4){0.f,0.f,0.f,0.f};
  }
  #pragma unroll
  for (int rt = 0; rt < 2; ++rt){
    int row = rt*16 + lr;
    #pragma unroll
    for (int ks = 0; ks < 4; ++ks){
      short8 af = *(const short8*)(&Sm[row*128 + (((ks*4 + q) ^ (row & 15))*8)]);
      acc[rt][0] = __builtin_amdgcn_mfma_f32_16x16x32_bf16(af, bfr[0][ks], acc[rt][0], 0,0,0);
      acc[rt][1] = __builtin_amdgcn_mfma_f32_16x16x32_bf16(af, bfr[1][ks], acc[rt][1], 0,0,0);
    }
  }

  // ---- epilogue: write z to ORIGINAL rows via pm, accumulate BN stats ----
  #pragma unroll
  for (int rt = 0; rt < 2; ++rt){
    #pragma unroll
    for (int c = 0; c < 2; ++c){
      #pragma unroll
      for (int j2 = 0; j2 < 4; ++j2){
        int rowl = rt*16 + q*4 + j2;
        int nodeo = pm[rowl];
        float v = acc[rt][c][j2];
        if (OUTF32){
          if (nodeo >= 0)
            ((float*)zout)[(size_t)nodeo*H + w*32 + c*16 + lr] = v;
        } else {
          float other = __shfl(v, l ^ 1);
          if (!(lr & 1) && nodeo >= 0){
            uint pk = (uint)f2bf(v) | ((uint)f2bf(other) << 16);
            ((uint*)zout)[(size_t)nodeo*64 + w*16 + c*8 + (lr >> 1)] = pk;
          }
        }
      }
    }
  }
  if (STATS){
    #pragma unroll
    for (int c = 0; c < 2; ++c){
      float sv = 0.f, sq = 0.f;
      #pragma unroll
      for (int rt = 0; rt < 2; ++rt)
        #pragma unroll
        for (int j2 = 0; j2 < 4; ++j2){
          float v = acc[rt][c][j2];   // invalid rows have s=0 -> acc=0
          sv += v; sq += v*v;
        }
      sv += __shfl(sv, l ^ 16); sv += __shfl(sv, l ^ 32);
      sq += __shfl(sq, l ^ 16); sq += __shfl(sq, l ^ 32);
      if (q == 0){
        float* st = stats + (size_t)(blockIdx.x & (RSTATS-1))*256;
        atomicAdd(&st[w*32 + c*16 + lr], sv);
        atomicAdd(&st[128 + w*32 + c*16 + lr], sq);
      }
    }
  }
}

// ---------------- BN finalize: stats replicas -> scale/shift; re-zero -------

__global__ void k_bnfinal(float* __restrict__ stats, const float* __restrict__ gamma,
                          const float* __restrict__ beta, float* __restrict__ scsh,
                          float inv_n){
  int f = threadIdx.x;   // 128
  float s = 0.f, s2 = 0.f;
  for (int r = 0; r < RSTATS; ++r){
    s  += stats[r*256 + f];
    s2 += stats[r*256 + 128 + f];
    stats[r*256 + f] = 0.f;          // re-zero for next layer
    stats[r*256 + 128 + f] = 0.f;
  }
  float mu  = s * inv_n;
  float var = s2 * inv_n - mu*mu;
  float sc  = rsqrtf(var + EPS_BN) * gamma[f];
  scsh[f]       = sc;
  scsh[128 + f] = beta[f] - mu*sc;
}

// ---------------- BN apply (in place): y = relu(z*sc + sh), bf16 ----------

__global__ __launch_bounds__(256) void k_bnapply(
    uint4* __restrict__ z, const float* __restrict__ scsh, int n16){
  int i = blockIdx.x*blockDim.x + threadIdx.x;   // one uint4 = 8 elems
  if (i >= n16) return;
  int f8 = (i & 15) * 8;
  uint4 v = z[i];
  uint r[4];
  #pragma unroll
  for (int p = 0; p < 4; ++p){
    uint  u  = (&v.x)[p];
    float z0 = bf2f((ushort)(u & 0xffff));
    float z1 = bf2f((ushort)(u >> 16));
    float y0 = fmaxf(fmaf(z0, scsh[f8 + p*2],     scsh[128 + f8 + p*2]),     0.f);
    float y1 = fmaxf(fmaf(z1, scsh[f8 + p*2 + 1], scsh[128 + f8 + p*2 + 1]), 0.f);
    r[p] = (uint)f2bf(y0) | ((uint)f2bf(y1) << 16);
  }
  z[i] = make_uint4(r[0], r[1], r[2], r[3]);
}

// ---------------- MFMA GEMM for input layer: xw = x(f32) @ lin0T^T ----------

__global__ __launch_bounds__(256) void k_gemm0(
    const float* __restrict__ Af, const ushort* __restrict__ BT,
    ushort* __restrict__ Cb, int n){
  const int K = 256;
  __shared__ ushort As[64*32];
  __shared__ ushort Bs[128*32];
  int t = threadIdx.x;
  int br = blockIdx.x * 64;
  int w = t >> 6, l = t & 63;
  int lr = l & 15, lk = l >> 4;
  int swz = (lr >> 1) & 3;

  f32x4 acc[8];
  #pragma unroll
  for (int i = 0; i < 8; ++i) acc[i] = (f32x4){0.f,0.f,0.f,0.f};

  int sar = t >> 2;
  int sab = t & 3;
  int sa_off = sar*32 + ((sab ^ ((sar>>1)&3))*8);

  for (int k0 = 0; k0 < K; k0 += 32){
    int grow = br + sar;
    float4 v0 = make_float4(0.f,0.f,0.f,0.f), v1 = v0;
    if (grow < n){
      v0 = *(const float4*)(Af + (size_t)grow*K + k0 + sab*8);
      v1 = *(const float4*)(Af + (size_t)grow*K + k0 + sab*8 + 4);
    }
    ushort tmp[8] = {f2bf(v0.x),f2bf(v0.y),f2bf(v0.z),f2bf(v0.w),
                     f2bf(v1.x),f2bf(v1.y),f2bf(v1.z),f2bf(v1.w)};
    *(uint4*)(&As[sa_off]) = *(const uint4*)tmp;
    #pragma unroll
    for (int i = 0; i < 2; ++i){
      int qq = t + i*256;
      int nrow = qq >> 2, bb = qq & 3;
      uint4 v = *(const uint4*)(BT + (size_t)nrow*K + k0 + bb*8);
      *(uint4*)(&Bs[nrow*32 + ((bb ^ ((nrow>>1)&3))*8)]) = v;
    }
    __syncthreads();
    short8 af = *(const short8*)(&As[(w*16+lr)*32 + ((lk ^ swz)*8)]);
    #pragma unroll
    for (int tn = 0; tn < 8; ++tn){
      short8 bfv = *(const short8*)(&Bs[(tn*16+lr)*32 + ((lk ^ swz)*8)]);
      acc[tn] = __builtin_amdgcn_mfma_f32_16x16x32_bf16(af, bfv, acc[tn], 0, 0, 0);
    }
    __syncthreads();
  }
  int orow = br + w*16 + lk*4;
  #pragma unroll
  for (int tn = 0; tn < 8; ++tn){
    #pragma unroll
    for (int j = 0; j < 4; ++j){
      float mine  = acc[tn][j];
      float other = __shfl(mine, l ^ 1);
      if (!(l & 1) && (orow + j) < n){
        uint pk = (uint)f2bf(mine) | ((uint)f2bf(other) << 16);
        ((uint*)Cb)[(size_t)(orow+j)*64 + tn*8 + (lr >> 1)] = pk;
      }
    }
  }
}

// ---------------- launch ----------------

extern "C" void kernel_launch(void* const* d_in, const int* in_sizes, int n_in,
                              void* d_out, int out_size, void* d_ws, size_t ws_size,
                              hipStream_t stream){
  const float* x        = (const float*)d_in[0];
  const int*   ei       = (const int*)  d_in[1];
  const float* lin0_w   = (const float*)d_in[2];
  const float* lin0_b   = (const float*)d_in[3];
  const float* conv_w   = (const float*)d_in[4];
  const float* bn_gamma = (const float*)d_in[5];
  const float* bn_beta  = (const float*)d_in[6];
  float* out = (float*)d_out;

  int N = in_sizes[0] / 256;
  int E = in_sizes[1] / 2;
  const int* row = ei;
  const int* col = ei + E;

  char* ws = (char*)d_ws;
  size_t p = 0;
  auto alloc = [&](size_t bytes)->char*{
    char* r = ws + p; p = (p + bytes + 255) & ~(size_t)255; return r;
  };
  int*    cnt    = (int*)   alloc((size_t)N*4);
  int*    off    = (int*)   alloc((size_t)(N+1)*4);
  int*    cursor = (int*)   alloc((size_t)N*4);
  float*  dinv   = (float*) alloc((size_t)N*4);
  int*    bsum   = (int*)   alloc(512*4);
  int*    dh     = (int*)   alloc(256*4);
  int*    bh     = (int*)   alloc(64*4);
  int*    perm   = (int*)   alloc((size_t)N*4);
  uint2*  edge   = (uint2*) alloc((size_t)E*8);
  ushort* zb     = (ushort*)alloc((size_t)N*H*2);   // also bucket scratch
  ushort* sb     = (ushort*)alloc((size_t)N*H*2);   // xw, then ping-pong z
  ushort* x0b    = (ushort*)alloc((size_t)N*H*2);
  ushort* lin0T  = (ushort*)alloc(128*256*2);
  ushort* WpT    = (ushort*)alloc(4*128*128*2);
  float*  stats  = (float*) alloc(RSTATS*256*4);
  float*  scsh   = (float*) alloc(2*128*4);

  uint2* tmp = (uint2*)zb;   // E*8 = 12.8MB <= 25.6MB; free until layer-1 output

  float betas[4];
  for (int i = 0; i < 4; ++i) betas[i] = logf(0.5f/(float)(i+1) + 1.0f);
  float inv_n = 1.0f/(float)N;

  // ---- CSR build (bucketed) + degree-sort perm ----
  hipMemsetAsync(cnt, 0, (size_t)N*4, stream);
  hipMemsetAsync(dh, 0, 256*4, stream);
  hipMemsetAsync(bh, 0, 64*4, stream);
  k_count<<<(E+255)/256, 256, 0, stream>>>(col, E, cnt);
  int eb1k = (E + 1023)/1024;
  int nb1k = (N + 1023)/1024;
  k_bcount<<<eb1k, 1024, 0, stream>>>(col, E, bh);
  k_bscan<<<1, 64, 0, stream>>>(bh);
  k_dhist<<<nb1k, 1024, 0, stream>>>(cnt, dh, N);
  k_dscan<<<1, 256, 0, stream>>>(dh);
  k_dperm<<<nb1k, 1024, 0, stream>>>(cnt, dh, perm, N);
  k_scan1<<<nb1k, 1024, 0, stream>>>(cnt, off, bsum, dinv, N);
  k_scan2<<<1, 64, 0, stream>>>(bsum, nb1k);
  k_scan3<<<(N+255)/256, 256, 0, stream>>>(off, cursor, bsum, N, E);
  k_bucket<<<eb1k, 1024, 0, stream>>>(row, col, E, bh, tmp);
  int f2wg = (E + 255)/256;
  k_fill2<<<f2wg, 256, 0, stream>>>(tmp, E, dinv, cursor, edge, f2wg);

  k_prepw<<<(128*256 + 4*128*128 + 255)/256, 256, 0, stream>>>(
      lin0_w, conv_w, lin0T, WpT, betas[0], betas[1], betas[2], betas[3]);

  int gemm_blocks = (N + 63)/64;
  int lay_blocks  = (N + 31)/32;
  int prop_blocks = (N + 15)/16;      // 16 quads (nodes) per 256-thread block
  int bn_blocks   = ((N*16) + 255)/256;

  // ---- input layer: xw = x @ lin0 ; x0 = prop(xw)+b  (z0 == x0) ----
  k_gemm0<<<gemm_blocks, 256, 0, stream>>>(x, lin0T, sb, N);
  k_prop0<<<prop_blocks, 256, 0, stream>>>(sb, off, edge, dinv, lin0_b, perm, x0b, N);

  hipMemsetAsync(stats, 0, RSTATS*256*4, stream);   // once; k_bnfinal re-zeroes

  // ---- layer 0: zin=x0b (== x0) -> zout=sb, stats; then BN in place ----
  k_layer<true,false,true><<<lay_blocks, 256, 0, stream>>>(
      x0b, x0b, off, edge, dinv, WpT + 0*128*128, perm, sb, stats, N);
  k_bnfinal<<<1, 128, 0, stream>>>(stats, bn_gamma + 0*H, bn_beta + 0*H, scsh, inv_n);
  k_bnapply<<<bn_blocks, 256, 0, stream>>>((uint4*)sb, scsh, N*16);

  // ---- layer 1: zin=sb -> zout=zb, stats; BN in place ----
  k_layer<true,false,false><<<lay_blocks, 256, 0, stream>>>(
      sb, x0b, off, edge, dinv, WpT + 1*128*128, perm, zb, stats, N);
  k_bnfinal<<<1, 128, 0, stream>>>(stats, bn_gamma + 1*H, bn_beta + 1*H, scsh, inv_n);
  k_bnapply<<<bn_blocks, 256, 0, stream>>>((uint4*)zb, scsh, N*16);

  // ---- layer 2: zin=zb -> zout=sb, stats; BN in place ----
  k_layer<true,false,false><<<lay_blocks, 256, 0, stream>>>(
      zb, x0b, off, edge, dinv, WpT + 2*128*128, perm, sb, stats, N);
  k_bnfinal<<<1, 128, 0, stream>>>(stats, bn_gamma + 2*H, bn_beta + 2*H, scsh, inv_n);
  k_bnapply<<<bn_blocks, 256, 0, stream>>>((uint4*)sb, scsh, N*16);

  // ---- layer 3: zin=sb -> out (f32), no stats ----
  k_layer<false,true,false><<<lay_blocks, 256, 0, stream>>>(
      sb, x0b, off, edge, dinv, WpT + 3*128*128, perm, out, nullptr, N);
}

// Round 13
// 644.547 us; speedup vs baseline: 1.0574x; 1.0574x over previous
//
#include <hip/hip_runtime.h>
#include <hip/hip_bf16.h>
#include <math.h>

#define H 128
#define EPS_BN 1e-5f
#define RSTATS 16

typedef __attribute__((ext_vector_type(8))) short short8;
typedef __attribute__((ext_vector_type(4))) float f32x4;

__device__ __forceinline__ float bf2f(ushort u){
  union { float f; uint v; } x; x.v = ((uint)u) << 16; return x.f;
}
__device__ __forceinline__ ushort f2bf(float f){
  union { float f; uint v; } x; x.f = f;
  uint v = x.v;
  uint r = v + 0x7fff + ((v >> 16) & 1);   // RNE
  return (ushort)(r >> 16);
}

__device__ __forceinline__ void acc8(float* a, uint4 v, float wt){
  a[0] += wt*bf2f((ushort)(v.x & 0xffff)); a[1] += wt*bf2f((ushort)(v.x >> 16));
  a[2] += wt*bf2f((ushort)(v.y & 0xffff)); a[3] += wt*bf2f((ushort)(v.y >> 16));
  a[4] += wt*bf2f((ushort)(v.z & 0xffff)); a[5] += wt*bf2f((ushort)(v.z >> 16));
  a[6] += wt*bf2f((ushort)(v.w & 0xffff)); a[7] += wt*bf2f((ushort)(v.w >> 16));
}

// ---------------- CSR build ----------------

__global__ void k_count(const int* __restrict__ col, int E, int* __restrict__ cnt){
  int i = blockIdx.x*blockDim.x + threadIdx.x;
  if (i < E) atomicAdd(&cnt[col[i]], 1);
}

__global__ void k_scan1(const int* __restrict__ cnt, int* __restrict__ off,
                        int* __restrict__ bsum, float* __restrict__ dinv, int n){
  __shared__ int s[1024];
  int t = threadIdx.x;
  int i = blockIdx.x*1024 + t;
  int v = (i < n) ? cnt[i] : 0;
  if (i < n) dinv[i] = rsqrtf((float)v + 1.0f);   // +1 self-loop
  s[t] = v; __syncthreads();
  for (int d = 1; d < 1024; d <<= 1){
    int x = (t >= d) ? s[t-d] : 0;
    __syncthreads();
    s[t] += x;
    __syncthreads();
  }
  if (i < n) off[i] = s[t] - v;
  if (t == 1023) bsum[blockIdx.x] = s[1023];
}

__global__ void k_scan2(int* bsum, int nb){
  int l = threadIdx.x;           // 64 threads, 1 block
  int carry = 0;
  for (int b0 = 0; b0 < nb; b0 += 64){
    int i = b0 + l;
    int orig = (i < nb) ? bsum[i] : 0;
    int v = orig;
    #pragma unroll
    for (int d = 1; d < 64; d <<= 1){
      int x = __shfl_up(v, d);
      if (l >= d) v += x;
    }
    if (i < nb) bsum[i] = carry + v - orig;   // exclusive
    carry += __shfl(v, 63);
  }
}

__global__ void k_scan3(int* __restrict__ off, int* __restrict__ cursor,
                        const int* __restrict__ bsum, int n, int Etot){
  int i = blockIdx.x*blockDim.x + threadIdx.x;
  if (i < n){ int o = off[i] + bsum[i >> 10]; off[i] = o; cursor[i] = o; }
  if (i == 0) off[n] = Etot;
}

// edge record = source index only (4 B); weight recomputed in gather
__global__ void k_fill(const int* __restrict__ row, const int* __restrict__ col, int E,
                       int* __restrict__ cursor, int* __restrict__ esrc){
  int i = blockIdx.x*blockDim.x + threadIdx.x;
  if (i < E){
    int c = col[i], r = row[i];
    int p = atomicAdd(&cursor[c], 1);
    esrc[p] = r;
  }
}

// -------- degree-sort permutation: LDS-aggregated counting sort (256 bins) ----

__global__ __launch_bounds__(1024) void k_dhist(
    const int* __restrict__ cnt, int* __restrict__ dh, int n){
  __shared__ int lh[256];
  int t = threadIdx.x;
  if (t < 256) lh[t] = 0;
  __syncthreads();
  int i = blockIdx.x*1024 + t;
  if (i < n){
    int d = cnt[i]; if (d > 255) d = 255;
    atomicAdd(&lh[d], 1);
  }
  __syncthreads();
  if (t < 256 && lh[t]) atomicAdd(&dh[t], lh[t]);
}

__global__ void k_dscan(int* __restrict__ dh){   // 1 block, 256 threads
  __shared__ int s[256];
  int t = threadIdx.x;
  int v = dh[t];
  s[t] = v; __syncthreads();
  for (int d = 1; d < 256; d <<= 1){
    int x = (t >= d) ? s[t-d] : 0;
    __syncthreads();
    s[t] += x;
    __syncthreads();
  }
  dh[t] = s[t] - v;   // exclusive; reused as cursor
}

__global__ __launch_bounds__(1024) void k_dperm(
    const int* __restrict__ cnt, int* __restrict__ dh,
    int* __restrict__ perm, int n){
  __shared__ int lh[256];
  __shared__ int lbase[256];
  int t = threadIdx.x;
  if (t < 256) lh[t] = 0;
  __syncthreads();
  int i = blockIdx.x*1024 + t;
  int d = 0, li = 0;
  if (i < n){
    d = cnt[i]; if (d > 255) d = 255;
    li = atomicAdd(&lh[d], 1);
  }
  __syncthreads();
  if (t < 256){
    int c = lh[t];
    lbase[t] = c ? atomicAdd(&dh[t], c) : 0;
  }
  __syncthreads();
  if (i < n) perm[lbase[d] + li] = i;
}

// ---------------- weight prep: bf16, transposed, beta-folded ----------------

__global__ void k_prepw(const float* __restrict__ lin0_w, const float* __restrict__ conv_w,
                        ushort* __restrict__ lin0T, ushort* __restrict__ WpT,
                        float b0, float b1, float b2, float b3){
  int i = blockIdx.x*blockDim.x + threadIdx.x;
  if (i < 128*256){
    int nn = i >> 8, k = i & 255;
    lin0T[i] = f2bf(lin0_w[k*128 + nn]);
  } else if (i < 128*256 + 4*128*128){
    int j = i - 128*256;
    int ll = j >> 14, rc = j & 16383;
    int nn = rc >> 7, k = rc & 127;
    float beta = (ll==0)?b0:(ll==1)?b1:(ll==2)?b2:b3;
    float v = beta * conv_w[ll*16384 + k*128 + nn];
    if (k == nn) v += 1.0f - beta;
    WpT[j] = f2bf(v);
  }
}

// ---------------- gather core: A = sum dinv[r]*h[r]; quad-per-node ----------
// dinv[r] load is lane-uniform + L2-resident; issues parallel to the row fetch.

__device__ __forceinline__ void gather_edges(
    float* a, const ushort* __restrict__ zin, const int* __restrict__ esrc,
    const float* __restrict__ dinv, int e0, int e1, int lr){
  int e = e0;
  for (; e + 3 < e1; e += 4){
    int r0 = esrc[e],   r1 = esrc[e+1];
    int r2 = esrc[e+2], r3 = esrc[e+3];
    float w0 = dinv[r0], w1 = dinv[r1], w2 = dinv[r2], w3 = dinv[r3];
    uint4 v0 = *(const uint4*)(zin + (size_t)r0*H + lr*8);
    uint4 v1 = *(const uint4*)(zin + (size_t)r1*H + lr*8);
    uint4 v2 = *(const uint4*)(zin + (size_t)r2*H + lr*8);
    uint4 v3 = *(const uint4*)(zin + (size_t)r3*H + lr*8);
    acc8(a, v0, w0);
    acc8(a, v1, w1);
    acc8(a, v2, w2);
    acc8(a, v3, w3);
  }
  for (; e < e1; ++e){
    int r = esrc[e];
    float w = dinv[r];
    uint4 v = *(const uint4*)(zin + (size_t)r*H + lr*8);
    acc8(a, v, w);
  }
}

// ---------------- input-layer prop: x0 = dinv_c*(A + dinv_c*h_c) + b --------

__global__ __launch_bounds__(256) void k_prop0(
    const ushort* __restrict__ h, const int* __restrict__ off,
    const int* __restrict__ esrc, const float* __restrict__ dinv,
    const float* __restrict__ bias, const int* __restrict__ perm,
    ushort* __restrict__ x0, int n){
  int pq = (blockIdx.x*blockDim.x + threadIdx.x) >> 4;
  if (pq >= n) return;
  int gq = perm[pq];                 // same for all 16 lanes of the quad
  int lr = threadIdx.x & 15;
  float a[8];
  #pragma unroll
  for (int j = 0; j < 8; ++j) a[j] = 0.f;
  float dc = dinv[gq];
  uint4 vs = *(const uint4*)(h + (size_t)gq*H + lr*8);
  gather_edges(a, h, esrc, dinv, off[gq], off[gq+1], lr);
  acc8(a, vs, dc);                  // + dinv_c * h_c
  float4 b0 = *(const float4*)(bias + lr*8);
  float4 b1 = *(const float4*)(bias + lr*8 + 4);
  uint4 pk;
  pk.x = (uint)f2bf(dc*a[0]+b0.x) | ((uint)f2bf(dc*a[1]+b0.y) << 16);
  pk.y = (uint)f2bf(dc*a[2]+b0.z) | ((uint)f2bf(dc*a[3]+b0.w) << 16);
  pk.z = (uint)f2bf(dc*a[4]+b1.x) | ((uint)f2bf(dc*a[5]+b1.y) << 16);
  pk.w = (uint)f2bf(dc*a[6]+b1.z) | ((uint)f2bf(dc*a[7]+b1.w) << 16);
  *(uint4*)(x0 + (size_t)gq*H + lr*8) = pk;
}

// ---------------- fused layer: prop -> LDS s-tile -> MFMA GEMM -> z (+stats) --
// block = 256 thr (4 waves) = 32 nodes taken from degree-sorted perm[] so all
// quads have ~equal work. Outputs written to original rows.

template<bool STATS, bool OUTF32, bool SAMEX0>
__global__ __launch_bounds__(256) void k_layer(
    const ushort* __restrict__ zin, const ushort* __restrict__ x0,
    const int* __restrict__ off, const int* __restrict__ esrc,
    const float* __restrict__ dinv, const ushort* __restrict__ BT,
    const int* __restrict__ perm,
    void* __restrict__ zout, float* __restrict__ stats, int n)
{
  __shared__ ushort Sm[32*128];   // swizzled s tile: row*128 + ((blk16^(row&15))*8)
  __shared__ int pm[32];
  int t = threadIdx.x;
  int w = t >> 6, l = t & 63;
  int lr = l & 15, q = l >> 4;
  int base = blockIdx.x * 32;
  if (t < 32) pm[t] = (base + t < n) ? perm[base + t] : -1;
  __syncthreads();

  // ---- prop phase: quad-per-node, 2 nodes per quad ----
  #pragma unroll
  for (int g2 = 0; g2 < 2; ++g2){
    int row  = w*8 + g2*4 + q;
    int node = pm[row];
    float a[8];
    #pragma unroll
    for (int j = 0; j < 8; ++j) a[j] = 0.f;
    uint4 pk = make_uint4(0u,0u,0u,0u);
    if (node >= 0){
      float dc = dinv[node];
      uint4 vs = *(const uint4*)(zin + (size_t)node*H + lr*8);
      gather_edges(a, zin, esrc, dinv, off[node], off[node+1], lr);
      acc8(a, vs, dc);              // + dinv_c * h_c
      uint4 xv = SAMEX0 ? vs : *(const uint4*)(x0 + (size_t)node*H + lr*8);
      float s0 = 0.9f*dc*a[0] + 0.1f*bf2f((ushort)(xv.x & 0xffff));
      float s1 = 0.9f*dc*a[1] + 0.1f*bf2f((ushort)(xv.x >> 16));
      float s2 = 0.9f*dc*a[2] + 0.1f*bf2f((ushort)(xv.y & 0xffff));
      float s3 = 0.9f*dc*a[3] + 0.1f*bf2f((ushort)(xv.y >> 16));
      float s4 = 0.9f*dc*a[4] + 0.1f*bf2f((ushort)(xv.z & 0xffff));
      float s5 = 0.9f*dc*a[5] + 0.1f*bf2f((ushort)(xv.z >> 16));
      float s6 = 0.9f*dc*a[6] + 0.1f*bf2f((ushort)(xv.w & 0xffff));
      float s7 = 0.9f*dc*a[7] + 0.1f*bf2f((ushort)(xv.w >> 16));
      pk.x = (uint)f2bf(s0) | ((uint)f2bf(s1) << 16);
      pk.y = (uint)f2bf(s2) | ((uint)f2bf(s3) << 16);
      pk.z = (uint)f2bf(s4) | ((uint)f2bf(s5) << 16);
      pk.w = (uint)f2bf(s6) | ((uint)f2bf(s7) << 16);
    }
    *(uint4*)(&Sm[row*128 + ((lr ^ (row & 15))*8)]) = pk;
  }

  // ---- B fragments (W'^T slice for this wave's 32 cols) ----
  short8 bfr[2][4];
  #pragma unroll
  for (int c = 0; c < 2; ++c)
    #pragma unroll
    for (int ks = 0; ks < 4; ++ks)
      bfr[c][ks] = *(const short8*)(BT + (size_t)(w*32 + c*16 + lr)*H + ks*32 + q*8);

  __syncthreads();

  // ---- GEMM phase: 32 rows x 32 cols per wave ----
  f32x4 acc[2][2];
  #pragma unroll
  for (int rt = 0; rt < 2; ++rt){
    acc[rt][0] = (f32x4){0.f,0.f,0.f,0.f};
    acc[rt][1] = (f32x4){0.f,0.f,0.f,0.f};
  }
  #pragma unroll
  for (int rt = 0; rt < 2; ++rt){
    int row = rt*16 + lr;
    #pragma unroll
    for (int ks = 0; ks < 4; ++ks){
      short8 af = *(const short8*)(&Sm[row*128 + (((ks*4 + q) ^ (row & 15))*8)]);
      acc[rt][0] = __builtin_amdgcn_mfma_f32_16x16x32_bf16(af, bfr[0][ks], acc[rt][0], 0,0,0);
      acc[rt][1] = __builtin_amdgcn_mfma_f32_16x16x32_bf16(af, bfr[1][ks], acc[rt][1], 0,0,0);
    }
  }

  // ---- epilogue: write z to ORIGINAL rows via pm, accumulate BN stats ----
  #pragma unroll
  for (int rt = 0; rt < 2; ++rt){
    #pragma unroll
    for (int c = 0; c < 2; ++c){
      #pragma unroll
      for (int j2 = 0; j2 < 4; ++j2){
        int rowl = rt*16 + q*4 + j2;
        int nodeo = pm[rowl];
        float v = acc[rt][c][j2];
        if (OUTF32){
          if (nodeo >= 0)
            ((float*)zout)[(size_t)nodeo*H + w*32 + c*16 + lr] = v;
        } else {
          float other = __shfl(v, l ^ 1);
          if (!(lr & 1) && nodeo >= 0){
            uint pk = (uint)f2bf(v) | ((uint)f2bf(other) << 16);
            ((uint*)zout)[(size_t)nodeo*64 + w*16 + c*8 + (lr >> 1)] = pk;
          }
        }
      }
    }
  }
  if (STATS){
    #pragma unroll
    for (int c = 0; c < 2; ++c){
      float sv = 0.f, sq = 0.f;
      #pragma unroll
      for (int rt = 0; rt < 2; ++rt)
        #pragma unroll
        for (int j2 = 0; j2 < 4; ++j2){
          float v = acc[rt][c][j2];   // invalid rows have s=0 -> acc=0
          sv += v; sq += v*v;
        }
      sv += __shfl(sv, l ^ 16); sv += __shfl(sv, l ^ 32);
      sq += __shfl(sq, l ^ 16); sq += __shfl(sq, l ^ 32);
      if (q == 0){
        float* st = stats + (size_t)(blockIdx.x & (RSTATS-1))*256;
        atomicAdd(&st[w*32 + c*16 + lr], sv);
        atomicAdd(&st[128 + w*32 + c*16 + lr], sq);
      }
    }
  }
}

// ---------------- BN finalize: stats replicas -> scale/shift; re-zero -------

__global__ void k_bnfinal(float* __restrict__ stats, const float* __restrict__ gamma,
                          const float* __restrict__ beta, float* __restrict__ scsh,
                          float inv_n){
  int f = threadIdx.x;   // 128
  float s = 0.f, s2 = 0.f;
  for (int r = 0; r < RSTATS; ++r){
    s  += stats[r*256 + f];
    s2 += stats[r*256 + 128 + f];
    stats[r*256 + f] = 0.f;          // re-zero for next layer
    stats[r*256 + 128 + f] = 0.f;
  }
  float mu  = s * inv_n;
  float var = s2 * inv_n - mu*mu;
  float sc  = rsqrtf(var + EPS_BN) * gamma[f];
  scsh[f]       = sc;
  scsh[128 + f] = beta[f] - mu*sc;
}

// ---------------- BN apply (in place): y = relu(z*sc + sh), bf16 ----------

__global__ __launch_bounds__(256) void k_bnapply(
    uint4* __restrict__ z, const float* __restrict__ scsh, int n16){
  int i = blockIdx.x*blockDim.x + threadIdx.x;   // one uint4 = 8 elems
  if (i >= n16) return;
  int f8 = (i & 15) * 8;
  uint4 v = z[i];
  uint r[4];
  #pragma unroll
  for (int p = 0; p < 4; ++p){
    uint  u  = (&v.x)[p];
    float z0 = bf2f((ushort)(u & 0xffff));
    float z1 = bf2f((ushort)(u >> 16));
    float y0 = fmaxf(fmaf(z0, scsh[f8 + p*2],     scsh[128 + f8 + p*2]),     0.f);
    float y1 = fmaxf(fmaf(z1, scsh[f8 + p*2 + 1], scsh[128 + f8 + p*2 + 1]), 0.f);
    r[p] = (uint)f2bf(y0) | ((uint)f2bf(y1) << 16);
  }
  z[i] = make_uint4(r[0], r[1], r[2], r[3]);
}

// ---------------- MFMA GEMM for input layer: xw = x(f32) @ lin0T^T ----------

__global__ __launch_bounds__(256) void k_gemm0(
    const float* __restrict__ Af, const ushort* __restrict__ BT,
    ushort* __restrict__ Cb, int n){
  const int K = 256;
  __shared__ ushort As[64*32];
  __shared__ ushort Bs[128*32];
  int t = threadIdx.x;
  int br = blockIdx.x * 64;
  int w = t >> 6, l = t & 63;
  int lr = l & 15, lk = l >> 4;
  int swz = (lr >> 1) & 3;

  f32x4 acc[8];
  #pragma unroll
  for (int i = 0; i < 8; ++i) acc[i] = (f32x4){0.f,0.f,0.f,0.f};

  int sar = t >> 2;
  int sab = t & 3;
  int sa_off = sar*32 + ((sab ^ ((sar>>1)&3))*8);

  for (int k0 = 0; k0 < K; k0 += 32){
    int grow = br + sar;
    float4 v0 = make_float4(0.f,0.f,0.f,0.f), v1 = v0;
    if (grow < n){
      v0 = *(const float4*)(Af + (size_t)grow*K + k0 + sab*8);
      v1 = *(const float4*)(Af + (size_t)grow*K + k0 + sab*8 + 4);
    }
    ushort tmp[8] = {f2bf(v0.x),f2bf(v0.y),f2bf(v0.z),f2bf(v0.w),
                     f2bf(v1.x),f2bf(v1.y),f2bf(v1.z),f2bf(v1.w)};
    *(uint4*)(&As[sa_off]) = *(const uint4*)tmp;
    #pragma unroll
    for (int i = 0; i < 2; ++i){
      int qq = t + i*256;
      int nrow = qq >> 2, bb = qq & 3;
      uint4 v = *(const uint4*)(BT + (size_t)nrow*K + k0 + bb*8);
      *(uint4*)(&Bs[nrow*32 + ((bb ^ ((nrow>>1)&3))*8)]) = v;
    }
    __syncthreads();
    short8 af = *(const short8*)(&As[(w*16+lr)*32 + ((lk ^ swz)*8)]);
    #pragma unroll
    for (int tn = 0; tn < 8; ++tn){
      short8 bfv = *(const short8*)(&Bs[(tn*16+lr)*32 + ((lk ^ swz)*8)]);
      acc[tn] = __builtin_amdgcn_mfma_f32_16x16x32_bf16(af, bfv, acc[tn], 0, 0, 0);
    }
    __syncthreads();
  }
  int orow = br + w*16 + lk*4;
  #pragma unroll
  for (int tn = 0; tn < 8; ++tn){
    #pragma unroll
    for (int j = 0; j < 4; ++j){
      float mine  = acc[tn][j];
      float other = __shfl(mine, l ^ 1);
      if (!(l & 1) && (orow + j) < n){
        uint pk = (uint)f2bf(mine) | ((uint)f2bf(other) << 16);
        ((uint*)Cb)[(size_t)(orow+j)*64 + tn*8 + (lr >> 1)] = pk;
      }
    }
  }
}

// ---------------- launch ----------------

extern "C" void kernel_launch(void* const* d_in, const int* in_sizes, int n_in,
                              void* d_out, int out_size, void* d_ws, size_t ws_size,
                              hipStream_t stream){
  const float* x        = (const float*)d_in[0];
  const int*   ei       = (const int*)  d_in[1];
  const float* lin0_w   = (const float*)d_in[2];
  const float* lin0_b   = (const float*)d_in[3];
  const float* conv_w   = (const float*)d_in[4];
  const float* bn_gamma = (const float*)d_in[5];
  const float* bn_beta  = (const float*)d_in[6];
  float* out = (float*)d_out;

  int N = in_sizes[0] / 256;
  int E = in_sizes[1] / 2;
  const int* row = ei;
  const int* col = ei + E;

  char* ws = (char*)d_ws;
  size_t p = 0;
  auto alloc = [&](size_t bytes)->char*{
    char* r = ws + p; p = (p + bytes + 255) & ~(size_t)255; return r;
  };
  int*    cnt    = (int*)   alloc((size_t)N*4);
  int*    off    = (int*)   alloc((size_t)(N+1)*4);
  int*    cursor = (int*)   alloc((size_t)N*4);
  float*  dinv   = (float*) alloc((size_t)N*4);
  int*    bsum   = (int*)   alloc(512*4);
  int*    dh     = (int*)   alloc(256*4);
  int*    perm   = (int*)   alloc((size_t)N*4);
  int*    esrc   = (int*)   alloc((size_t)E*4);
  ushort* zb     = (ushort*)alloc((size_t)N*H*2);
  ushort* sb     = (ushort*)alloc((size_t)N*H*2);   // xw, then ping-pong z
  ushort* x0b    = (ushort*)alloc((size_t)N*H*2);
  ushort* lin0T  = (ushort*)alloc(128*256*2);
  ushort* WpT    = (ushort*)alloc(4*128*128*2);
  float*  stats  = (float*) alloc(RSTATS*256*4);
  float*  scsh   = (float*) alloc(2*128*4);

  float betas[4];
  for (int i = 0; i < 4; ++i) betas[i] = logf(0.5f/(float)(i+1) + 1.0f);
  float inv_n = 1.0f/(float)N;

  // ---- CSR build + degree-sort perm (LDS-aggregated) ----
  hipMemsetAsync(cnt, 0, (size_t)N*4, stream);
  hipMemsetAsync(dh, 0, 256*4, stream);
  k_count<<<(E+255)/256, 256, 0, stream>>>(col, E, cnt);
  int nb1k = (N + 1023)/1024;
  k_dhist<<<nb1k, 1024, 0, stream>>>(cnt, dh, N);
  k_dscan<<<1, 256, 0, stream>>>(dh);
  k_dperm<<<nb1k, 1024, 0, stream>>>(cnt, dh, perm, N);
  k_scan1<<<nb1k, 1024, 0, stream>>>(cnt, off, bsum, dinv, N);
  k_scan2<<<1, 64, 0, stream>>>(bsum, nb1k);
  k_scan3<<<(N+255)/256, 256, 0, stream>>>(off, cursor, bsum, N, E);
  k_fill <<<(E+255)/256, 256, 0, stream>>>(row, col, E, cursor, esrc);

  k_prepw<<<(128*256 + 4*128*128 + 255)/256, 256, 0, stream>>>(
      lin0_w, conv_w, lin0T, WpT, betas[0], betas[1], betas[2], betas[3]);

  int gemm_blocks = (N + 63)/64;
  int lay_blocks  = (N + 31)/32;
  int prop_blocks = (N + 15)/16;      // 16 quads (nodes) per 256-thread block
  int bn_blocks   = ((N*16) + 255)/256;

  // ---- input layer: xw = x @ lin0 ; x0 = prop(xw)+b  (z0 == x0) ----
  k_gemm0<<<gemm_blocks, 256, 0, stream>>>(x, lin0T, sb, N);
  k_prop0<<<prop_blocks, 256, 0, stream>>>(sb, off, esrc, dinv, lin0_b, perm, x0b, N);

  hipMemsetAsync(stats, 0, RSTATS*256*4, stream);   // once; k_bnfinal re-zeroes

  // ---- layer 0: zin=x0b (== x0) -> zout=sb, stats; then BN in place ----
  k_layer<true,false,true><<<lay_blocks, 256, 0, stream>>>(
      x0b, x0b, off, esrc, dinv, WpT + 0*128*128, perm, sb, stats, N);
  k_bnfinal<<<1, 128, 0, stream>>>(stats, bn_gamma + 0*H, bn_beta + 0*H, scsh, inv_n);
  k_bnapply<<<bn_blocks, 256, 0, stream>>>((uint4*)sb, scsh, N*16);

  // ---- layer 1: zin=sb -> zout=zb, stats; BN in place ----
  k_layer<true,false,false><<<lay_blocks, 256, 0, stream>>>(
      sb, x0b, off, esrc, dinv, WpT + 1*128*128, perm, zb, stats, N);
  k_bnfinal<<<1, 128, 0, stream>>>(stats, bn_gamma + 1*H, bn_beta + 1*H, scsh, inv_n);
  k_bnapply<<<bn_blocks, 256, 0, stream>>>((uint4*)zb, scsh, N*16);

  // ---- layer 2: zin=zb -> zout=sb, stats; BN in place ----
  k_layer<true,false,false><<<lay_blocks, 256, 0, stream>>>(
      zb, x0b, off, esrc, dinv, WpT + 2*128*128, perm, sb, stats, N);
  k_bnfinal<<<1, 128, 0, stream>>>(stats, bn_gamma + 2*H, bn_beta + 2*H, scsh, inv_n);
  k_bnapply<<<bn_blocks, 256, 0, stream>>>((uint4*)sb, scsh, N*16);

  // ---- layer 3: zin=sb -> out (f32), no stats ----
  k_layer<false,true,false><<<lay_blocks, 256, 0, stream>>>(
      sb, x0b, off, esrc, dinv, WpT + 3*128*128, perm, out, nullptr, N);
}

// Round 14
// 612.644 us; speedup vs baseline: 1.1124x; 1.0521x over previous
//
#include <hip/hip_runtime.h>
#include <hip/hip_bf16.h>
#include <math.h>

#define H 128
#define EPS_BN 1e-5f
#define RSTATS 16

typedef __attribute__((ext_vector_type(8))) short short8;
typedef __attribute__((ext_vector_type(4))) float f32x4;

__device__ __forceinline__ float bf2f(ushort u){
  union { float f; uint v; } x; x.v = ((uint)u) << 16; return x.f;
}
__device__ __forceinline__ ushort f2bf(float f){
  union { float f; uint v; } x; x.f = f;
  uint v = x.v;
  uint r = v + 0x7fff + ((v >> 16) & 1);   // RNE
  return (ushort)(r >> 16);
}

__device__ __forceinline__ void acc8(float* a, uint4 v, float wt){
  a[0] += wt*bf2f((ushort)(v.x & 0xffff)); a[1] += wt*bf2f((ushort)(v.x >> 16));
  a[2] += wt*bf2f((ushort)(v.y & 0xffff)); a[3] += wt*bf2f((ushort)(v.y >> 16));
  a[4] += wt*bf2f((ushort)(v.z & 0xffff)); a[5] += wt*bf2f((ushort)(v.z >> 16));
  a[6] += wt*bf2f((ushort)(v.w & 0xffff)); a[7] += wt*bf2f((ushort)(v.w >> 16));
}

// ---------------- CSR build ----------------

__global__ void k_count(const int* __restrict__ col, int E, int* __restrict__ cnt){
  int i = blockIdx.x*blockDim.x + threadIdx.x;
  if (i < E) atomicAdd(&cnt[col[i]], 1);
}

__global__ void k_scan1(const int* __restrict__ cnt, int* __restrict__ off,
                        int* __restrict__ bsum, float* __restrict__ dinv, int n){
  __shared__ int s[1024];
  int t = threadIdx.x;
  int i = blockIdx.x*1024 + t;
  int v = (i < n) ? cnt[i] : 0;
  if (i < n) dinv[i] = rsqrtf((float)v + 1.0f);   // +1 self-loop
  s[t] = v; __syncthreads();
  for (int d = 1; d < 1024; d <<= 1){
    int x = (t >= d) ? s[t-d] : 0;
    __syncthreads();
    s[t] += x;
    __syncthreads();
  }
  if (i < n) off[i] = s[t] - v;
  if (t == 1023) bsum[blockIdx.x] = s[1023];
}

__global__ void k_scan2(int* bsum, int nb){
  int l = threadIdx.x;           // 64 threads, 1 block
  int carry = 0;
  for (int b0 = 0; b0 < nb; b0 += 64){
    int i = b0 + l;
    int orig = (i < nb) ? bsum[i] : 0;
    int v = orig;
    #pragma unroll
    for (int d = 1; d < 64; d <<= 1){
      int x = __shfl_up(v, d);
      if (l >= d) v += x;
    }
    if (i < nb) bsum[i] = carry + v - orig;   // exclusive
    carry += __shfl(v, 63);
  }
}

__global__ void k_scan3(int* __restrict__ off, int* __restrict__ cursor,
                        const int* __restrict__ bsum, int n, int Etot){
  int i = blockIdx.x*blockDim.x + threadIdx.x;
  if (i < n){ int o = off[i] + bsum[i >> 10]; off[i] = o; cursor[i] = o; }
  if (i == 0) off[n] = Etot;
}

__global__ void k_fill(const int* __restrict__ row, const int* __restrict__ col, int E,
                       const float* __restrict__ dinv, int* __restrict__ cursor,
                       uint2* __restrict__ edge){
  int i = blockIdx.x*blockDim.x + threadIdx.x;
  if (i < E){
    int c = col[i], r = row[i];
    int p = atomicAdd(&cursor[c], 1);
    edge[p] = make_uint2((uint)r, __float_as_uint(dinv[r]*dinv[c]));
  }
}

// -------- degree-sort permutation: LDS-aggregated counting sort (256 bins) ----

__global__ __launch_bounds__(1024) void k_dhist(
    const int* __restrict__ cnt, int* __restrict__ dh, int n){
  __shared__ int lh[256];
  int t = threadIdx.x;
  if (t < 256) lh[t] = 0;
  __syncthreads();
  int i = blockIdx.x*1024 + t;
  if (i < n){
    int d = cnt[i]; if (d > 255) d = 255;
    atomicAdd(&lh[d], 1);
  }
  __syncthreads();
  if (t < 256 && lh[t]) atomicAdd(&dh[t], lh[t]);
}

__global__ void k_dscan(int* __restrict__ dh){   // 1 block, 256 threads
  __shared__ int s[256];
  int t = threadIdx.x;
  int v = dh[t];
  s[t] = v; __syncthreads();
  for (int d = 1; d < 256; d <<= 1){
    int x = (t >= d) ? s[t-d] : 0;
    __syncthreads();
    s[t] += x;
    __syncthreads();
  }
  dh[t] = s[t] - v;   // exclusive; reused as cursor
}

__global__ __launch_bounds__(1024) void k_dperm(
    const int* __restrict__ cnt, int* __restrict__ dh,
    int* __restrict__ perm, int n){
  __shared__ int lh[256];
  __shared__ int lbase[256];
  int t = threadIdx.x;
  if (t < 256) lh[t] = 0;
  __syncthreads();
  int i = blockIdx.x*1024 + t;
  int d = 0, li = 0;
  if (i < n){
    d = cnt[i]; if (d > 255) d = 255;
    li = atomicAdd(&lh[d], 1);
  }
  __syncthreads();
  if (t < 256){
    int c = lh[t];
    lbase[t] = c ? atomicAdd(&dh[t], c) : 0;
  }
  __syncthreads();
  if (i < n) perm[lbase[d] + li] = i;
}

// ---------------- weight prep: bf16, transposed, beta-folded ----------------

__global__ void k_prepw(const float* __restrict__ lin0_w, const float* __restrict__ conv_w,
                        ushort* __restrict__ lin0T, ushort* __restrict__ WpT,
                        float b0, float b1, float b2, float b3){
  int i = blockIdx.x*blockDim.x + threadIdx.x;
  if (i < 128*256){
    int nn = i >> 8, k = i & 255;
    lin0T[i] = f2bf(lin0_w[k*128 + nn]);
  } else if (i < 128*256 + 4*128*128){
    int j = i - 128*256;
    int ll = j >> 14, rc = j & 16383;
    int nn = rc >> 7, k = rc & 127;
    float beta = (ll==0)?b0:(ll==1)?b1:(ll==2)?b2:b3;
    float v = beta * conv_w[ll*16384 + k*128 + nn];
    if (k == nn) v += 1.0f - beta;
    WpT[j] = f2bf(v);
  }
}

// ---------------- gather core (R6/R11 form): edges only ---------------------
// one quad (16 lanes) per node; lane lr owns feats lr*8..lr*8+7.

__device__ __forceinline__ void gather_edges(
    float* a, const ushort* __restrict__ zin, const uint2* __restrict__ edge,
    int e0, int e1, int lr){
  int e = e0;
  for (; e + 3 < e1; e += 4){
    uint2 er0 = edge[e],   er1 = edge[e+1];
    uint2 er2 = edge[e+2], er3 = edge[e+3];
    uint4 v0 = *(const uint4*)(zin + (size_t)er0.x*H + lr*8);
    uint4 v1 = *(const uint4*)(zin + (size_t)er1.x*H + lr*8);
    uint4 v2 = *(const uint4*)(zin + (size_t)er2.x*H + lr*8);
    uint4 v3 = *(const uint4*)(zin + (size_t)er3.x*H + lr*8);
    acc8(a, v0, __uint_as_float(er0.y));
    acc8(a, v1, __uint_as_float(er1.y));
    acc8(a, v2, __uint_as_float(er2.y));
    acc8(a, v3, __uint_as_float(er3.y));
  }
  for (; e < e1; ++e){
    uint2 er = edge[e];
    uint4 v = *(const uint4*)(zin + (size_t)er.x*H + lr*8);
    acc8(a, v, __uint_as_float(er.y));
  }
}

// ---------------- input-layer prop: x0 = agg(xw)+b ; quad-per-node (LJF) ----

__global__ __launch_bounds__(256) void k_prop0(
    const ushort* __restrict__ h, const int* __restrict__ off,
    const uint2* __restrict__ edge, const float* __restrict__ dinv,
    const float* __restrict__ bias, const int* __restrict__ perm,
    ushort* __restrict__ x0, int n){
  int pq = (blockIdx.x*blockDim.x + threadIdx.x) >> 4;
  if (pq >= n) return;
  int gq = perm[n - 1 - pq];         // longest-job-first
  int lr = threadIdx.x & 15;
  float a[8];
  #pragma unroll
  for (int j = 0; j < 8; ++j) a[j] = 0.f;
  float wc = dinv[gq]; wc *= wc;
  uint4 vs = *(const uint4*)(h + (size_t)gq*H + lr*8);
  gather_edges(a, h, edge, off[gq], off[gq+1], lr);
  acc8(a, vs, wc);
  float4 b0 = *(const float4*)(bias + lr*8);
  float4 b1 = *(const float4*)(bias + lr*8 + 4);
  uint4 pk;
  pk.x = (uint)f2bf(a[0]+b0.x) | ((uint)f2bf(a[1]+b0.y) << 16);
  pk.y = (uint)f2bf(a[2]+b0.z) | ((uint)f2bf(a[3]+b0.w) << 16);
  pk.z = (uint)f2bf(a[4]+b1.x) | ((uint)f2bf(a[5]+b1.y) << 16);
  pk.w = (uint)f2bf(a[6]+b1.z) | ((uint)f2bf(a[7]+b1.w) << 16);
  *(uint4*)(x0 + (size_t)gq*H + lr*8) = pk;
}

// ---------------- fused layer: prop -> LDS s-tile -> MFMA GEMM -> z (+stats) --
// block = 256 thr (4 waves) = 32 same-degree nodes from perm[], traversed in
// DESCENDING degree order (longest-job-first). Outputs to original rows.

template<bool STATS, bool OUTF32, bool SAMEX0>
__global__ __launch_bounds__(256) void k_layer(
    const ushort* __restrict__ zin, const ushort* __restrict__ x0,
    const int* __restrict__ off, const uint2* __restrict__ edge,
    const float* __restrict__ dinv, const ushort* __restrict__ BT,
    const int* __restrict__ perm,
    void* __restrict__ zout, float* __restrict__ stats, int n)
{
  __shared__ ushort Sm[32*128];   // swizzled s tile: row*128 + ((blk16^(row&15))*8)
  __shared__ int pm[32];
  int t = threadIdx.x;
  int w = t >> 6, l = t & 63;
  int lr = l & 15, q = l >> 4;
  int base = blockIdx.x * 32;
  if (t < 32) pm[t] = (base + t < n) ? perm[n - 1 - (base + t)] : -1;
  __syncthreads();

  // ---- prop phase: quad-per-node, 2 nodes per quad ----
  #pragma unroll
  for (int g2 = 0; g2 < 2; ++g2){
    int row  = w*8 + g2*4 + q;
    int node = pm[row];
    float a[8];
    #pragma unroll
    for (int j = 0; j < 8; ++j) a[j] = 0.f;
    uint4 pk = make_uint4(0u,0u,0u,0u);
    if (node >= 0){
      float wc = dinv[node]; wc *= wc;
      uint4 vs = *(const uint4*)(zin + (size_t)node*H + lr*8);
      gather_edges(a, zin, edge, off[node], off[node+1], lr);
      acc8(a, vs, wc);
      uint4 xv = SAMEX0 ? vs : *(const uint4*)(x0 + (size_t)node*H + lr*8);
      float s0 = 0.9f*a[0] + 0.1f*bf2f((ushort)(xv.x & 0xffff));
      float s1 = 0.9f*a[1] + 0.1f*bf2f((ushort)(xv.x >> 16));
      float s2 = 0.9f*a[2] + 0.1f*bf2f((ushort)(xv.y & 0xffff));
      float s3 = 0.9f*a[3] + 0.1f*bf2f((ushort)(xv.y >> 16));
      float s4 = 0.9f*a[4] + 0.1f*bf2f((ushort)(xv.z & 0xffff));
      float s5 = 0.9f*a[5] + 0.1f*bf2f((ushort)(xv.z >> 16));
      float s6 = 0.9f*a[6] + 0.1f*bf2f((ushort)(xv.w & 0xffff));
      float s7 = 0.9f*a[7] + 0.1f*bf2f((ushort)(xv.w >> 16));
      pk.x = (uint)f2bf(s0) | ((uint)f2bf(s1) << 16);
      pk.y = (uint)f2bf(s2) | ((uint)f2bf(s3) << 16);
      pk.z = (uint)f2bf(s4) | ((uint)f2bf(s5) << 16);
      pk.w = (uint)f2bf(s6) | ((uint)f2bf(s7) << 16);
    }
    *(uint4*)(&Sm[row*128 + ((lr ^ (row & 15))*8)]) = pk;
  }

  // ---- B fragments (W'^T slice for this wave's 32 cols) ----
  short8 bfr[2][4];
  #pragma unroll
  for (int c = 0; c < 2; ++c)
    #pragma unroll
    for (int ks = 0; ks < 4; ++ks)
      bfr[c][ks] = *(const short8*)(BT + (size_t)(w*32 + c*16 + lr)*H + ks*32 + q*8);

  __syncthreads();

  // ---- GEMM phase: 32 rows x 32 cols per wave ----
  f32x4 acc[2][2];
  #pragma unroll
  for (int rt = 0; rt < 2; ++rt){
    acc[rt][0] = (f32x4){0.f,0.f,0.f,0.f};
    acc[rt][1] = (f32x4){0.f,0.f,0.f,0.f};
  }
  #pragma unroll
  for (int rt = 0; rt < 2; ++rt){
    int row = rt*16 + lr;
    #pragma unroll
    for (int ks = 0; ks < 4; ++ks){
      short8 af = *(const short8*)(&Sm[row*128 + (((ks*4 + q) ^ (row & 15))*8)]);
      acc[rt][0] = __builtin_amdgcn_mfma_f32_16x16x32_bf16(af, bfr[0][ks], acc[rt][0], 0,0,0);
      acc[rt][1] = __builtin_amdgcn_mfma_f32_16x16x32_bf16(af, bfr[1][ks], acc[rt][1], 0,0,0);
    }
  }

  // ---- epilogue: write z to ORIGINAL rows via pm, accumulate BN stats ----
  #pragma unroll
  for (int rt = 0; rt < 2; ++rt){
    #pragma unroll
    for (int c = 0; c < 2; ++c){
      #pragma unroll
      for (int j2 = 0; j2 < 4; ++j2){
        int rowl = rt*16 + q*4 + j2;
        int nodeo = pm[rowl];
        float v = acc[rt][c][j2];
        if (OUTF32){
          if (nodeo >= 0)
            ((float*)zout)[(size_t)nodeo*H + w*32 + c*16 + lr] = v;
        } else {
          float other = __shfl(v, l ^ 1);
          if (!(lr & 1) && nodeo >= 0){
            uint pk = (uint)f2bf(v) | ((uint)f2bf(other) << 16);
            ((uint*)zout)[(size_t)nodeo*64 + w*16 + c*8 + (lr >> 1)] = pk;
          }
        }
      }
    }
  }
  if (STATS){
    #pragma unroll
    for (int c = 0; c < 2; ++c){
      float sv = 0.f, sq = 0.f;
      #pragma unroll
      for (int rt = 0; rt < 2; ++rt)
        #pragma unroll
        for (int j2 = 0; j2 < 4; ++j2){
          float v = acc[rt][c][j2];   // invalid rows have s=0 -> acc=0
          sv += v; sq += v*v;
        }
      sv += __shfl(sv, l ^ 16); sv += __shfl(sv, l ^ 32);
      sq += __shfl(sq, l ^ 16); sq += __shfl(sq, l ^ 32);
      if (q == 0){
        float* st = stats + (size_t)(blockIdx.x & (RSTATS-1))*256;
        atomicAdd(&st[w*32 + c*16 + lr], sv);
        atomicAdd(&st[128 + w*32 + c*16 + lr], sq);
      }
    }
  }
}

// ---------------- BN finalize: stats replicas -> scale/shift; re-zero -------

__global__ void k_bnfinal(float* __restrict__ stats, const float* __restrict__ gamma,
                          const float* __restrict__ beta, float* __restrict__ scsh,
                          float inv_n){
  int f = threadIdx.x;   // 128
  float s = 0.f, s2 = 0.f;
  for (int r = 0; r < RSTATS; ++r){
    s  += stats[r*256 + f];
    s2 += stats[r*256 + 128 + f];
    stats[r*256 + f] = 0.f;          // re-zero for next layer
    stats[r*256 + 128 + f] = 0.f;
  }
  float mu  = s * inv_n;
  float var = s2 * inv_n - mu*mu;
  float sc  = rsqrtf(var + EPS_BN) * gamma[f];
  scsh[f]       = sc;
  scsh[128 + f] = beta[f] - mu*sc;
}

// ---------------- BN apply (in place): y = relu(z*sc + sh), bf16 ----------

__global__ __launch_bounds__(256) void k_bnapply(
    uint4* __restrict__ z, const float* __restrict__ scsh, int n16){
  int i = blockIdx.x*blockDim.x + threadIdx.x;   // one uint4 = 8 elems
  if (i >= n16) return;
  int f8 = (i & 15) * 8;
  uint4 v = z[i];
  uint r[4];
  #pragma unroll
  for (int p = 0; p < 4; ++p){
    uint  u  = (&v.x)[p];
    float z0 = bf2f((ushort)(u & 0xffff));
    float z1 = bf2f((ushort)(u >> 16));
    float y0 = fmaxf(fmaf(z0, scsh[f8 + p*2],     scsh[128 + f8 + p*2]),     0.f);
    float y1 = fmaxf(fmaf(z1, scsh[f8 + p*2 + 1], scsh[128 + f8 + p*2 + 1]), 0.f);
    r[p] = (uint)f2bf(y0) | ((uint)f2bf(y1) << 16);
  }
  z[i] = make_uint4(r[0], r[1], r[2], r[3]);
}

// ---------------- MFMA GEMM for input layer: xw = x(f32) @ lin0T^T ----------

__global__ __launch_bounds__(256) void k_gemm0(
    const float* __restrict__ Af, const ushort* __restrict__ BT,
    ushort* __restrict__ Cb, int n){
  const int K = 256;
  __shared__ ushort As[64*32];
  __shared__ ushort Bs[128*32];
  int t = threadIdx.x;
  int br = blockIdx.x * 64;
  int w = t >> 6, l = t & 63;
  int lr = l & 15, lk = l >> 4;
  int swz = (lr >> 1) & 3;

  f32x4 acc[8];
  #pragma unroll
  for (int i = 0; i < 8; ++i) acc[i] = (f32x4){0.f,0.f,0.f,0.f};

  int sar = t >> 2;
  int sab = t & 3;
  int sa_off = sar*32 + ((sab ^ ((sar>>1)&3))*8);

  for (int k0 = 0; k0 < K; k0 += 32){
    int grow = br + sar;
    float4 v0 = make_float4(0.f,0.f,0.f,0.f), v1 = v0;
    if (grow < n){
      v0 = *(const float4*)(Af + (size_t)grow*K + k0 + sab*8);
      v1 = *(const float4*)(Af + (size_t)grow*K + k0 + sab*8 + 4);
    }
    ushort tmp[8] = {f2bf(v0.x),f2bf(v0.y),f2bf(v0.z),f2bf(v0.w),
                     f2bf(v1.x),f2bf(v1.y),f2bf(v1.z),f2bf(v1.w)};
    *(uint4*)(&As[sa_off]) = *(const uint4*)tmp;
    #pragma unroll
    for (int i = 0; i < 2; ++i){
      int qq = t + i*256;
      int nrow = qq >> 2, bb = qq & 3;
      uint4 v = *(const uint4*)(BT + (size_t)nrow*K + k0 + bb*8);
      *(uint4*)(&Bs[nrow*32 + ((bb ^ ((nrow>>1)&3))*8)]) = v;
    }
    __syncthreads();
    short8 af = *(const short8*)(&As[(w*16+lr)*32 + ((lk ^ swz)*8)]);
    #pragma unroll
    for (int tn = 0; tn < 8; ++tn){
      short8 bfv = *(const short8*)(&Bs[(tn*16+lr)*32 + ((lk ^ swz)*8)]);
      acc[tn] = __builtin_amdgcn_mfma_f32_16x16x32_bf16(af, bfv, acc[tn], 0, 0, 0);
    }
    __syncthreads();
  }
  int orow = br + w*16 + lk*4;
  #pragma unroll
  for (int tn = 0; tn < 8; ++tn){
    #pragma unroll
    for (int j = 0; j < 4; ++j){
      float mine  = acc[tn][j];
      float other = __shfl(mine, l ^ 1);
      if (!(l & 1) && (orow + j) < n){
        uint pk = (uint)f2bf(mine) | ((uint)f2bf(other) << 16);
        ((uint*)Cb)[(size_t)(orow+j)*64 + tn*8 + (lr >> 1)] = pk;
      }
    }
  }
}

// ---------------- launch ----------------

extern "C" void kernel_launch(void* const* d_in, const int* in_sizes, int n_in,
                              void* d_out, int out_size, void* d_ws, size_t ws_size,
                              hipStream_t stream){
  const float* x        = (const float*)d_in[0];
  const int*   ei       = (const int*)  d_in[1];
  const float* lin0_w   = (const float*)d_in[2];
  const float* lin0_b   = (const float*)d_in[3];
  const float* conv_w   = (const float*)d_in[4];
  const float* bn_gamma = (const float*)d_in[5];
  const float* bn_beta  = (const float*)d_in[6];
  float* out = (float*)d_out;

  int N = in_sizes[0] / 256;
  int E = in_sizes[1] / 2;
  const int* row = ei;
  const int* col = ei + E;

  char* ws = (char*)d_ws;
  size_t p = 0;
  auto alloc = [&](size_t bytes)->char*{
    char* r = ws + p; p = (p + bytes + 255) & ~(size_t)255; return r;
  };
  int*    cnt    = (int*)   alloc((size_t)N*4);
  int*    off    = (int*)   alloc((size_t)(N+1)*4);
  int*    cursor = (int*)   alloc((size_t)N*4);
  float*  dinv   = (float*) alloc((size_t)N*4);
  int*    bsum   = (int*)   alloc(512*4);
  int*    dh     = (int*)   alloc(256*4);
  int*    perm   = (int*)   alloc((size_t)N*4);
  uint2*  edge   = (uint2*) alloc((size_t)E*8);
  ushort* zb     = (ushort*)alloc((size_t)N*H*2);
  ushort* sb     = (ushort*)alloc((size_t)N*H*2);   // xw, then ping-pong z
  ushort* x0b    = (ushort*)alloc((size_t)N*H*2);
  ushort* lin0T  = (ushort*)alloc(128*256*2);
  ushort* WpT    = (ushort*)alloc(4*128*128*2);
  float*  stats  = (float*) alloc(RSTATS*256*4);
  float*  scsh   = (float*) alloc(2*128*4);

  float betas[4];
  for (int i = 0; i < 4; ++i) betas[i] = logf(0.5f/(float)(i+1) + 1.0f);
  float inv_n = 1.0f/(float)N;

  // ---- CSR build + degree-sort perm (LDS-aggregated) ----
  hipMemsetAsync(cnt, 0, (size_t)N*4, stream);
  hipMemsetAsync(dh, 0, 256*4, stream);
  k_count<<<(E+255)/256, 256, 0, stream>>>(col, E, cnt);
  int nb1k = (N + 1023)/1024;
  k_dhist<<<nb1k, 1024, 0, stream>>>(cnt, dh, N);
  k_dscan<<<1, 256, 0, stream>>>(dh);
  k_dperm<<<nb1k, 1024, 0, stream>>>(cnt, dh, perm, N);
  k_scan1<<<nb1k, 1024, 0, stream>>>(cnt, off, bsum, dinv, N);
  k_scan2<<<1, 64, 0, stream>>>(bsum, nb1k);
  k_scan3<<<(N+255)/256, 256, 0, stream>>>(off, cursor, bsum, N, E);
  k_fill <<<(E+255)/256, 256, 0, stream>>>(row, col, E, dinv, cursor, edge);

  k_prepw<<<(128*256 + 4*128*128 + 255)/256, 256, 0, stream>>>(
      lin0_w, conv_w, lin0T, WpT, betas[0], betas[1], betas[2], betas[3]);

  int gemm_blocks = (N + 63)/64;
  int lay_blocks  = (N + 31)/32;
  int prop_blocks = (N + 15)/16;      // 16 quads (nodes) per 256-thread block
  int bn_blocks   = ((N*16) + 255)/256;

  // ---- input layer: xw = x @ lin0 ; x0 = prop(xw)+b  (z0 == x0) ----
  k_gemm0<<<gemm_blocks, 256, 0, stream>>>(x, lin0T, sb, N);
  k_prop0<<<prop_blocks, 256, 0, stream>>>(sb, off, edge, dinv, lin0_b, perm, x0b, N);

  hipMemsetAsync(stats, 0, RSTATS*256*4, stream);   // once; k_bnfinal re-zeroes

  // ---- layer 0: zin=x0b (== x0) -> zout=sb, stats; then BN in place ----
  k_layer<true,false,true><<<lay_blocks, 256, 0, stream>>>(
      x0b, x0b, off, edge, dinv, WpT + 0*128*128, perm, sb, stats, N);
  k_bnfinal<<<1, 128, 0, stream>>>(stats, bn_gamma + 0*H, bn_beta + 0*H, scsh, inv_n);
  k_bnapply<<<bn_blocks, 256, 0, stream>>>((uint4*)sb, scsh, N*16);

  // ---- layer 1: zin=sb -> zout=zb, stats; BN in place ----
  k_layer<true,false,false><<<lay_blocks, 256, 0, stream>>>(
      sb, x0b, off, edge, dinv, WpT + 1*128*128, perm, zb, stats, N);
  k_bnfinal<<<1, 128, 0, stream>>>(stats, bn_gamma + 1*H, bn_beta + 1*H, scsh, inv_n);
  k_bnapply<<<bn_blocks, 256, 0, stream>>>((uint4*)zb, scsh, N*16);

  // ---- layer 2: zin=zb -> zout=sb, stats; BN in place ----
  k_layer<true,false,false><<<lay_blocks, 256, 0, stream>>>(
      zb, x0b, off, edge, dinv, WpT + 2*128*128, perm, sb, stats, N);
  k_bnfinal<<<1, 128, 0, stream>>>(stats, bn_gamma + 2*H, bn_beta + 2*H, scsh, inv_n);
  k_bnapply<<<bn_blocks, 256, 0, stream>>>((uint4*)sb, scsh, N*16);

  // ---- layer 3: zin=sb -> out (f32), no stats ----
  k_layer<false,true,false><<<lay_blocks, 256, 0, stream>>>(
      sb, x0b, off, edge, dinv, WpT + 3*128*128, perm, out, nullptr, N);
}

// Round 15
// 603.212 us; speedup vs baseline: 1.1298x; 1.0156x over previous
//
#include <hip/hip_runtime.h>
#include <hip/hip_bf16.h>
#include <math.h>

#define H 128
#define EPS_BN 1e-5f
#define RSTATS 16

typedef __attribute__((ext_vector_type(8))) short short8;
typedef __attribute__((ext_vector_type(4))) float f32x4;

__device__ __forceinline__ float bf2f(ushort u){
  union { float f; uint v; } x; x.v = ((uint)u) << 16; return x.f;
}
__device__ __forceinline__ ushort f2bf(float f){
  union { float f; uint v; } x; x.f = f;
  uint v = x.v;
  uint r = v + 0x7fff + ((v >> 16) & 1);   // RNE
  return (ushort)(r >> 16);
}

__device__ __forceinline__ void acc8(float* a, uint4 v, float wt){
  a[0] += wt*bf2f((ushort)(v.x & 0xffff)); a[1] += wt*bf2f((ushort)(v.x >> 16));
  a[2] += wt*bf2f((ushort)(v.y & 0xffff)); a[3] += wt*bf2f((ushort)(v.y >> 16));
  a[4] += wt*bf2f((ushort)(v.z & 0xffff)); a[5] += wt*bf2f((ushort)(v.z >> 16));
  a[6] += wt*bf2f((ushort)(v.w & 0xffff)); a[7] += wt*bf2f((ushort)(v.w >> 16));
}

// ---------------- CSR build ----------------

__global__ void k_count(const int* __restrict__ col, int E, int* __restrict__ cnt){
  int i = blockIdx.x*blockDim.x + threadIdx.x;
  if (i < E) atomicAdd(&cnt[col[i]], 1);
}

__global__ void k_scan1(const int* __restrict__ cnt, int* __restrict__ off,
                        int* __restrict__ bsum, float* __restrict__ dinv, int n){
  __shared__ int s[1024];
  int t = threadIdx.x;
  int i = blockIdx.x*1024 + t;
  int v = (i < n) ? cnt[i] : 0;
  if (i < n) dinv[i] = rsqrtf((float)v + 1.0f);   // +1 self-loop
  s[t] = v; __syncthreads();
  for (int d = 1; d < 1024; d <<= 1){
    int x = (t >= d) ? s[t-d] : 0;
    __syncthreads();
    s[t] += x;
    __syncthreads();
  }
  if (i < n) off[i] = s[t] - v;
  if (t == 1023) bsum[blockIdx.x] = s[1023];
}

__global__ void k_scan2(int* bsum, int nb){
  int l = threadIdx.x;           // 64 threads, 1 block
  int carry = 0;
  for (int b0 = 0; b0 < nb; b0 += 64){
    int i = b0 + l;
    int orig = (i < nb) ? bsum[i] : 0;
    int v = orig;
    #pragma unroll
    for (int d = 1; d < 64; d <<= 1){
      int x = __shfl_up(v, d);
      if (l >= d) v += x;
    }
    if (i < nb) bsum[i] = carry + v - orig;   // exclusive
    carry += __shfl(v, 63);
  }
}

__global__ void k_scan3(int* __restrict__ off, int* __restrict__ cursor,
                        const int* __restrict__ bsum, int n, int Etot){
  int i = blockIdx.x*blockDim.x + threadIdx.x;
  if (i < n){ int o = off[i] + bsum[i >> 10]; off[i] = o; cursor[i] = o; }
  if (i == 0) off[n] = Etot;
}

// edge record = {permuted source row, weight}
__global__ void k_fill(const int* __restrict__ row, const int* __restrict__ col, int E,
                       const float* __restrict__ dinv, const int* __restrict__ iperm,
                       int* __restrict__ cursor, uint2* __restrict__ edge){
  int i = blockIdx.x*blockDim.x + threadIdx.x;
  if (i < E){
    int c = col[i], r = row[i];
    int p = atomicAdd(&cursor[c], 1);
    edge[p] = make_uint2((uint)iperm[r], __float_as_uint(dinv[r]*dinv[c]));
  }
}

// -------- degree-sort permutation (DESCENDING): LDS-aggregated counting sort --

__global__ __launch_bounds__(1024) void k_dhist(
    const int* __restrict__ cnt, int* __restrict__ dh, int n){
  __shared__ int lh[256];
  int t = threadIdx.x;
  if (t < 256) lh[t] = 0;
  __syncthreads();
  int i = blockIdx.x*1024 + t;
  if (i < n){
    int d = cnt[i]; if (d > 255) d = 255;
    atomicAdd(&lh[d], 1);
  }
  __syncthreads();
  if (t < 256 && lh[t]) atomicAdd(&dh[t], lh[t]);
}

__global__ void k_dscan(int* __restrict__ dh){   // 1 block, 256 thr; DESC offsets
  __shared__ int s[256];
  int t = threadIdx.x;
  int v = dh[255 - t];              // reversed order
  s[t] = v; __syncthreads();
  for (int d = 1; d < 256; d <<= 1){
    int x = (t >= d) ? s[t-d] : 0;
    __syncthreads();
    s[t] += x;
    __syncthreads();
  }
  dh[255 - t] = s[t] - v;   // bin d offset = count of nodes with degree > d
}

__global__ __launch_bounds__(1024) void k_dperm(
    const int* __restrict__ cnt, int* __restrict__ dh,
    int* __restrict__ perm, int* __restrict__ iperm, int n){
  __shared__ int lh[256];
  __shared__ int lbase[256];
  int t = threadIdx.x;
  if (t < 256) lh[t] = 0;
  __syncthreads();
  int i = blockIdx.x*1024 + t;
  int d = 0, li = 0;
  if (i < n){
    d = cnt[i]; if (d > 255) d = 255;
    li = atomicAdd(&lh[d], 1);
  }
  __syncthreads();
  if (t < 256){
    int c = lh[t];
    lbase[t] = c ? atomicAdd(&dh[t], c) : 0;
  }
  __syncthreads();
  if (i < n){
    int pos = lbase[d] + li;
    perm[pos] = i;
    iperm[i] = pos;
  }
}

// ---------------- weight prep: bf16, transposed, beta-folded ----------------

__global__ void k_prepw(const float* __restrict__ lin0_w, const float* __restrict__ conv_w,
                        ushort* __restrict__ lin0T, ushort* __restrict__ WpT,
                        float b0, float b1, float b2, float b3){
  int i = blockIdx.x*blockDim.x + threadIdx.x;
  if (i < 128*256){
    int nn = i >> 8, k = i & 255;
    lin0T[i] = f2bf(lin0_w[k*128 + nn]);
  } else if (i < 128*256 + 4*128*128){
    int j = i - 128*256;
    int ll = j >> 14, rc = j & 16383;
    int nn = rc >> 7, k = rc & 127;
    float beta = (ll==0)?b0:(ll==1)?b1:(ll==2)?b2:b3;
    float v = beta * conv_w[ll*16384 + k*128 + nn];
    if (k == nn) v += 1.0f - beta;
    WpT[j] = f2bf(v);
  }
}

// ---------------- gather core: edges only; one quad (16 lanes) per node -----
// edge.x is the PERMUTED source row; zin is in permuted layout.

__device__ __forceinline__ void gather_edges(
    float* a, const ushort* __restrict__ zin, const uint2* __restrict__ edge,
    int e0, int e1, int lr){
  int e = e0;
  for (; e + 3 < e1; e += 4){
    uint2 er0 = edge[e],   er1 = edge[e+1];
    uint2 er2 = edge[e+2], er3 = edge[e+3];
    uint4 v0 = *(const uint4*)(zin + (size_t)er0.x*H + lr*8);
    uint4 v1 = *(const uint4*)(zin + (size_t)er1.x*H + lr*8);
    uint4 v2 = *(const uint4*)(zin + (size_t)er2.x*H + lr*8);
    uint4 v3 = *(const uint4*)(zin + (size_t)er3.x*H + lr*8);
    acc8(a, v0, __uint_as_float(er0.y));
    acc8(a, v1, __uint_as_float(er1.y));
    acc8(a, v2, __uint_as_float(er2.y));
    acc8(a, v3, __uint_as_float(er3.y));
  }
  for (; e < e1; ++e){
    uint2 er = edge[e];
    uint4 v = *(const uint4*)(zin + (size_t)er.x*H + lr*8);
    acc8(a, v, __uint_as_float(er.y));
  }
}

// ---------------- input-layer prop: x0 = agg(xw)+b ; permuted layout --------

__global__ __launch_bounds__(256) void k_prop0(
    const ushort* __restrict__ h, const int* __restrict__ off,
    const uint2* __restrict__ edge, const float* __restrict__ dinv,
    const float* __restrict__ bias, const int* __restrict__ perm,
    ushort* __restrict__ x0, int n){
  int pq = (blockIdx.x*blockDim.x + threadIdx.x) >> 4;   // permuted row
  if (pq >= n) return;
  int gq = perm[pq];                 // original node (off/dinv)
  int lr = threadIdx.x & 15;
  float a[8];
  #pragma unroll
  for (int j = 0; j < 8; ++j) a[j] = 0.f;
  float wc = dinv[gq]; wc *= wc;
  uint4 vs = *(const uint4*)(h + (size_t)pq*H + lr*8);   // self: permuted row
  gather_edges(a, h, edge, off[gq], off[gq+1], lr);
  acc8(a, vs, wc);
  float4 b0 = *(const float4*)(bias + lr*8);
  float4 b1 = *(const float4*)(bias + lr*8 + 4);
  uint4 pk;
  pk.x = (uint)f2bf(a[0]+b0.x) | ((uint)f2bf(a[1]+b0.y) << 16);
  pk.y = (uint)f2bf(a[2]+b0.z) | ((uint)f2bf(a[3]+b0.w) << 16);
  pk.z = (uint)f2bf(a[4]+b1.x) | ((uint)f2bf(a[5]+b1.y) << 16);
  pk.w = (uint)f2bf(a[6]+b1.z) | ((uint)f2bf(a[7]+b1.w) << 16);
  *(uint4*)(x0 + (size_t)pq*H + lr*8) = pk;              // contiguous write
}

// ---------------- fused layer: prop -> LDS s-tile -> MFMA GEMM -> z (+stats) --
// Activations in permuted layout; rows base..base+31 are same-degree (heavy
// first = LJF). bf16 z written contiguously; only OUTF32 scatters to original.

template<bool STATS, bool OUTF32, bool SAMEX0>
__global__ __launch_bounds__(256) void k_layer(
    const ushort* __restrict__ zin, const ushort* __restrict__ x0,
    const int* __restrict__ off, const uint2* __restrict__ edge,
    const float* __restrict__ dinv, const ushort* __restrict__ BT,
    const int* __restrict__ perm,
    void* __restrict__ zout, float* __restrict__ stats, int n)
{
  __shared__ ushort Sm[32*128];   // swizzled s tile: row*128 + ((blk16^(row&15))*8)
  __shared__ int pm[32];
  int t = threadIdx.x;
  int w = t >> 6, l = t & 63;
  int lr = l & 15, q = l >> 4;
  int base = blockIdx.x * 32;
  if (t < 32) pm[t] = (base + t < n) ? perm[base + t] : -1;
  __syncthreads();

  // ---- prop phase: quad-per-node, 2 nodes per quad ----
  #pragma unroll
  for (int g2 = 0; g2 < 2; ++g2){
    int row  = w*8 + g2*4 + q;
    int node = pm[row];             // original id (off/dinv only)
    int grow = base + row;          // permuted row (addresses)
    float a[8];
    #pragma unroll
    for (int j = 0; j < 8; ++j) a[j] = 0.f;
    uint4 pk = make_uint4(0u,0u,0u,0u);
    if (node >= 0){
      float wc = dinv[node]; wc *= wc;
      uint4 vs = *(const uint4*)(zin + (size_t)grow*H + lr*8);
      gather_edges(a, zin, edge, off[node], off[node+1], lr);
      acc8(a, vs, wc);
      uint4 xv = SAMEX0 ? vs : *(const uint4*)(x0 + (size_t)grow*H + lr*8);
      float s0 = 0.9f*a[0] + 0.1f*bf2f((ushort)(xv.x & 0xffff));
      float s1 = 0.9f*a[1] + 0.1f*bf2f((ushort)(xv.x >> 16));
      float s2 = 0.9f*a[2] + 0.1f*bf2f((ushort)(xv.y & 0xffff));
      float s3 = 0.9f*a[3] + 0.1f*bf2f((ushort)(xv.y >> 16));
      float s4 = 0.9f*a[4] + 0.1f*bf2f((ushort)(xv.z & 0xffff));
      float s5 = 0.9f*a[5] + 0.1f*bf2f((ushort)(xv.z >> 16));
      float s6 = 0.9f*a[6] + 0.1f*bf2f((ushort)(xv.w & 0xffff));
      float s7 = 0.9f*a[7] + 0.1f*bf2f((ushort)(xv.w >> 16));
      pk.x = (uint)f2bf(s0) | ((uint)f2bf(s1) << 16);
      pk.y = (uint)f2bf(s2) | ((uint)f2bf(s3) << 16);
      pk.z = (uint)f2bf(s4) | ((uint)f2bf(s5) << 16);
      pk.w = (uint)f2bf(s6) | ((uint)f2bf(s7) << 16);
    }
    *(uint4*)(&Sm[row*128 + ((lr ^ (row & 15))*8)]) = pk;
  }

  // ---- B fragments (W'^T slice for this wave's 32 cols) ----
  short8 bfr[2][4];
  #pragma unroll
  for (int c = 0; c < 2; ++c)
    #pragma unroll
    for (int ks = 0; ks < 4; ++ks)
      bfr[c][ks] = *(const short8*)(BT + (size_t)(w*32 + c*16 + lr)*H + ks*32 + q*8);

  __syncthreads();

  // ---- GEMM phase: 32 rows x 32 cols per wave ----
  f32x4 acc[2][2];
  #pragma unroll
  for (int rt = 0; rt < 2; ++rt){
    acc[rt][0] = (f32x4){0.f,0.f,0.f,0.f};
    acc[rt][1] = (f32x4){0.f,0.f,0.f,0.f};
  }
  #pragma unroll
  for (int rt = 0; rt < 2; ++rt){
    int row = rt*16 + lr;
    #pragma unroll
    for (int ks = 0; ks < 4; ++ks){
      short8 af = *(const short8*)(&Sm[row*128 + (((ks*4 + q) ^ (row & 15))*8)]);
      acc[rt][0] = __builtin_amdgcn_mfma_f32_16x16x32_bf16(af, bfr[0][ks], acc[rt][0], 0,0,0);
      acc[rt][1] = __builtin_amdgcn_mfma_f32_16x16x32_bf16(af, bfr[1][ks], acc[rt][1], 0,0,0);
    }
  }

  // ---- epilogue: bf16 -> contiguous permuted rows; f32 -> original rows ----
  #pragma unroll
  for (int rt = 0; rt < 2; ++rt){
    #pragma unroll
    for (int c = 0; c < 2; ++c){
      #pragma unroll
      for (int j2 = 0; j2 < 4; ++j2){
        int rowl = rt*16 + q*4 + j2;
        float v = acc[rt][c][j2];
        if (OUTF32){
          int nodeo = pm[rowl];
          if (nodeo >= 0)
            ((float*)zout)[(size_t)nodeo*H + w*32 + c*16 + lr] = v;
        } else {
          int growl = base + rowl;
          float other = __shfl(v, l ^ 1);
          if (!(lr & 1) && growl < n){
            uint pk = (uint)f2bf(v) | ((uint)f2bf(other) << 16);
            ((uint*)zout)[(size_t)growl*64 + w*16 + c*8 + (lr >> 1)] = pk;
          }
        }
      }
    }
  }
  if (STATS){
    #pragma unroll
    for (int c = 0; c < 2; ++c){
      float sv = 0.f, sq = 0.f;
      #pragma unroll
      for (int rt = 0; rt < 2; ++rt)
        #pragma unroll
        for (int j2 = 0; j2 < 4; ++j2){
          float v = acc[rt][c][j2];   // invalid rows have s=0 -> acc=0
          sv += v; sq += v*v;
        }
      sv += __shfl(sv, l ^ 16); sv += __shfl(sv, l ^ 32);
      sq += __shfl(sq, l ^ 16); sq += __shfl(sq, l ^ 32);
      if (q == 0){
        float* st = stats + (size_t)(blockIdx.x & (RSTATS-1))*256;
        atomicAdd(&st[w*32 + c*16 + lr], sv);
        atomicAdd(&st[128 + w*32 + c*16 + lr], sq);
      }
    }
  }
}

// ---------------- BN finalize: stats replicas -> scale/shift; re-zero -------

__global__ void k_bnfinal(float* __restrict__ stats, const float* __restrict__ gamma,
                          const float* __restrict__ beta, float* __restrict__ scsh,
                          float inv_n){
  int f = threadIdx.x;   // 128
  float s = 0.f, s2 = 0.f;
  for (int r = 0; r < RSTATS; ++r){
    s  += stats[r*256 + f];
    s2 += stats[r*256 + 128 + f];
    stats[r*256 + f] = 0.f;          // re-zero for next layer
    stats[r*256 + 128 + f] = 0.f;
  }
  float mu  = s * inv_n;
  float var = s2 * inv_n - mu*mu;
  float sc  = rsqrtf(var + EPS_BN) * gamma[f];
  scsh[f]       = sc;
  scsh[128 + f] = beta[f] - mu*sc;
}

// ---------------- BN apply (in place): y = relu(z*sc + sh), bf16 ----------

__global__ __launch_bounds__(256) void k_bnapply(
    uint4* __restrict__ z, const float* __restrict__ scsh, int n16){
  int i = blockIdx.x*blockDim.x + threadIdx.x;   // one uint4 = 8 elems
  if (i >= n16) return;
  int f8 = (i & 15) * 8;
  uint4 v = z[i];
  uint r[4];
  #pragma unroll
  for (int p = 0; p < 4; ++p){
    uint  u  = (&v.x)[p];
    float z0 = bf2f((ushort)(u & 0xffff));
    float z1 = bf2f((ushort)(u >> 16));
    float y0 = fmaxf(fmaf(z0, scsh[f8 + p*2],     scsh[128 + f8 + p*2]),     0.f);
    float y1 = fmaxf(fmaf(z1, scsh[f8 + p*2 + 1], scsh[128 + f8 + p*2 + 1]), 0.f);
    r[p] = (uint)f2bf(y0) | ((uint)f2bf(y1) << 16);
  }
  z[i] = make_uint4(r[0], r[1], r[2], r[3]);
}

// ---------------- MFMA GEMM for input layer: xw = x(perm rows) @ lin0T^T ----

__global__ __launch_bounds__(256) void k_gemm0(
    const float* __restrict__ Af, const ushort* __restrict__ BT,
    const int* __restrict__ perm, ushort* __restrict__ Cb, int n){
  const int K = 256;
  __shared__ ushort As[64*32];
  __shared__ ushort Bs[128*32];
  __shared__ int pmr[64];
  int t = threadIdx.x;
  int br = blockIdx.x * 64;
  int w = t >> 6, l = t & 63;
  int lr = l & 15, lk = l >> 4;
  int swz = (lr >> 1) & 3;
  if (t < 64) pmr[t] = (br + t < n) ? perm[br + t] : -1;
  __syncthreads();

  f32x4 acc[8];
  #pragma unroll
  for (int i = 0; i < 8; ++i) acc[i] = (f32x4){0.f,0.f,0.f,0.f};

  int sar = t >> 2;
  int sab = t & 3;
  int sa_off = sar*32 + ((sab ^ ((sar>>1)&3))*8);

  for (int k0 = 0; k0 < K; k0 += 32){
    int grow = pmr[sar];              // original row of x
    float4 v0 = make_float4(0.f,0.f,0.f,0.f), v1 = v0;
    if (grow >= 0){
      v0 = *(const float4*)(Af + (size_t)grow*K + k0 + sab*8);
      v1 = *(const float4*)(Af + (size_t)grow*K + k0 + sab*8 + 4);
    }
    ushort tmp[8] = {f2bf(v0.x),f2bf(v0.y),f2bf(v0.z),f2bf(v0.w),
                     f2bf(v1.x),f2bf(v1.y),f2bf(v1.z),f2bf(v1.w)};
    *(uint4*)(&As[sa_off]) = *(const uint4*)tmp;
    #pragma unroll
    for (int i = 0; i < 2; ++i){
      int qq = t + i*256;
      int nrow = qq >> 2, bb = qq & 3;
      uint4 v = *(const uint4*)(BT + (size_t)nrow*K + k0 + bb*8);
      *(uint4*)(&Bs[nrow*32 + ((bb ^ ((nrow>>1)&3))*8)]) = v;
    }
    __syncthreads();
    short8 af = *(const short8*)(&As[(w*16+lr)*32 + ((lk ^ swz)*8)]);
    #pragma unroll
    for (int tn = 0; tn < 8; ++tn){
      short8 bfv = *(const short8*)(&Bs[(tn*16+lr)*32 + ((lk ^ swz)*8)]);
      acc[tn] = __builtin_amdgcn_mfma_f32_16x16x32_bf16(af, bfv, acc[tn], 0, 0, 0);
    }
    __syncthreads();
  }
  int orow = br + w*16 + lk*4;        // permuted layout, contiguous
  #pragma unroll
  for (int tn = 0; tn < 8; ++tn){
    #pragma unroll
    for (int j = 0; j < 4; ++j){
      float mine  = acc[tn][j];
      float other = __shfl(mine, l ^ 1);
      if (!(l & 1) && (orow + j) < n){
        uint pk = (uint)f2bf(mine) | ((uint)f2bf(other) << 16);
        ((uint*)Cb)[(size_t)(orow+j)*64 + tn*8 + (lr >> 1)] = pk;
      }
    }
  }
}

// ---------------- launch ----------------

extern "C" void kernel_launch(void* const* d_in, const int* in_sizes, int n_in,
                              void* d_out, int out_size, void* d_ws, size_t ws_size,
                              hipStream_t stream){
  const float* x        = (const float*)d_in[0];
  const int*   ei       = (const int*)  d_in[1];
  const float* lin0_w   = (const float*)d_in[2];
  const float* lin0_b   = (const float*)d_in[3];
  const float* conv_w   = (const float*)d_in[4];
  const float* bn_gamma = (const float*)d_in[5];
  const float* bn_beta  = (const float*)d_in[6];
  float* out = (float*)d_out;

  int N = in_sizes[0] / 256;
  int E = in_sizes[1] / 2;
  const int* row = ei;
  const int* col = ei + E;

  char* ws = (char*)d_ws;
  size_t p = 0;
  auto alloc = [&](size_t bytes)->char*{
    char* r = ws + p; p = (p + bytes + 255) & ~(size_t)255; return r;
  };
  int*    cnt    = (int*)   alloc((size_t)N*4);
  int*    off    = (int*)   alloc((size_t)(N+1)*4);
  int*    cursor = (int*)   alloc((size_t)N*4);
  float*  dinv   = (float*) alloc((size_t)N*4);
  int*    bsum   = (int*)   alloc(512*4);
  int*    dh     = (int*)   alloc(256*4);
  int*    perm   = (int*)   alloc((size_t)N*4);
  int*    iperm  = (int*)   alloc((size_t)N*4);
  uint2*  edge   = (uint2*) alloc((size_t)E*8);
  ushort* zb     = (ushort*)alloc((size_t)N*H*2);
  ushort* sb     = (ushort*)alloc((size_t)N*H*2);   // xw, then ping-pong z
  ushort* x0b    = (ushort*)alloc((size_t)N*H*2);
  ushort* lin0T  = (ushort*)alloc(128*256*2);
  ushort* WpT    = (ushort*)alloc(4*128*128*2);
  float*  stats  = (float*) alloc(RSTATS*256*4);
  float*  scsh   = (float*) alloc(2*128*4);

  float betas[4];
  for (int i = 0; i < 4; ++i) betas[i] = logf(0.5f/(float)(i+1) + 1.0f);
  float inv_n = 1.0f/(float)N;

  // ---- CSR build + degree-sort perm (descending; LDS-aggregated) ----
  hipMemsetAsync(cnt, 0, (size_t)N*4, stream);
  hipMemsetAsync(dh, 0, 256*4, stream);
  k_count<<<(E+255)/256, 256, 0, stream>>>(col, E, cnt);
  int nb1k = (N + 1023)/1024;
  k_dhist<<<nb1k, 1024, 0, stream>>>(cnt, dh, N);
  k_dscan<<<1, 256, 0, stream>>>(dh);
  k_dperm<<<nb1k, 1024, 0, stream>>>(cnt, dh, perm, iperm, N);
  k_scan1<<<nb1k, 1024, 0, stream>>>(cnt, off, bsum, dinv, N);
  k_scan2<<<1, 64, 0, stream>>>(bsum, nb1k);
  k_scan3<<<(N+255)/256, 256, 0, stream>>>(off, cursor, bsum, N, E);
  k_fill <<<(E+255)/256, 256, 0, stream>>>(row, col, E, dinv, iperm, cursor, edge);

  k_prepw<<<(128*256 + 4*128*128 + 255)/256, 256, 0, stream>>>(
      lin0_w, conv_w, lin0T, WpT, betas[0], betas[1], betas[2], betas[3]);

  int gemm_blocks = (N + 63)/64;
  int lay_blocks  = (N + 31)/32;
  int prop_blocks = (N + 15)/16;      // 16 quads (nodes) per 256-thread block
  int bn_blocks   = ((N*16) + 255)/256;

  // ---- input layer: xw = x @ lin0 (permuted rows); x0 = prop(xw)+b ----
  k_gemm0<<<gemm_blocks, 256, 0, stream>>>(x, lin0T, perm, sb, N);
  k_prop0<<<prop_blocks, 256, 0, stream>>>(sb, off, edge, dinv, lin0_b, perm, x0b, N);

  hipMemsetAsync(stats, 0, RSTATS*256*4, stream);   // once; k_bnfinal re-zeroes

  // ---- layer 0: zin=x0b (== x0) -> zout=sb, stats; then BN in place ----
  k_layer<true,false,true><<<lay_blocks, 256, 0, stream>>>(
      x0b, x0b, off, edge, dinv, WpT + 0*128*128, perm, sb, stats, N);
  k_bnfinal<<<1, 128, 0, stream>>>(stats, bn_gamma + 0*H, bn_beta + 0*H, scsh, inv_n);
  k_bnapply<<<bn_blocks, 256, 0, stream>>>((uint4*)sb, scsh, N*16);

  // ---- layer 1: zin=sb -> zout=zb, stats; BN in place ----
  k_layer<true,false,false><<<lay_blocks, 256, 0, stream>>>(
      sb, x0b, off, edge, dinv, WpT + 1*128*128, perm, zb, stats, N);
  k_bnfinal<<<1, 128, 0, stream>>>(stats, bn_gamma + 1*H, bn_beta + 1*H, scsh, inv_n);
  k_bnapply<<<bn_blocks, 256, 0, stream>>>((uint4*)zb, scsh, N*16);

  // ---- layer 2: zin=zb -> zout=sb, stats; BN in place ----
  k_layer<true,false,false><<<lay_blocks, 256, 0, stream>>>(
      zb, x0b, off, edge, dinv, WpT + 2*128*128, perm, sb, stats, N);
  k_bnfinal<<<1, 128, 0, stream>>>(stats, bn_gamma + 2*H, bn_beta + 2*H, scsh, inv_n);
  k_bnapply<<<bn_blocks, 256, 0, stream>>>((uint4*)sb, scsh, N*16);

  // ---- layer 3: zin=sb -> out (f32, original rows), no stats ----
  k_layer<false,true,false><<<lay_blocks, 256, 0, stream>>>(
      sb, x0b, off, edge, dinv, WpT + 3*128*128, perm, out, nullptr, N);
}

// Round 16
// 595.444 us; speedup vs baseline: 1.1446x; 1.0130x over previous
//
#include <hip/hip_runtime.h>
#include <hip/hip_bf16.h>
#include <math.h>

#define H 128
#define EPS_BN 1e-5f
#define RSTATS 16

typedef __attribute__((ext_vector_type(8))) short short8;
typedef __attribute__((ext_vector_type(4))) float f32x4;

__device__ __forceinline__ float bf2f(ushort u){
  union { float f; uint v; } x; x.v = ((uint)u) << 16; return x.f;
}
__device__ __forceinline__ ushort f2bf(float f){
  union { float f; uint v; } x; x.f = f;
  uint v = x.v;
  uint r = v + 0x7fff + ((v >> 16) & 1);   // RNE
  return (ushort)(r >> 16);
}

__device__ __forceinline__ void acc8(float* a, uint4 v, float wt){
  a[0] += wt*bf2f((ushort)(v.x & 0xffff)); a[1] += wt*bf2f((ushort)(v.x >> 16));
  a[2] += wt*bf2f((ushort)(v.y & 0xffff)); a[3] += wt*bf2f((ushort)(v.y >> 16));
  a[4] += wt*bf2f((ushort)(v.z & 0xffff)); a[5] += wt*bf2f((ushort)(v.z >> 16));
  a[6] += wt*bf2f((ushort)(v.w & 0xffff)); a[7] += wt*bf2f((ushort)(v.w >> 16));
}

// ---------------- CSR build: XCD-owned edge passes ----------------
// block bid processes edge chunk bid>>3; commits only targets in slot (bid&7)'s
// range [n*s/8, n*(s+1)/8). Writes/atomics localize to one XCD's L2; the 8x
// chunk re-read is served by the shared L3.

__global__ __launch_bounds__(256) void k_count(
    const int* __restrict__ col, int E, int* __restrict__ cnt, int n){
  int s = blockIdx.x & 7;
  int i = (blockIdx.x >> 3)*256 + threadIdx.x;
  if (i >= E) return;
  int c = col[i];
  int lo = (int)(((long long)n * s) >> 3);
  int hi = (int)(((long long)n * (s+1)) >> 3);
  if (c >= lo && c < hi) atomicAdd(&cnt[c], 1);
}

__global__ void k_scan1(const int* __restrict__ cnt, int* __restrict__ off,
                        int* __restrict__ bsum, float* __restrict__ dinv, int n){
  __shared__ int s[1024];
  int t = threadIdx.x;
  int i = blockIdx.x*1024 + t;
  int v = (i < n) ? cnt[i] : 0;
  if (i < n) dinv[i] = rsqrtf((float)v + 1.0f);   // +1 self-loop
  s[t] = v; __syncthreads();
  for (int d = 1; d < 1024; d <<= 1){
    int x = (t >= d) ? s[t-d] : 0;
    __syncthreads();
    s[t] += x;
    __syncthreads();
  }
  if (i < n) off[i] = s[t] - v;
  if (t == 1023) bsum[blockIdx.x] = s[1023];
}

__global__ void k_scan2(int* bsum, int nb){
  int l = threadIdx.x;           // 64 threads, 1 block
  int carry = 0;
  for (int b0 = 0; b0 < nb; b0 += 64){
    int i = b0 + l;
    int orig = (i < nb) ? bsum[i] : 0;
    int v = orig;
    #pragma unroll
    for (int d = 1; d < 64; d <<= 1){
      int x = __shfl_up(v, d);
      if (l >= d) v += x;
    }
    if (i < nb) bsum[i] = carry + v - orig;   // exclusive
    carry += __shfl(v, 63);
  }
}

__global__ void k_scan3(int* __restrict__ off, int* __restrict__ cursor,
                        const int* __restrict__ bsum, int n, int Etot){
  int i = blockIdx.x*blockDim.x + threadIdx.x;
  if (i < n){ int o = off[i] + bsum[i >> 10]; off[i] = o; cursor[i] = o; }
  if (i == 0) off[n] = Etot;
}

// edge record = {permuted source row, weight}; XCD-owned write regions
__global__ __launch_bounds__(256) void k_fill(
    const int* __restrict__ row, const int* __restrict__ col, int E,
    const float* __restrict__ dinv, const int* __restrict__ iperm,
    int* __restrict__ cursor, uint2* __restrict__ edge, int n){
  int s = blockIdx.x & 7;
  int i = (blockIdx.x >> 3)*256 + threadIdx.x;
  if (i >= E) return;
  int c = col[i];
  int lo = (int)(((long long)n * s) >> 3);
  int hi = (int)(((long long)n * (s+1)) >> 3);
  if (c < lo || c >= hi) return;
  int r = row[i];
  int p = atomicAdd(&cursor[c], 1);
  edge[p] = make_uint2((uint)iperm[r], __float_as_uint(dinv[r]*dinv[c]));
}

// -------- degree-sort permutation (DESCENDING): LDS-aggregated counting sort --

__global__ __launch_bounds__(1024) void k_dhist(
    const int* __restrict__ cnt, int* __restrict__ dh, int n){
  __shared__ int lh[256];
  int t = threadIdx.x;
  if (t < 256) lh[t] = 0;
  __syncthreads();
  int i = blockIdx.x*1024 + t;
  if (i < n){
    int d = cnt[i]; if (d > 255) d = 255;
    atomicAdd(&lh[d], 1);
  }
  __syncthreads();
  if (t < 256 && lh[t]) atomicAdd(&dh[t], lh[t]);
}

__global__ void k_dscan(int* __restrict__ dh){   // 1 block, 256 thr; DESC offsets
  __shared__ int s[256];
  int t = threadIdx.x;
  int v = dh[255 - t];              // reversed order
  s[t] = v; __syncthreads();
  for (int d = 1; d < 256; d <<= 1){
    int x = (t >= d) ? s[t-d] : 0;
    __syncthreads();
    s[t] += x;
    __syncthreads();
  }
  dh[255 - t] = s[t] - v;   // bin d offset = count of nodes with degree > d
}

__global__ __launch_bounds__(1024) void k_dperm(
    const int* __restrict__ cnt, int* __restrict__ dh,
    int* __restrict__ perm, int* __restrict__ iperm, int n){
  __shared__ int lh[256];
  __shared__ int lbase[256];
  int t = threadIdx.x;
  if (t < 256) lh[t] = 0;
  __syncthreads();
  int i = blockIdx.x*1024 + t;
  int d = 0, li = 0;
  if (i < n){
    d = cnt[i]; if (d > 255) d = 255;
    li = atomicAdd(&lh[d], 1);
  }
  __syncthreads();
  if (t < 256){
    int c = lh[t];
    lbase[t] = c ? atomicAdd(&dh[t], c) : 0;
  }
  __syncthreads();
  if (i < n){
    int pos = lbase[d] + li;
    perm[pos] = i;
    iperm[i] = pos;
  }
}

// ---------------- weight prep: bf16, transposed, beta-folded ----------------

__global__ void k_prepw(const float* __restrict__ lin0_w, const float* __restrict__ conv_w,
                        ushort* __restrict__ lin0T, ushort* __restrict__ WpT,
                        float b0, float b1, float b2, float b3){
  int i = blockIdx.x*blockDim.x + threadIdx.x;
  if (i < 128*256){
    int nn = i >> 8, k = i & 255;
    lin0T[i] = f2bf(lin0_w[k*128 + nn]);
  } else if (i < 128*256 + 4*128*128){
    int j = i - 128*256;
    int ll = j >> 14, rc = j & 16383;
    int nn = rc >> 7, k = rc & 127;
    float beta = (ll==0)?b0:(ll==1)?b1:(ll==2)?b2:b3;
    float v = beta * conv_w[ll*16384 + k*128 + nn];
    if (k == nn) v += 1.0f - beta;
    WpT[j] = f2bf(v);
  }
}

// ---------------- gather core: edges only; one quad (16 lanes) per node -----
// edge.x is the PERMUTED source row; zin is in permuted layout.

__device__ __forceinline__ void gather_edges(
    float* a, const ushort* __restrict__ zin, const uint2* __restrict__ edge,
    int e0, int e1, int lr){
  int e = e0;
  for (; e + 3 < e1; e += 4){
    uint2 er0 = edge[e],   er1 = edge[e+1];
    uint2 er2 = edge[e+2], er3 = edge[e+3];
    uint4 v0 = *(const uint4*)(zin + (size_t)er0.x*H + lr*8);
    uint4 v1 = *(const uint4*)(zin + (size_t)er1.x*H + lr*8);
    uint4 v2 = *(const uint4*)(zin + (size_t)er2.x*H + lr*8);
    uint4 v3 = *(const uint4*)(zin + (size_t)er3.x*H + lr*8);
    acc8(a, v0, __uint_as_float(er0.y));
    acc8(a, v1, __uint_as_float(er1.y));
    acc8(a, v2, __uint_as_float(er2.y));
    acc8(a, v3, __uint_as_float(er3.y));
  }
  for (; e < e1; ++e){
    uint2 er = edge[e];
    uint4 v = *(const uint4*)(zin + (size_t)er.x*H + lr*8);
    acc8(a, v, __uint_as_float(er.y));
  }
}

// ---------------- input-layer prop: x0 = agg(xw)+b ; permuted layout --------

__global__ __launch_bounds__(256) void k_prop0(
    const ushort* __restrict__ h, const int* __restrict__ off,
    const uint2* __restrict__ edge, const float* __restrict__ dinv,
    const float* __restrict__ bias, const int* __restrict__ perm,
    ushort* __restrict__ x0, int n){
  int pq = (blockIdx.x*blockDim.x + threadIdx.x) >> 4;   // permuted row
  if (pq >= n) return;
  int gq = perm[pq];                 // original node (off/dinv)
  int lr = threadIdx.x & 15;
  float a[8];
  #pragma unroll
  for (int j = 0; j < 8; ++j) a[j] = 0.f;
  float wc = dinv[gq]; wc *= wc;
  uint4 vs = *(const uint4*)(h + (size_t)pq*H + lr*8);   // self: permuted row
  gather_edges(a, h, edge, off[gq], off[gq+1], lr);
  acc8(a, vs, wc);
  float4 b0 = *(const float4*)(bias + lr*8);
  float4 b1 = *(const float4*)(bias + lr*8 + 4);
  uint4 pk;
  pk.x = (uint)f2bf(a[0]+b0.x) | ((uint)f2bf(a[1]+b0.y) << 16);
  pk.y = (uint)f2bf(a[2]+b0.z) | ((uint)f2bf(a[3]+b0.w) << 16);
  pk.z = (uint)f2bf(a[4]+b1.x) | ((uint)f2bf(a[5]+b1.y) << 16);
  pk.w = (uint)f2bf(a[6]+b1.z) | ((uint)f2bf(a[7]+b1.w) << 16);
  *(uint4*)(x0 + (size_t)pq*H + lr*8) = pk;              // contiguous write
}

// ---------------- fused layer: prop -> LDS s-tile -> MFMA GEMM -> z (+stats) --
// Activations in permuted layout; rows base..base+31 are same-degree (heavy
// first = LJF). bf16 z written contiguously; only OUTF32 scatters to original.

template<bool STATS, bool OUTF32, bool SAMEX0>
__global__ __launch_bounds__(256) void k_layer(
    const ushort* __restrict__ zin, const ushort* __restrict__ x0,
    const int* __restrict__ off, const uint2* __restrict__ edge,
    const float* __restrict__ dinv, const ushort* __restrict__ BT,
    const int* __restrict__ perm,
    void* __restrict__ zout, float* __restrict__ stats, int n)
{
  __shared__ ushort Sm[32*128];   // swizzled s tile: row*128 + ((blk16^(row&15))*8)
  __shared__ int pm[32];
  int t = threadIdx.x;
  int w = t >> 6, l = t & 63;
  int lr = l & 15, q = l >> 4;
  int base = blockIdx.x * 32;
  if (t < 32) pm[t] = (base + t < n) ? perm[base + t] : -1;
  __syncthreads();

  // ---- prop phase: quad-per-node, 2 nodes per quad ----
  #pragma unroll
  for (int g2 = 0; g2 < 2; ++g2){
    int row  = w*8 + g2*4 + q;
    int node = pm[row];             // original id (off/dinv only)
    int grow = base + row;          // permuted row (addresses)
    float a[8];
    #pragma unroll
    for (int j = 0; j < 8; ++j) a[j] = 0.f;
    uint4 pk = make_uint4(0u,0u,0u,0u);
    if (node >= 0){
      float wc = dinv[node]; wc *= wc;
      uint4 vs = *(const uint4*)(zin + (size_t)grow*H + lr*8);
      gather_edges(a, zin, edge, off[node], off[node+1], lr);
      acc8(a, vs, wc);
      uint4 xv = SAMEX0 ? vs : *(const uint4*)(x0 + (size_t)grow*H + lr*8);
      float s0 = 0.9f*a[0] + 0.1f*bf2f((ushort)(xv.x & 0xffff));
      float s1 = 0.9f*a[1] + 0.1f*bf2f((ushort)(xv.x >> 16));
      float s2 = 0.9f*a[2] + 0.1f*bf2f((ushort)(xv.y & 0xffff));
      float s3 = 0.9f*a[3] + 0.1f*bf2f((ushort)(xv.y >> 16));
      float s4 = 0.9f*a[4] + 0.1f*bf2f((ushort)(xv.z & 0xffff));
      float s5 = 0.9f*a[5] + 0.1f*bf2f((ushort)(xv.z >> 16));
      float s6 = 0.9f*a[6] + 0.1f*bf2f((ushort)(xv.w & 0xffff));
      float s7 = 0.9f*a[7] + 0.1f*bf2f((ushort)(xv.w >> 16));
      pk.x = (uint)f2bf(s0) | ((uint)f2bf(s1) << 16);
      pk.y = (uint)f2bf(s2) | ((uint)f2bf(s3) << 16);
      pk.z = (uint)f2bf(s4) | ((uint)f2bf(s5) << 16);
      pk.w = (uint)f2bf(s6) | ((uint)f2bf(s7) << 16);
    }
    *(uint4*)(&Sm[row*128 + ((lr ^ (row & 15))*8)]) = pk;
  }

  // ---- B fragments (W'^T slice for this wave's 32 cols) ----
  short8 bfr[2][4];
  #pragma unroll
  for (int c = 0; c < 2; ++c)
    #pragma unroll
    for (int ks = 0; ks < 4; ++ks)
      bfr[c][ks] = *(const short8*)(BT + (size_t)(w*32 + c*16 + lr)*H + ks*32 + q*8);

  __syncthreads();

  // ---- GEMM phase: 32 rows x 32 cols per wave ----
  f32x4 acc[2][2];
  #pragma unroll
  for (int rt = 0; rt < 2; ++rt){
    acc[rt][0] = (f32x4){0.f,0.f,0.f,0.f};
    acc[rt][1] = (f32x4){0.f,0.f,0.f,0.f};
  }
  #pragma unroll
  for (int rt = 0; rt < 2; ++rt){
    int row = rt*16 + lr;
    #pragma unroll
    for (int ks = 0; ks < 4; ++ks){
      short8 af = *(const short8*)(&Sm[row*128 + (((ks*4 + q) ^ (row & 15))*8)]);
      acc[rt][0] = __builtin_amdgcn_mfma_f32_16x16x32_bf16(af, bfr[0][ks], acc[rt][0], 0,0,0);
      acc[rt][1] = __builtin_amdgcn_mfma_f32_16x16x32_bf16(af, bfr[1][ks], acc[rt][1], 0,0,0);
    }
  }

  // ---- epilogue: bf16 -> contiguous permuted rows; f32 -> original rows ----
  #pragma unroll
  for (int rt = 0; rt < 2; ++rt){
    #pragma unroll
    for (int c = 0; c < 2; ++c){
      #pragma unroll
      for (int j2 = 0; j2 < 4; ++j2){
        int rowl = rt*16 + q*4 + j2;
        float v = acc[rt][c][j2];
        if (OUTF32){
          int nodeo = pm[rowl];
          if (nodeo >= 0)
            ((float*)zout)[(size_t)nodeo*H + w*32 + c*16 + lr] = v;
        } else {
          int growl = base + rowl;
          float other = __shfl(v, l ^ 1);
          if (!(lr & 1) && growl < n){
            uint pk = (uint)f2bf(v) | ((uint)f2bf(other) << 16);
            ((uint*)zout)[(size_t)growl*64 + w*16 + c*8 + (lr >> 1)] = pk;
          }
        }
      }
    }
  }
  if (STATS){
    #pragma unroll
    for (int c = 0; c < 2; ++c){
      float sv = 0.f, sq = 0.f;
      #pragma unroll
      for (int rt = 0; rt < 2; ++rt)
        #pragma unroll
        for (int j2 = 0; j2 < 4; ++j2){
          float v = acc[rt][c][j2];   // invalid rows have s=0 -> acc=0
          sv += v; sq += v*v;
        }
      sv += __shfl(sv, l ^ 16); sv += __shfl(sv, l ^ 32);
      sq += __shfl(sq, l ^ 16); sq += __shfl(sq, l ^ 32);
      if (q == 0){
        float* st = stats + (size_t)(blockIdx.x & (RSTATS-1))*256;
        atomicAdd(&st[w*32 + c*16 + lr], sv);
        atomicAdd(&st[128 + w*32 + c*16 + lr], sq);
      }
    }
  }
}

// ---------------- BN finalize: stats replicas -> scale/shift; re-zero -------

__global__ void k_bnfinal(float* __restrict__ stats, const float* __restrict__ gamma,
                          const float* __restrict__ beta, float* __restrict__ scsh,
                          float inv_n){
  int f = threadIdx.x;   // 128
  float s = 0.f, s2 = 0.f;
  for (int r = 0; r < RSTATS; ++r){
    s  += stats[r*256 + f];
    s2 += stats[r*256 + 128 + f];
    stats[r*256 + f] = 0.f;          // re-zero for next layer
    stats[r*256 + 128 + f] = 0.f;
  }
  float mu  = s * inv_n;
  float var = s2 * inv_n - mu*mu;
  float sc  = rsqrtf(var + EPS_BN) * gamma[f];
  scsh[f]       = sc;
  scsh[128 + f] = beta[f] - mu*sc;
}

// ---------------- BN apply (in place): y = relu(z*sc + sh), bf16 ----------

__global__ __launch_bounds__(256) void k_bnapply(
    uint4* __restrict__ z, const float* __restrict__ scsh, int n16){
  int i = blockIdx.x*blockDim.x + threadIdx.x;   // one uint4 = 8 elems
  if (i >= n16) return;
  int f8 = (i & 15) * 8;
  uint4 v = z[i];
  uint r[4];
  #pragma unroll
  for (int p = 0; p < 4; ++p){
    uint  u  = (&v.x)[p];
    float z0 = bf2f((ushort)(u & 0xffff));
    float z1 = bf2f((ushort)(u >> 16));
    float y0 = fmaxf(fmaf(z0, scsh[f8 + p*2],     scsh[128 + f8 + p*2]),     0.f);
    float y1 = fmaxf(fmaf(z1, scsh[f8 + p*2 + 1], scsh[128 + f8 + p*2 + 1]), 0.f);
    r[p] = (uint)f2bf(y0) | ((uint)f2bf(y1) << 16);
  }
  z[i] = make_uint4(r[0], r[1], r[2], r[3]);
}

// ---------------- MFMA GEMM for input layer: xw = x(perm rows) @ lin0T^T ----

__global__ __launch_bounds__(256) void k_gemm0(
    const float* __restrict__ Af, const ushort* __restrict__ BT,
    const int* __restrict__ perm, ushort* __restrict__ Cb, int n){
  const int K = 256;
  __shared__ ushort As[64*32];
  __shared__ ushort Bs[128*32];
  __shared__ int pmr[64];
  int t = threadIdx.x;
  int br = blockIdx.x * 64;
  int w = t >> 6, l = t & 63;
  int lr = l & 15, lk = l >> 4;
  int swz = (lr >> 1) & 3;
  if (t < 64) pmr[t] = (br + t < n) ? perm[br + t] : -1;
  __syncthreads();

  f32x4 acc[8];
  #pragma unroll
  for (int i = 0; i < 8; ++i) acc[i] = (f32x4){0.f,0.f,0.f,0.f};

  int sar = t >> 2;
  int sab = t & 3;
  int sa_off = sar*32 + ((sab ^ ((sar>>1)&3))*8);

  for (int k0 = 0; k0 < K; k0 += 32){
    int grow = pmr[sar];              // original row of x
    float4 v0 = make_float4(0.f,0.f,0.f,0.f), v1 = v0;
    if (grow >= 0){
      v0 = *(const float4*)(Af + (size_t)grow*K + k0 + sab*8);
      v1 = *(const float4*)(Af + (size_t)grow*K + k0 + sab*8 + 4);
    }
    ushort tmp[8] = {f2bf(v0.x),f2bf(v0.y),f2bf(v0.z),f2bf(v0.w),
                     f2bf(v1.x),f2bf(v1.y),f2bf(v1.z),f2bf(v1.w)};
    *(uint4*)(&As[sa_off]) = *(const uint4*)tmp;
    #pragma unroll
    for (int i = 0; i < 2; ++i){
      int qq = t + i*256;
      int nrow = qq >> 2, bb = qq & 3;
      uint4 v = *(const uint4*)(BT + (size_t)nrow*K + k0 + bb*8);
      *(uint4*)(&Bs[nrow*32 + ((bb ^ ((nrow>>1)&3))*8)]) = v;
    }
    __syncthreads();
    short8 af = *(const short8*)(&As[(w*16+lr)*32 + ((lk ^ swz)*8)]);
    #pragma unroll
    for (int tn = 0; tn < 8; ++tn){
      short8 bfv = *(const short8*)(&Bs[(tn*16+lr)*32 + ((lk ^ swz)*8)]);
      acc[tn] = __builtin_amdgcn_mfma_f32_16x16x32_bf16(af, bfv, acc[tn], 0, 0, 0);
    }
    __syncthreads();
  }
  int orow = br + w*16 + lk*4;        // permuted layout, contiguous
  #pragma unroll
  for (int tn = 0; tn < 8; ++tn){
    #pragma unroll
    for (int j = 0; j < 4; ++j){
      float mine  = acc[tn][j];
      float other = __shfl(mine, l ^ 1);
      if (!(l & 1) && (orow + j) < n){
        uint pk = (uint)f2bf(mine) | ((uint)f2bf(other) << 16);
        ((uint*)Cb)[(size_t)(orow+j)*64 + tn*8 + (lr >> 1)] = pk;
      }
    }
  }
}

// ---------------- launch ----------------

extern "C" void kernel_launch(void* const* d_in, const int* in_sizes, int n_in,
                              void* d_out, int out_size, void* d_ws, size_t ws_size,
                              hipStream_t stream){
  const float* x        = (const float*)d_in[0];
  const int*   ei       = (const int*)  d_in[1];
  const float* lin0_w   = (const float*)d_in[2];
  const float* lin0_b   = (const float*)d_in[3];
  const float* conv_w   = (const float*)d_in[4];
  const float* bn_gamma = (const float*)d_in[5];
  const float* bn_beta  = (const float*)d_in[6];
  float* out = (float*)d_out;

  int N = in_sizes[0] / 256;
  int E = in_sizes[1] / 2;
  const int* row = ei;
  const int* col = ei + E;

  char* ws = (char*)d_ws;
  size_t p = 0;
  auto alloc = [&](size_t bytes)->char*{
    char* r = ws + p; p = (p + bytes + 255) & ~(size_t)255; return r;
  };
  int*    cnt    = (int*)   alloc((size_t)N*4);
  int*    off    = (int*)   alloc((size_t)(N+1)*4);
  int*    cursor = (int*)   alloc((size_t)N*4);
  float*  dinv   = (float*) alloc((size_t)N*4);
  int*    bsum   = (int*)   alloc(512*4);
  int*    dh     = (int*)   alloc(256*4);
  int*    perm   = (int*)   alloc((size_t)N*4);
  int*    iperm  = (int*)   alloc((size_t)N*4);
  uint2*  edge   = (uint2*) alloc((size_t)E*8);
  ushort* zb     = (ushort*)alloc((size_t)N*H*2);
  ushort* sb     = (ushort*)alloc((size_t)N*H*2);   // xw, then ping-pong z
  ushort* x0b    = (ushort*)alloc((size_t)N*H*2);
  ushort* lin0T  = (ushort*)alloc(128*256*2);
  ushort* WpT    = (ushort*)alloc(4*128*128*2);
  float*  stats  = (float*) alloc(RSTATS*256*4);
  float*  scsh   = (float*) alloc(2*128*4);

  float betas[4];
  for (int i = 0; i < 4; ++i) betas[i] = logf(0.5f/(float)(i+1) + 1.0f);
  float inv_n = 1.0f/(float)N;

  // ---- CSR build (XCD-owned passes) + degree-sort perm ----
  hipMemsetAsync(cnt, 0, (size_t)N*4, stream);
  hipMemsetAsync(dh, 0, 256*4, stream);
  int ecb = 8 * ((E + 255)/256);
  k_count<<<ecb, 256, 0, stream>>>(col, E, cnt, N);
  int nb1k = (N + 1023)/1024;
  k_dhist<<<nb1k, 1024, 0, stream>>>(cnt, dh, N);
  k_dscan<<<1, 256, 0, stream>>>(dh);
  k_dperm<<<nb1k, 1024, 0, stream>>>(cnt, dh, perm, iperm, N);
  k_scan1<<<nb1k, 1024, 0, stream>>>(cnt, off, bsum, dinv, N);
  k_scan2<<<1, 64, 0, stream>>>(bsum, nb1k);
  k_scan3<<<(N+255)/256, 256, 0, stream>>>(off, cursor, bsum, N, E);
  k_fill <<<ecb, 256, 0, stream>>>(row, col, E, dinv, iperm, cursor, edge, N);

  k_prepw<<<(128*256 + 4*128*128 + 255)/256, 256, 0, stream>>>(
      lin0_w, conv_w, lin0T, WpT, betas[0], betas[1], betas[2], betas[3]);

  int gemm_blocks = (N + 63)/64;
  int lay_blocks  = (N + 31)/32;
  int prop_blocks = (N + 15)/16;      // 16 quads (nodes) per 256-thread block
  int bn_blocks   = ((N*16) + 255)/256;

  // ---- input layer: xw = x @ lin0 (permuted rows); x0 = prop(xw)+b ----
  k_gemm0<<<gemm_blocks, 256, 0, stream>>>(x, lin0T, perm, sb, N);
  k_prop0<<<prop_blocks, 256, 0, stream>>>(sb, off, edge, dinv, lin0_b, perm, x0b, N);

  hipMemsetAsync(stats, 0, RSTATS*256*4, stream);   // once; k_bnfinal re-zeroes

  // ---- layer 0: zin=x0b (== x0) -> zout=sb, stats; then BN in place ----
  k_layer<true,false,true><<<lay_blocks, 256, 0, stream>>>(
      x0b, x0b, off, edge, dinv, WpT + 0*128*128, perm, sb, stats, N);
  k_bnfinal<<<1, 128, 0, stream>>>(stats, bn_gamma + 0*H, bn_beta + 0*H, scsh, inv_n);
  k_bnapply<<<bn_blocks, 256, 0, stream>>>((uint4*)sb, scsh, N*16);

  // ---- layer 1: zin=sb -> zout=zb, stats; BN in place ----
  k_layer<true,false,false><<<lay_blocks, 256, 0, stream>>>(
      sb, x0b, off, edge, dinv, WpT + 1*128*128, perm, zb, stats, N);
  k_bnfinal<<<1, 128, 0, stream>>>(stats, bn_gamma + 1*H, bn_beta + 1*H, scsh, inv_n);
  k_bnapply<<<bn_blocks, 256, 0, stream>>>((uint4*)zb, scsh, N*16);

  // ---- layer 2: zin=zb -> zout=sb, stats; BN in place ----
  k_layer<true,false,false><<<lay_blocks, 256, 0, stream>>>(
      zb, x0b, off, edge, dinv, WpT + 2*128*128, perm, sb, stats, N);
  k_bnfinal<<<1, 128, 0, stream>>>(stats, bn_gamma + 2*H, bn_beta + 2*H, scsh, inv_n);
  k_bnapply<<<bn_blocks, 256, 0, stream>>>((uint4*)sb, scsh, N*16);

  // ---- layer 3: zin=sb -> out (f32, original rows), no stats ----
  k_layer<false,true,false><<<lay_blocks, 256, 0, stream>>>(
      sb, x0b, off, edge, dinv, WpT + 3*128*128, perm, out, nullptr, N);
}

// Round 17
// 590.085 us; speedup vs baseline: 1.1550x; 1.0091x over previous
//
#include <hip/hip_runtime.h>
#include <hip/hip_bf16.h>
#include <math.h>

#define H 128
#define EPS_BN 1e-5f
#define RSTATS 16

typedef __attribute__((ext_vector_type(8))) short short8;
typedef __attribute__((ext_vector_type(4))) float f32x4;

__device__ __forceinline__ float bf2f(ushort u){
  union { float f; uint v; } x; x.v = ((uint)u) << 16; return x.f;
}
__device__ __forceinline__ ushort f2bf(float f){
  union { float f; uint v; } x; x.f = f;
  uint v = x.v;
  uint r = v + 0x7fff + ((v >> 16) & 1);   // RNE
  return (ushort)(r >> 16);
}

__device__ __forceinline__ void acc8(float* a, uint4 v, float wt){
  a[0] += wt*bf2f((ushort)(v.x & 0xffff)); a[1] += wt*bf2f((ushort)(v.x >> 16));
  a[2] += wt*bf2f((ushort)(v.y & 0xffff)); a[3] += wt*bf2f((ushort)(v.y >> 16));
  a[4] += wt*bf2f((ushort)(v.z & 0xffff)); a[5] += wt*bf2f((ushort)(v.z >> 16));
  a[6] += wt*bf2f((ushort)(v.w & 0xffff)); a[7] += wt*bf2f((ushort)(v.w >> 16));
}
// BN+ReLU applied to the loaded row before accumulation
__device__ __forceinline__ void acc8bn(float* a, uint4 v, float wt,
                                       const float* sc, const float* sh){
  float z[8] = { bf2f((ushort)(v.x & 0xffff)), bf2f((ushort)(v.x >> 16)),
                 bf2f((ushort)(v.y & 0xffff)), bf2f((ushort)(v.y >> 16)),
                 bf2f((ushort)(v.z & 0xffff)), bf2f((ushort)(v.z >> 16)),
                 bf2f((ushort)(v.w & 0xffff)), bf2f((ushort)(v.w >> 16)) };
  #pragma unroll
  for (int j = 0; j < 8; ++j){
    float y = fmaxf(fmaf(z[j], sc[j], sh[j]), 0.f);
    a[j] = fmaf(wt, y, a[j]);
  }
}

// ---------------- CSR build (simple single-pass) ----------------

__global__ void k_count(const int* __restrict__ col, int E, int* __restrict__ cnt){
  int i = blockIdx.x*blockDim.x + threadIdx.x;
  if (i < E) atomicAdd(&cnt[col[i]], 1);
}

__global__ void k_scan1(const int* __restrict__ cnt, int* __restrict__ off,
                        int* __restrict__ bsum, float* __restrict__ dinv, int n){
  __shared__ int s[1024];
  int t = threadIdx.x;
  int i = blockIdx.x*1024 + t;
  int v = (i < n) ? cnt[i] : 0;
  if (i < n) dinv[i] = rsqrtf((float)v + 1.0f);   // +1 self-loop
  s[t] = v; __syncthreads();
  for (int d = 1; d < 1024; d <<= 1){
    int x = (t >= d) ? s[t-d] : 0;
    __syncthreads();
    s[t] += x;
    __syncthreads();
  }
  if (i < n) off[i] = s[t] - v;
  if (t == 1023) bsum[blockIdx.x] = s[1023];
}

__global__ void k_scan2(int* bsum, int nb){
  int l = threadIdx.x;           // 64 threads, 1 block
  int carry = 0;
  for (int b0 = 0; b0 < nb; b0 += 64){
    int i = b0 + l;
    int orig = (i < nb) ? bsum[i] : 0;
    int v = orig;
    #pragma unroll
    for (int d = 1; d < 64; d <<= 1){
      int x = __shfl_up(v, d);
      if (l >= d) v += x;
    }
    if (i < nb) bsum[i] = carry + v - orig;   // exclusive
    carry += __shfl(v, 63);
  }
}

__global__ void k_scan3(int* __restrict__ off, int* __restrict__ cursor,
                        const int* __restrict__ bsum, int n, int Etot){
  int i = blockIdx.x*blockDim.x + threadIdx.x;
  if (i < n){ int o = off[i] + bsum[i >> 10]; off[i] = o; cursor[i] = o; }
  if (i == 0) off[n] = Etot;
}

// edge record = {permuted source row, weight}
__global__ void k_fill(const int* __restrict__ row, const int* __restrict__ col, int E,
                       const float* __restrict__ dinv, const int* __restrict__ iperm,
                       int* __restrict__ cursor, uint2* __restrict__ edge){
  int i = blockIdx.x*blockDim.x + threadIdx.x;
  if (i < E){
    int c = col[i], r = row[i];
    int p = atomicAdd(&cursor[c], 1);
    edge[p] = make_uint2((uint)iperm[r], __float_as_uint(dinv[r]*dinv[c]));
  }
}

// -------- degree-sort permutation (DESCENDING): LDS-aggregated counting sort --

__global__ __launch_bounds__(1024) void k_dhist(
    const int* __restrict__ cnt, int* __restrict__ dh, int n){
  __shared__ int lh[256];
  int t = threadIdx.x;
  if (t < 256) lh[t] = 0;
  __syncthreads();
  int i = blockIdx.x*1024 + t;
  if (i < n){
    int d = cnt[i]; if (d > 255) d = 255;
    atomicAdd(&lh[d], 1);
  }
  __syncthreads();
  if (t < 256 && lh[t]) atomicAdd(&dh[t], lh[t]);
}

__global__ void k_dscan(int* __restrict__ dh){   // 1 block, 256 thr; DESC offsets
  __shared__ int s[256];
  int t = threadIdx.x;
  int v = dh[255 - t];              // reversed order
  s[t] = v; __syncthreads();
  for (int d = 1; d < 256; d <<= 1){
    int x = (t >= d) ? s[t-d] : 0;
    __syncthreads();
    s[t] += x;
    __syncthreads();
  }
  dh[255 - t] = s[t] - v;   // bin d offset = count of nodes with degree > d
}

__global__ __launch_bounds__(1024) void k_dperm(
    const int* __restrict__ cnt, int* __restrict__ dh,
    int* __restrict__ perm, int* __restrict__ iperm, int n){
  __shared__ int lh[256];
  __shared__ int lbase[256];
  int t = threadIdx.x;
  if (t < 256) lh[t] = 0;
  __syncthreads();
  int i = blockIdx.x*1024 + t;
  int d = 0, li = 0;
  if (i < n){
    d = cnt[i]; if (d > 255) d = 255;
    li = atomicAdd(&lh[d], 1);
  }
  __syncthreads();
  if (t < 256){
    int c = lh[t];
    lbase[t] = c ? atomicAdd(&dh[t], c) : 0;
  }
  __syncthreads();
  if (i < n){
    int pos = lbase[d] + li;
    perm[pos] = i;
    iperm[i] = pos;
  }
}

// ---------------- weight prep: bf16, transposed, beta-folded ----------------

__global__ void k_prepw(const float* __restrict__ lin0_w, const float* __restrict__ conv_w,
                        ushort* __restrict__ lin0T, ushort* __restrict__ WpT,
                        float b0, float b1, float b2, float b3){
  int i = blockIdx.x*blockDim.x + threadIdx.x;
  if (i < 128*256){
    int nn = i >> 8, k = i & 255;
    lin0T[i] = f2bf(lin0_w[k*128 + nn]);
  } else if (i < 128*256 + 4*128*128){
    int j = i - 128*256;
    int ll = j >> 14, rc = j & 16383;
    int nn = rc >> 7, k = rc & 127;
    float beta = (ll==0)?b0:(ll==1)?b1:(ll==2)?b2:b3;
    float v = beta * conv_w[ll*16384 + k*128 + nn];
    if (k == nn) v += 1.0f - beta;
    WpT[j] = f2bf(v);
  }
}

// ---------------- gather cores: one quad (16 lanes) per node ----------------
// edge.x is the PERMUTED source row; zin is in permuted layout.

__device__ __forceinline__ void gather_edges(
    float* a, const ushort* __restrict__ zin, const uint2* __restrict__ edge,
    int e0, int e1, int lr){
  int e = e0;
  for (; e + 3 < e1; e += 4){
    uint2 er0 = edge[e],   er1 = edge[e+1];
    uint2 er2 = edge[e+2], er3 = edge[e+3];
    uint4 v0 = *(const uint4*)(zin + (size_t)er0.x*H + lr*8);
    uint4 v1 = *(const uint4*)(zin + (size_t)er1.x*H + lr*8);
    uint4 v2 = *(const uint4*)(zin + (size_t)er2.x*H + lr*8);
    uint4 v3 = *(const uint4*)(zin + (size_t)er3.x*H + lr*8);
    acc8(a, v0, __uint_as_float(er0.y));
    acc8(a, v1, __uint_as_float(er1.y));
    acc8(a, v2, __uint_as_float(er2.y));
    acc8(a, v3, __uint_as_float(er3.y));
  }
  for (; e < e1; ++e){
    uint2 er = edge[e];
    uint4 v = *(const uint4*)(zin + (size_t)er.x*H + lr*8);
    acc8(a, v, __uint_as_float(er.y));
  }
}

__device__ __forceinline__ void gather_edges_bn(
    float* a, const ushort* __restrict__ zin, const uint2* __restrict__ edge,
    int e0, int e1, int lr, const float* sc, const float* sh){
  int e = e0;
  for (; e + 3 < e1; e += 4){
    uint2 er0 = edge[e],   er1 = edge[e+1];
    uint2 er2 = edge[e+2], er3 = edge[e+3];
    uint4 v0 = *(const uint4*)(zin + (size_t)er0.x*H + lr*8);
    uint4 v1 = *(const uint4*)(zin + (size_t)er1.x*H + lr*8);
    uint4 v2 = *(const uint4*)(zin + (size_t)er2.x*H + lr*8);
    uint4 v3 = *(const uint4*)(zin + (size_t)er3.x*H + lr*8);
    acc8bn(a, v0, __uint_as_float(er0.y), sc, sh);
    acc8bn(a, v1, __uint_as_float(er1.y), sc, sh);
    acc8bn(a, v2, __uint_as_float(er2.y), sc, sh);
    acc8bn(a, v3, __uint_as_float(er3.y), sc, sh);
  }
  for (; e < e1; ++e){
    uint2 er = edge[e];
    uint4 v = *(const uint4*)(zin + (size_t)er.x*H + lr*8);
    acc8bn(a, v, __uint_as_float(er.y), sc, sh);
  }
}

// ---------------- input-layer prop: x0 = agg(xw)+b ; permuted layout --------

__global__ __launch_bounds__(256) void k_prop0(
    const ushort* __restrict__ h, const int* __restrict__ off,
    const uint2* __restrict__ edge, const float* __restrict__ dinv,
    const float* __restrict__ bias, const int* __restrict__ perm,
    ushort* __restrict__ x0, int n){
  int pq = (blockIdx.x*blockDim.x + threadIdx.x) >> 4;   // permuted row
  if (pq >= n) return;
  int gq = perm[pq];                 // original node (off/dinv)
  int lr = threadIdx.x & 15;
  float a[8];
  #pragma unroll
  for (int j = 0; j < 8; ++j) a[j] = 0.f;
  float wc = dinv[gq]; wc *= wc;
  uint4 vs = *(const uint4*)(h + (size_t)pq*H + lr*8);   // self: permuted row
  gather_edges(a, h, edge, off[gq], off[gq+1], lr);
  acc8(a, vs, wc);
  float4 b0 = *(const float4*)(bias + lr*8);
  float4 b1 = *(const float4*)(bias + lr*8 + 4);
  uint4 pk;
  pk.x = (uint)f2bf(a[0]+b0.x) | ((uint)f2bf(a[1]+b0.y) << 16);
  pk.y = (uint)f2bf(a[2]+b0.z) | ((uint)f2bf(a[3]+b0.w) << 16);
  pk.z = (uint)f2bf(a[4]+b1.x) | ((uint)f2bf(a[5]+b1.y) << 16);
  pk.w = (uint)f2bf(a[6]+b1.z) | ((uint)f2bf(a[7]+b1.w) << 16);
  *(uint4*)(x0 + (size_t)pq*H + lr*8) = pk;              // contiguous write
}

// ---------------- fused layer: [BN+ReLU ->] prop -> MFMA GEMM -> z (+stats) --
// zin holds RAW z of the previous layer; BNIN applies y=relu(z*sc+sh) to every
// gathered row in-register (scsh from k_bnfinal). Eliminates the bnapply pass.

template<bool BNIN, bool STATS, bool OUTF32, bool SAMEX0>
__global__ __launch_bounds__(256) void k_layer(
    const ushort* __restrict__ zin, const ushort* __restrict__ x0,
    const int* __restrict__ off, const uint2* __restrict__ edge,
    const float* __restrict__ dinv, const ushort* __restrict__ BT,
    const int* __restrict__ perm, const float* __restrict__ scsh,
    void* __restrict__ zout, float* __restrict__ stats, int n)
{
  __shared__ ushort Sm[32*128];   // swizzled s tile: row*128 + ((blk16^(row&15))*8)
  __shared__ int pm[32];
  int t = threadIdx.x;
  int w = t >> 6, l = t & 63;
  int lr = l & 15, q = l >> 4;
  int base = blockIdx.x * 32;
  if (t < 32) pm[t] = (base + t < n) ? perm[base + t] : -1;

  float sc[8], sh[8];
  if (BNIN){
    #pragma unroll
    for (int j = 0; j < 8; ++j){
      sc[j] = scsh[lr*8 + j];
      sh[j] = scsh[128 + lr*8 + j];
    }
  }
  __syncthreads();

  // ---- prop phase: quad-per-node, 2 nodes per quad ----
  #pragma unroll
  for (int g2 = 0; g2 < 2; ++g2){
    int row  = w*8 + g2*4 + q;
    int node = pm[row];             // original id (off/dinv only)
    int grow = base + row;          // permuted row (addresses)
    float a[8];
    #pragma unroll
    for (int j = 0; j < 8; ++j) a[j] = 0.f;
    uint4 pk = make_uint4(0u,0u,0u,0u);
    if (node >= 0){
      float wc = dinv[node]; wc *= wc;
      uint4 vs = *(const uint4*)(zin + (size_t)grow*H + lr*8);
      if (BNIN){
        gather_edges_bn(a, zin, edge, off[node], off[node+1], lr, sc, sh);
        acc8bn(a, vs, wc, sc, sh);
      } else {
        gather_edges(a, zin, edge, off[node], off[node+1], lr);
        acc8(a, vs, wc);
      }
      uint4 xv = SAMEX0 ? vs : *(const uint4*)(x0 + (size_t)grow*H + lr*8);
      float s0 = 0.9f*a[0] + 0.1f*bf2f((ushort)(xv.x & 0xffff));
      float s1 = 0.9f*a[1] + 0.1f*bf2f((ushort)(xv.x >> 16));
      float s2 = 0.9f*a[2] + 0.1f*bf2f((ushort)(xv.y & 0xffff));
      float s3 = 0.9f*a[3] + 0.1f*bf2f((ushort)(xv.y >> 16));
      float s4 = 0.9f*a[4] + 0.1f*bf2f((ushort)(xv.z & 0xffff));
      float s5 = 0.9f*a[5] + 0.1f*bf2f((ushort)(xv.z >> 16));
      float s6 = 0.9f*a[6] + 0.1f*bf2f((ushort)(xv.w & 0xffff));
      float s7 = 0.9f*a[7] + 0.1f*bf2f((ushort)(xv.w >> 16));
      pk.x = (uint)f2bf(s0) | ((uint)f2bf(s1) << 16);
      pk.y = (uint)f2bf(s2) | ((uint)f2bf(s3) << 16);
      pk.z = (uint)f2bf(s4) | ((uint)f2bf(s5) << 16);
      pk.w = (uint)f2bf(s6) | ((uint)f2bf(s7) << 16);
    }
    *(uint4*)(&Sm[row*128 + ((lr ^ (row & 15))*8)]) = pk;
  }

  // ---- B fragments (W'^T slice for this wave's 32 cols) ----
  short8 bfr[2][4];
  #pragma unroll
  for (int c = 0; c < 2; ++c)
    #pragma unroll
    for (int ks = 0; ks < 4; ++ks)
      bfr[c][ks] = *(const short8*)(BT + (size_t)(w*32 + c*16 + lr)*H + ks*32 + q*8);

  __syncthreads();

  // ---- GEMM phase: 32 rows x 32 cols per wave ----
  f32x4 acc[2][2];
  #pragma unroll
  for (int rt = 0; rt < 2; ++rt){
    acc[rt][0] = (f32x4){0.f,0.f,0.f,0.f};
    acc[rt][1] = (f32x4){0.f,0.f,0.f,0.f};
  }
  #pragma unroll
  for (int rt = 0; rt < 2; ++rt){
    int row = rt*16 + lr;
    #pragma unroll
    for (int ks = 0; ks < 4; ++ks){
      short8 af = *(const short8*)(&Sm[row*128 + (((ks*4 + q) ^ (row & 15))*8)]);
      acc[rt][0] = __builtin_amdgcn_mfma_f32_16x16x32_bf16(af, bfr[0][ks], acc[rt][0], 0,0,0);
      acc[rt][1] = __builtin_amdgcn_mfma_f32_16x16x32_bf16(af, bfr[1][ks], acc[rt][1], 0,0,0);
    }
  }

  // ---- epilogue: bf16 -> contiguous permuted rows; f32 -> original rows ----
  #pragma unroll
  for (int rt = 0; rt < 2; ++rt){
    #pragma unroll
    for (int c = 0; c < 2; ++c){
      #pragma unroll
      for (int j2 = 0; j2 < 4; ++j2){
        int rowl = rt*16 + q*4 + j2;
        float v = acc[rt][c][j2];
        if (OUTF32){
          int nodeo = pm[rowl];
          if (nodeo >= 0)
            ((float*)zout)[(size_t)nodeo*H + w*32 + c*16 + lr] = v;
        } else {
          int growl = base + rowl;
          float other = __shfl(v, l ^ 1);
          if (!(lr & 1) && growl < n){
            uint pk = (uint)f2bf(v) | ((uint)f2bf(other) << 16);
            ((uint*)zout)[(size_t)growl*64 + w*16 + c*8 + (lr >> 1)] = pk;
          }
        }
      }
    }
  }
  if (STATS){
    #pragma unroll
    for (int c = 0; c < 2; ++c){
      float sv = 0.f, sq = 0.f;
      #pragma unroll
      for (int rt = 0; rt < 2; ++rt)
        #pragma unroll
        for (int j2 = 0; j2 < 4; ++j2){
          float v = acc[rt][c][j2];   // invalid rows have s=0 -> acc=0
          sv += v; sq += v*v;
        }
      sv += __shfl(sv, l ^ 16); sv += __shfl(sv, l ^ 32);
      sq += __shfl(sq, l ^ 16); sq += __shfl(sq, l ^ 32);
      if (q == 0){
        float* st = stats + (size_t)(blockIdx.x & (RSTATS-1))*256;
        atomicAdd(&st[w*32 + c*16 + lr], sv);
        atomicAdd(&st[128 + w*32 + c*16 + lr], sq);
      }
    }
  }
}

// ---------------- BN finalize: stats replicas -> scale/shift; re-zero -------

__global__ void k_bnfinal(float* __restrict__ stats, const float* __restrict__ gamma,
                          const float* __restrict__ beta, float* __restrict__ scsh,
                          float inv_n){
  int f = threadIdx.x;   // 128
  float s = 0.f, s2 = 0.f;
  for (int r = 0; r < RSTATS; ++r){
    s  += stats[r*256 + f];
    s2 += stats[r*256 + 128 + f];
    stats[r*256 + f] = 0.f;          // re-zero for next layer
    stats[r*256 + 128 + f] = 0.f;
  }
  float mu  = s * inv_n;
  float var = s2 * inv_n - mu*mu;
  float sc  = rsqrtf(var + EPS_BN) * gamma[f];
  scsh[f]       = sc;
  scsh[128 + f] = beta[f] - mu*sc;
}

// ---------------- MFMA GEMM for input layer: xw = x(perm rows) @ lin0T^T ----

__global__ __launch_bounds__(256) void k_gemm0(
    const float* __restrict__ Af, const ushort* __restrict__ BT,
    const int* __restrict__ perm, ushort* __restrict__ Cb, int n){
  const int K = 256;
  __shared__ ushort As[64*32];
  __shared__ ushort Bs[128*32];
  __shared__ int pmr[64];
  int t = threadIdx.x;
  int br = blockIdx.x * 64;
  int w = t >> 6, l = t & 63;
  int lr = l & 15, lk = l >> 4;
  int swz = (lr >> 1) & 3;
  if (t < 64) pmr[t] = (br + t < n) ? perm[br + t] : -1;
  __syncthreads();

  f32x4 acc[8];
  #pragma unroll
  for (int i = 0; i < 8; ++i) acc[i] = (f32x4){0.f,0.f,0.f,0.f};

  int sar = t >> 2;
  int sab = t & 3;
  int sa_off = sar*32 + ((sab ^ ((sar>>1)&3))*8);

  for (int k0 = 0; k0 < K; k0 += 32){
    int grow = pmr[sar];              // original row of x
    float4 v0 = make_float4(0.f,0.f,0.f,0.f), v1 = v0;
    if (grow >= 0){
      v0 = *(const float4*)(Af + (size_t)grow*K + k0 + sab*8);
      v1 = *(const float4*)(Af + (size_t)grow*K + k0 + sab*8 + 4);
    }
    ushort tmp[8] = {f2bf(v0.x),f2bf(v0.y),f2bf(v0.z),f2bf(v0.w),
                     f2bf(v1.x),f2bf(v1.y),f2bf(v1.z),f2bf(v1.w)};
    *(uint4*)(&As[sa_off]) = *(const uint4*)tmp;
    #pragma unroll
    for (int i = 0; i < 2; ++i){
      int qq = t + i*256;
      int nrow = qq >> 2, bb = qq & 3;
      uint4 v = *(const uint4*)(BT + (size_t)nrow*K + k0 + bb*8);
      *(uint4*)(&Bs[nrow*32 + ((bb ^ ((nrow>>1)&3))*8)]) = v;
    }
    __syncthreads();
    short8 af = *(const short8*)(&As[(w*16+lr)*32 + ((lk ^ swz)*8)]);
    #pragma unroll
    for (int tn = 0; tn < 8; ++tn){
      short8 bfv = *(const short8*)(&Bs[(tn*16+lr)*32 + ((lk ^ swz)*8)]);
      acc[tn] = __builtin_amdgcn_mfma_f32_16x16x32_bf16(af, bfv, acc[tn], 0, 0, 0);
    }
    __syncthreads();
  }
  int orow = br + w*16 + lk*4;        // permuted layout, contiguous
  #pragma unroll
  for (int tn = 0; tn < 8; ++tn){
    #pragma unroll
    for (int j = 0; j < 4; ++j){
      float mine  = acc[tn][j];
      float other = __shfl(mine, l ^ 1);
      if (!(l & 1) && (orow + j) < n){
        uint pk = (uint)f2bf(mine) | ((uint)f2bf(other) << 16);
        ((uint*)Cb)[(size_t)(orow+j)*64 + tn*8 + (lr >> 1)] = pk;
      }
    }
  }
}

// ---------------- launch ----------------

extern "C" void kernel_launch(void* const* d_in, const int* in_sizes, int n_in,
                              void* d_out, int out_size, void* d_ws, size_t ws_size,
                              hipStream_t stream){
  const float* x        = (const float*)d_in[0];
  const int*   ei       = (const int*)  d_in[1];
  const float* lin0_w   = (const float*)d_in[2];
  const float* lin0_b   = (const float*)d_in[3];
  const float* conv_w   = (const float*)d_in[4];
  const float* bn_gamma = (const float*)d_in[5];
  const float* bn_beta  = (const float*)d_in[6];
  float* out = (float*)d_out;

  int N = in_sizes[0] / 256;
  int E = in_sizes[1] / 2;
  const int* row = ei;
  const int* col = ei + E;

  char* ws = (char*)d_ws;
  size_t p = 0;
  auto alloc = [&](size_t bytes)->char*{
    char* r = ws + p; p = (p + bytes + 255) & ~(size_t)255; return r;
  };
  int*    cnt    = (int*)   alloc((size_t)N*4);
  int*    off    = (int*)   alloc((size_t)(N+1)*4);
  int*    cursor = (int*)   alloc((size_t)N*4);
  float*  dinv   = (float*) alloc((size_t)N*4);
  int*    bsum   = (int*)   alloc(512*4);
  int*    dh     = (int*)   alloc(256*4);
  int*    perm   = (int*)   alloc((size_t)N*4);
  int*    iperm  = (int*)   alloc((size_t)N*4);
  uint2*  edge   = (uint2*) alloc((size_t)E*8);
  ushort* zb     = (ushort*)alloc((size_t)N*H*2);
  ushort* sb     = (ushort*)alloc((size_t)N*H*2);   // xw, then ping-pong z
  ushort* x0b    = (ushort*)alloc((size_t)N*H*2);
  ushort* lin0T  = (ushort*)alloc(128*256*2);
  ushort* WpT    = (ushort*)alloc(4*128*128*2);
  float*  stats  = (float*) alloc(RSTATS*256*4);
  float*  scsh   = (float*) alloc(2*128*4);

  float betas[4];
  for (int i = 0; i < 4; ++i) betas[i] = logf(0.5f/(float)(i+1) + 1.0f);
  float inv_n = 1.0f/(float)N;

  // ---- CSR build + degree-sort perm (descending; LDS-aggregated) ----
  hipMemsetAsync(cnt, 0, (size_t)N*4, stream);
  hipMemsetAsync(dh, 0, 256*4, stream);
  k_count<<<(E+255)/256, 256, 0, stream>>>(col, E, cnt);
  int nb1k = (N + 1023)/1024;
  k_dhist<<<nb1k, 1024, 0, stream>>>(cnt, dh, N);
  k_dscan<<<1, 256, 0, stream>>>(dh);
  k_dperm<<<nb1k, 1024, 0, stream>>>(cnt, dh, perm, iperm, N);
  k_scan1<<<nb1k, 1024, 0, stream>>>(cnt, off, bsum, dinv, N);
  k_scan2<<<1, 64, 0, stream>>>(bsum, nb1k);
  k_scan3<<<(N+255)/256, 256, 0, stream>>>(off, cursor, bsum, N, E);
  k_fill <<<(E+255)/256, 256, 0, stream>>>(row, col, E, dinv, iperm, cursor, edge);

  k_prepw<<<(128*256 + 4*128*128 + 255)/256, 256, 0, stream>>>(
      lin0_w, conv_w, lin0T, WpT, betas[0], betas[1], betas[2], betas[3]);

  int gemm_blocks = (N + 63)/64;
  int lay_blocks  = (N + 31)/32;
  int prop_blocks = (N + 15)/16;      // 16 quads (nodes) per 256-thread block

  // ---- input layer: xw = x @ lin0 (permuted rows); x0 = prop(xw)+b ----
  k_gemm0<<<gemm_blocks, 256, 0, stream>>>(x, lin0T, perm, sb, N);
  k_prop0<<<prop_blocks, 256, 0, stream>>>(sb, off, edge, dinv, lin0_b, perm, x0b, N);

  hipMemsetAsync(stats, 0, RSTATS*256*4, stream);   // once; k_bnfinal re-zeroes

  // ---- layer 0: zin=x0b (raw, == x0) -> zout=sb (raw z1), stats ----
  k_layer<false,true,false,true><<<lay_blocks, 256, 0, stream>>>(
      x0b, x0b, off, edge, dinv, WpT + 0*128*128, perm, nullptr, sb, stats, N);
  k_bnfinal<<<1, 128, 0, stream>>>(stats, bn_gamma + 0*H, bn_beta + 0*H, scsh, inv_n);

  // ---- layer 1: zin=sb (raw, BN in gather) -> zout=zb (raw z2), stats ----
  k_layer<true,true,false,false><<<lay_blocks, 256, 0, stream>>>(
      sb, x0b, off, edge, dinv, WpT + 1*128*128, perm, scsh, zb, stats, N);
  k_bnfinal<<<1, 128, 0, stream>>>(stats, bn_gamma + 1*H, bn_beta + 1*H, scsh, inv_n);

  // ---- layer 2: zin=zb (raw, BN in gather) -> zout=sb (raw z3), stats ----
  k_layer<true,true,false,false><<<lay_blocks, 256, 0, stream>>>(
      zb, x0b, off, edge, dinv, WpT + 2*128*128, perm, scsh, sb, stats, N);
  k_bnfinal<<<1, 128, 0, stream>>>(stats, bn_gamma + 2*H, bn_beta + 2*H, scsh, inv_n);

  // ---- layer 3: zin=sb (raw, BN in gather) -> out (f32, original rows) ----
  k_layer<true,false,true,false><<<lay_blocks, 256, 0, stream>>>(
      sb, x0b, off, edge, dinv, WpT + 3*128*128, perm, scsh, out, nullptr, N);
}

// Round 18
// 588.652 us; speedup vs baseline: 1.1578x; 1.0024x over previous
//
#include <hip/hip_runtime.h>
#include <hip/hip_bf16.h>
#include <math.h>

#define H 128
#define EPS_BN 1e-5f
#define RSTATS 16

typedef __attribute__((ext_vector_type(8))) short short8;
typedef __attribute__((ext_vector_type(4))) float f32x4;

__device__ __forceinline__ float bf2f(ushort u){
  union { float f; uint v; } x; x.v = ((uint)u) << 16; return x.f;
}
__device__ __forceinline__ ushort f2bf(float f){
  union { float f; uint v; } x; x.f = f;
  uint v = x.v;
  uint r = v + 0x7fff + ((v >> 16) & 1);   // RNE
  return (ushort)(r >> 16);
}

__device__ __forceinline__ void acc8(float* a, uint4 v, float wt){
  a[0] += wt*bf2f((ushort)(v.x & 0xffff)); a[1] += wt*bf2f((ushort)(v.x >> 16));
  a[2] += wt*bf2f((ushort)(v.y & 0xffff)); a[3] += wt*bf2f((ushort)(v.y >> 16));
  a[4] += wt*bf2f((ushort)(v.z & 0xffff)); a[5] += wt*bf2f((ushort)(v.z >> 16));
  a[6] += wt*bf2f((ushort)(v.w & 0xffff)); a[7] += wt*bf2f((ushort)(v.w >> 16));
}
// BN+ReLU applied to the loaded row before accumulation
__device__ __forceinline__ void acc8bn(float* a, uint4 v, float wt,
                                       const float* sc, const float* sh){
  float z[8] = { bf2f((ushort)(v.x & 0xffff)), bf2f((ushort)(v.x >> 16)),
                 bf2f((ushort)(v.y & 0xffff)), bf2f((ushort)(v.y >> 16)),
                 bf2f((ushort)(v.z & 0xffff)), bf2f((ushort)(v.z >> 16)),
                 bf2f((ushort)(v.w & 0xffff)), bf2f((ushort)(v.w >> 16)) };
  #pragma unroll
  for (int j = 0; j < 8; ++j){
    float y = fmaxf(fmaf(z[j], sc[j], sh[j]), 0.f);
    a[j] = fmaf(wt, y, a[j]);
  }
}

// ---------------- CSR build (simple single-pass) ----------------

__global__ void k_count(const int* __restrict__ col, int E, int* __restrict__ cnt){
  int i = blockIdx.x*blockDim.x + threadIdx.x;
  if (i < E) atomicAdd(&cnt[col[i]], 1);
}

__global__ void k_scan1(const int* __restrict__ cnt, int* __restrict__ off,
                        int* __restrict__ bsum, float* __restrict__ dinv, int n){
  __shared__ int s[1024];
  int t = threadIdx.x;
  int i = blockIdx.x*1024 + t;
  int v = (i < n) ? cnt[i] : 0;
  if (i < n) dinv[i] = rsqrtf((float)v + 1.0f);   // +1 self-loop
  s[t] = v; __syncthreads();
  for (int d = 1; d < 1024; d <<= 1){
    int x = (t >= d) ? s[t-d] : 0;
    __syncthreads();
    s[t] += x;
    __syncthreads();
  }
  if (i < n) off[i] = s[t] - v;
  if (t == 1023) bsum[blockIdx.x] = s[1023];
}

__global__ void k_scan2(int* bsum, int nb){
  int l = threadIdx.x;           // 64 threads, 1 block
  int carry = 0;
  for (int b0 = 0; b0 < nb; b0 += 64){
    int i = b0 + l;
    int orig = (i < nb) ? bsum[i] : 0;
    int v = orig;
    #pragma unroll
    for (int d = 1; d < 64; d <<= 1){
      int x = __shfl_up(v, d);
      if (l >= d) v += x;
    }
    if (i < nb) bsum[i] = carry + v - orig;   // exclusive
    carry += __shfl(v, 63);
  }
}

__global__ void k_scan3(int* __restrict__ off, int* __restrict__ cursor,
                        const int* __restrict__ bsum, int n, int Etot){
  int i = blockIdx.x*blockDim.x + threadIdx.x;
  if (i < n){ int o = off[i] + bsum[i >> 10]; off[i] = o; cursor[i] = o; }
  if (i == 0) off[n] = Etot;
}

// edge record = {permuted source row, weight}
__global__ void k_fill(const int* __restrict__ row, const int* __restrict__ col, int E,
                       const float* __restrict__ dinv, const int* __restrict__ iperm,
                       int* __restrict__ cursor, uint2* __restrict__ edge){
  int i = blockIdx.x*blockDim.x + threadIdx.x;
  if (i < E){
    int c = col[i], r = row[i];
    int p = atomicAdd(&cursor[c], 1);
    edge[p] = make_uint2((uint)iperm[r], __float_as_uint(dinv[r]*dinv[c]));
  }
}

// -------- degree-sort permutation (DESCENDING): LDS-aggregated counting sort --

__global__ __launch_bounds__(1024) void k_dhist(
    const int* __restrict__ cnt, int* __restrict__ dh, int n){
  __shared__ int lh[256];
  int t = threadIdx.x;
  if (t < 256) lh[t] = 0;
  __syncthreads();
  int i = blockIdx.x*1024 + t;
  if (i < n){
    int d = cnt[i]; if (d > 255) d = 255;
    atomicAdd(&lh[d], 1);
  }
  __syncthreads();
  if (t < 256 && lh[t]) atomicAdd(&dh[t], lh[t]);
}

__global__ void k_dscan(int* __restrict__ dh){   // 1 block, 256 thr; DESC offsets
  __shared__ int s[256];
  int t = threadIdx.x;
  int v = dh[255 - t];              // reversed order
  s[t] = v; __syncthreads();
  for (int d = 1; d < 256; d <<= 1){
    int x = (t >= d) ? s[t-d] : 0;
    __syncthreads();
    s[t] += x;
    __syncthreads();
  }
  dh[255 - t] = s[t] - v;   // bin d offset = count of nodes with degree > d
}

__global__ __launch_bounds__(1024) void k_dperm(
    const int* __restrict__ cnt, int* __restrict__ dh,
    int* __restrict__ perm, int* __restrict__ iperm, int n){
  __shared__ int lh[256];
  __shared__ int lbase[256];
  int t = threadIdx.x;
  if (t < 256) lh[t] = 0;
  __syncthreads();
  int i = blockIdx.x*1024 + t;
  int d = 0, li = 0;
  if (i < n){
    d = cnt[i]; if (d > 255) d = 255;
    li = atomicAdd(&lh[d], 1);
  }
  __syncthreads();
  if (t < 256){
    int c = lh[t];
    lbase[t] = c ? atomicAdd(&dh[t], c) : 0;
  }
  __syncthreads();
  if (i < n){
    int pos = lbase[d] + li;
    perm[pos] = i;
    iperm[i] = pos;
  }
}

// ---------------- weight prep: bf16, transposed, beta-folded ----------------

__global__ void k_prepw(const float* __restrict__ lin0_w, const float* __restrict__ conv_w,
                        ushort* __restrict__ lin0T, ushort* __restrict__ WpT,
                        float b0, float b1, float b2, float b3){
  int i = blockIdx.x*blockDim.x + threadIdx.x;
  if (i < 128*256){
    int nn = i >> 8, k = i & 255;
    lin0T[i] = f2bf(lin0_w[k*128 + nn]);
  } else if (i < 128*256 + 4*128*128){
    int j = i - 128*256;
    int ll = j >> 14, rc = j & 16383;
    int nn = rc >> 7, k = rc & 127;
    float beta = (ll==0)?b0:(ll==1)?b1:(ll==2)?b2:b3;
    float v = beta * conv_w[ll*16384 + k*128 + nn];
    if (k == nn) v += 1.0f - beta;
    WpT[j] = f2bf(v);
  }
}

// ---------------- gather cores: one quad (16 lanes) per node ----------------
// 8-wide unroll: 8 row-reads in flight per quad (deg~17 -> 2 main-loop trips).

__device__ __forceinline__ void gather_edges(
    float* a, const ushort* __restrict__ zin, const uint2* __restrict__ edge,
    int e0, int e1, int lr){
  int e = e0;
  for (; e + 7 < e1; e += 8){
    uint2 er0 = edge[e],   er1 = edge[e+1], er2 = edge[e+2], er3 = edge[e+3];
    uint2 er4 = edge[e+4], er5 = edge[e+5], er6 = edge[e+6], er7 = edge[e+7];
    uint4 v0 = *(const uint4*)(zin + (size_t)er0.x*H + lr*8);
    uint4 v1 = *(const uint4*)(zin + (size_t)er1.x*H + lr*8);
    uint4 v2 = *(const uint4*)(zin + (size_t)er2.x*H + lr*8);
    uint4 v3 = *(const uint4*)(zin + (size_t)er3.x*H + lr*8);
    uint4 v4 = *(const uint4*)(zin + (size_t)er4.x*H + lr*8);
    uint4 v5 = *(const uint4*)(zin + (size_t)er5.x*H + lr*8);
    uint4 v6 = *(const uint4*)(zin + (size_t)er6.x*H + lr*8);
    uint4 v7 = *(const uint4*)(zin + (size_t)er7.x*H + lr*8);
    acc8(a, v0, __uint_as_float(er0.y));
    acc8(a, v1, __uint_as_float(er1.y));
    acc8(a, v2, __uint_as_float(er2.y));
    acc8(a, v3, __uint_as_float(er3.y));
    acc8(a, v4, __uint_as_float(er4.y));
    acc8(a, v5, __uint_as_float(er5.y));
    acc8(a, v6, __uint_as_float(er6.y));
    acc8(a, v7, __uint_as_float(er7.y));
  }
  for (; e + 3 < e1; e += 4){
    uint2 er0 = edge[e], er1 = edge[e+1], er2 = edge[e+2], er3 = edge[e+3];
    uint4 v0 = *(const uint4*)(zin + (size_t)er0.x*H + lr*8);
    uint4 v1 = *(const uint4*)(zin + (size_t)er1.x*H + lr*8);
    uint4 v2 = *(const uint4*)(zin + (size_t)er2.x*H + lr*8);
    uint4 v3 = *(const uint4*)(zin + (size_t)er3.x*H + lr*8);
    acc8(a, v0, __uint_as_float(er0.y));
    acc8(a, v1, __uint_as_float(er1.y));
    acc8(a, v2, __uint_as_float(er2.y));
    acc8(a, v3, __uint_as_float(er3.y));
  }
  for (; e < e1; ++e){
    uint2 er = edge[e];
    uint4 v = *(const uint4*)(zin + (size_t)er.x*H + lr*8);
    acc8(a, v, __uint_as_float(er.y));
  }
}

__device__ __forceinline__ void gather_edges_bn(
    float* a, const ushort* __restrict__ zin, const uint2* __restrict__ edge,
    int e0, int e1, int lr, const float* sc, const float* sh){
  int e = e0;
  for (; e + 7 < e1; e += 8){
    uint2 er0 = edge[e],   er1 = edge[e+1], er2 = edge[e+2], er3 = edge[e+3];
    uint2 er4 = edge[e+4], er5 = edge[e+5], er6 = edge[e+6], er7 = edge[e+7];
    uint4 v0 = *(const uint4*)(zin + (size_t)er0.x*H + lr*8);
    uint4 v1 = *(const uint4*)(zin + (size_t)er1.x*H + lr*8);
    uint4 v2 = *(const uint4*)(zin + (size_t)er2.x*H + lr*8);
    uint4 v3 = *(const uint4*)(zin + (size_t)er3.x*H + lr*8);
    uint4 v4 = *(const uint4*)(zin + (size_t)er4.x*H + lr*8);
    uint4 v5 = *(const uint4*)(zin + (size_t)er5.x*H + lr*8);
    uint4 v6 = *(const uint4*)(zin + (size_t)er6.x*H + lr*8);
    uint4 v7 = *(const uint4*)(zin + (size_t)er7.x*H + lr*8);
    acc8bn(a, v0, __uint_as_float(er0.y), sc, sh);
    acc8bn(a, v1, __uint_as_float(er1.y), sc, sh);
    acc8bn(a, v2, __uint_as_float(er2.y), sc, sh);
    acc8bn(a, v3, __uint_as_float(er3.y), sc, sh);
    acc8bn(a, v4, __uint_as_float(er4.y), sc, sh);
    acc8bn(a, v5, __uint_as_float(er5.y), sc, sh);
    acc8bn(a, v6, __uint_as_float(er6.y), sc, sh);
    acc8bn(a, v7, __uint_as_float(er7.y), sc, sh);
  }
  for (; e + 3 < e1; e += 4){
    uint2 er0 = edge[e], er1 = edge[e+1], er2 = edge[e+2], er3 = edge[e+3];
    uint4 v0 = *(const uint4*)(zin + (size_t)er0.x*H + lr*8);
    uint4 v1 = *(const uint4*)(zin + (size_t)er1.x*H + lr*8);
    uint4 v2 = *(const uint4*)(zin + (size_t)er2.x*H + lr*8);
    uint4 v3 = *(const uint4*)(zin + (size_t)er3.x*H + lr*8);
    acc8bn(a, v0, __uint_as_float(er0.y), sc, sh);
    acc8bn(a, v1, __uint_as_float(er1.y), sc, sh);
    acc8bn(a, v2, __uint_as_float(er2.y), sc, sh);
    acc8bn(a, v3, __uint_as_float(er3.y), sc, sh);
  }
  for (; e < e1; ++e){
    uint2 er = edge[e];
    uint4 v = *(const uint4*)(zin + (size_t)er.x*H + lr*8);
    acc8bn(a, v, __uint_as_float(er.y), sc, sh);
  }
}

// ---------------- input-layer prop: x0 = agg(xw)+b ; permuted layout --------

__global__ __launch_bounds__(256) void k_prop0(
    const ushort* __restrict__ h, const int* __restrict__ off,
    const uint2* __restrict__ edge, const float* __restrict__ dinv,
    const float* __restrict__ bias, const int* __restrict__ perm,
    ushort* __restrict__ x0, int n){
  int pq = (blockIdx.x*blockDim.x + threadIdx.x) >> 4;   // permuted row
  if (pq >= n) return;
  int gq = perm[pq];                 // original node (off/dinv)
  int lr = threadIdx.x & 15;
  float a[8];
  #pragma unroll
  for (int j = 0; j < 8; ++j) a[j] = 0.f;
  float wc = dinv[gq]; wc *= wc;
  uint4 vs = *(const uint4*)(h + (size_t)pq*H + lr*8);   // self: permuted row
  gather_edges(a, h, edge, off[gq], off[gq+1], lr);
  acc8(a, vs, wc);
  float4 b0 = *(const float4*)(bias + lr*8);
  float4 b1 = *(const float4*)(bias + lr*8 + 4);
  uint4 pk;
  pk.x = (uint)f2bf(a[0]+b0.x) | ((uint)f2bf(a[1]+b0.y) << 16);
  pk.y = (uint)f2bf(a[2]+b0.z) | ((uint)f2bf(a[3]+b0.w) << 16);
  pk.z = (uint)f2bf(a[4]+b1.x) | ((uint)f2bf(a[5]+b1.y) << 16);
  pk.w = (uint)f2bf(a[6]+b1.z) | ((uint)f2bf(a[7]+b1.w) << 16);
  *(uint4*)(x0 + (size_t)pq*H + lr*8) = pk;              // contiguous write
}

// ---------------- fused layer: [BN+ReLU ->] prop -> MFMA GEMM -> z (+stats) --

template<bool BNIN, bool STATS, bool OUTF32, bool SAMEX0>
__global__ __launch_bounds__(256) void k_layer(
    const ushort* __restrict__ zin, const ushort* __restrict__ x0,
    const int* __restrict__ off, const uint2* __restrict__ edge,
    const float* __restrict__ dinv, const ushort* __restrict__ BT,
    const int* __restrict__ perm, const float* __restrict__ scsh,
    void* __restrict__ zout, float* __restrict__ stats, int n)
{
  __shared__ ushort Sm[32*128];   // swizzled s tile: row*128 + ((blk16^(row&15))*8)
  __shared__ int pm[32];
  int t = threadIdx.x;
  int w = t >> 6, l = t & 63;
  int lr = l & 15, q = l >> 4;
  int base = blockIdx.x * 32;
  if (t < 32) pm[t] = (base + t < n) ? perm[base + t] : -1;

  float sc[8], sh[8];
  if (BNIN){
    #pragma unroll
    for (int j = 0; j < 8; ++j){
      sc[j] = scsh[lr*8 + j];
      sh[j] = scsh[128 + lr*8 + j];
    }
  }
  __syncthreads();

  // ---- prop phase: quad-per-node, 2 nodes per quad ----
  #pragma unroll
  for (int g2 = 0; g2 < 2; ++g2){
    int row  = w*8 + g2*4 + q;
    int node = pm[row];             // original id (off/dinv only)
    int grow = base + row;          // permuted row (addresses)
    float a[8];
    #pragma unroll
    for (int j = 0; j < 8; ++j) a[j] = 0.f;
    uint4 pk = make_uint4(0u,0u,0u,0u);
    if (node >= 0){
      float wc = dinv[node]; wc *= wc;
      uint4 vs = *(const uint4*)(zin + (size_t)grow*H + lr*8);
      if (BNIN){
        gather_edges_bn(a, zin, edge, off[node], off[node+1], lr, sc, sh);
        acc8bn(a, vs, wc, sc, sh);
      } else {
        gather_edges(a, zin, edge, off[node], off[node+1], lr);
        acc8(a, vs, wc);
      }
      uint4 xv = SAMEX0 ? vs : *(const uint4*)(x0 + (size_t)grow*H + lr*8);
      float s0 = 0.9f*a[0] + 0.1f*bf2f((ushort)(xv.x & 0xffff));
      float s1 = 0.9f*a[1] + 0.1f*bf2f((ushort)(xv.x >> 16));
      float s2 = 0.9f*a[2] + 0.1f*bf2f((ushort)(xv.y & 0xffff));
      float s3 = 0.9f*a[3] + 0.1f*bf2f((ushort)(xv.y >> 16));
      float s4 = 0.9f*a[4] + 0.1f*bf2f((ushort)(xv.z & 0xffff));
      float s5 = 0.9f*a[5] + 0.1f*bf2f((ushort)(xv.z >> 16));
      float s6 = 0.9f*a[6] + 0.1f*bf2f((ushort)(xv.w & 0xffff));
      float s7 = 0.9f*a[7] + 0.1f*bf2f((ushort)(xv.w >> 16));
      pk.x = (uint)f2bf(s0) | ((uint)f2bf(s1) << 16);
      pk.y = (uint)f2bf(s2) | ((uint)f2bf(s3) << 16);
      pk.z = (uint)f2bf(s4) | ((uint)f2bf(s5) << 16);
      pk.w = (uint)f2bf(s6) | ((uint)f2bf(s7) << 16);
    }
    *(uint4*)(&Sm[row*128 + ((lr ^ (row & 15))*8)]) = pk;
  }

  // ---- B fragments (W'^T slice for this wave's 32 cols) ----
  short8 bfr[2][4];
  #pragma unroll
  for (int c = 0; c < 2; ++c)
    #pragma unroll
    for (int ks = 0; ks < 4; ++ks)
      bfr[c][ks] = *(const short8*)(BT + (size_t)(w*32 + c*16 + lr)*H + ks*32 + q*8);

  __syncthreads();

  // ---- GEMM phase: 32 rows x 32 cols per wave ----
  f32x4 acc[2][2];
  #pragma unroll
  for (int rt = 0; rt < 2; ++rt){
    acc[rt][0] = (f32x4){0.f,0.f,0.f,0.f};
    acc[rt][1] = (f32x4){0.f,0.f,0.f,0.f};
  }
  #pragma unroll
  for (int rt = 0; rt < 2; ++rt){
    int row = rt*16 + lr;
    #pragma unroll
    for (int ks = 0; ks < 4; ++ks){
      short8 af = *(const short8*)(&Sm[row*128 + (((ks*4 + q) ^ (row & 15))*8)]);
      acc[rt][0] = __builtin_amdgcn_mfma_f32_16x16x32_bf16(af, bfr[0][ks], acc[rt][0], 0,0,0);
      acc[rt][1] = __builtin_amdgcn_mfma_f32_16x16x32_bf16(af, bfr[1][ks], acc[rt][1], 0,0,0);
    }
  }

  // ---- epilogue: bf16 -> contiguous permuted rows; f32 -> original rows ----
  #pragma unroll
  for (int rt = 0; rt < 2; ++rt){
    #pragma unroll
    for (int c = 0; c < 2; ++c){
      #pragma unroll
      for (int j2 = 0; j2 < 4; ++j2){
        int rowl = rt*16 + q*4 + j2;
        float v = acc[rt][c][j2];
        if (OUTF32){
          int nodeo = pm[rowl];
          if (nodeo >= 0)
            ((float*)zout)[(size_t)nodeo*H + w*32 + c*16 + lr] = v;
        } else {
          int growl = base + rowl;
          float other = __shfl(v, l ^ 1);
          if (!(lr & 1) && growl < n){
            uint pk = (uint)f2bf(v) | ((uint)f2bf(other) << 16);
            ((uint*)zout)[(size_t)growl*64 + w*16 + c*8 + (lr >> 1)] = pk;
          }
        }
      }
    }
  }
  if (STATS){
    #pragma unroll
    for (int c = 0; c < 2; ++c){
      float sv = 0.f, sq = 0.f;
      #pragma unroll
      for (int rt = 0; rt < 2; ++rt)
        #pragma unroll
        for (int j2 = 0; j2 < 4; ++j2){
          float v = acc[rt][c][j2];   // invalid rows have s=0 -> acc=0
          sv += v; sq += v*v;
        }
      sv += __shfl(sv, l ^ 16); sv += __shfl(sv, l ^ 32);
      sq += __shfl(sq, l ^ 16); sq += __shfl(sq, l ^ 32);
      if (q == 0){
        float* st = stats + (size_t)(blockIdx.x & (RSTATS-1))*256;
        atomicAdd(&st[w*32 + c*16 + lr], sv);
        atomicAdd(&st[128 + w*32 + c*16 + lr], sq);
      }
    }
  }
}

// ---------------- BN finalize: stats replicas -> scale/shift; re-zero -------

__global__ void k_bnfinal(float* __restrict__ stats, const float* __restrict__ gamma,
                          const float* __restrict__ beta, float* __restrict__ scsh,
                          float inv_n){
  int f = threadIdx.x;   // 128
  float s = 0.f, s2 = 0.f;
  for (int r = 0; r < RSTATS; ++r){
    s  += stats[r*256 + f];
    s2 += stats[r*256 + 128 + f];
    stats[r*256 + f] = 0.f;          // re-zero for next layer
    stats[r*256 + 128 + f] = 0.f;
  }
  float mu  = s * inv_n;
  float var = s2 * inv_n - mu*mu;
  float sc  = rsqrtf(var + EPS_BN) * gamma[f];
  scsh[f]       = sc;
  scsh[128 + f] = beta[f] - mu*sc;
}

// ---------------- MFMA GEMM for input layer: xw = x(perm rows) @ lin0T^T ----

__global__ __launch_bounds__(256) void k_gemm0(
    const float* __restrict__ Af, const ushort* __restrict__ BT,
    const int* __restrict__ perm, ushort* __restrict__ Cb, int n){
  const int K = 256;
  __shared__ ushort As[64*32];
  __shared__ ushort Bs[128*32];
  __shared__ int pmr[64];
  int t = threadIdx.x;
  int br = blockIdx.x * 64;
  int w = t >> 6, l = t & 63;
  int lr = l & 15, lk = l >> 4;
  int swz = (lr >> 1) & 3;
  if (t < 64) pmr[t] = (br + t < n) ? perm[br + t] : -1;
  __syncthreads();

  f32x4 acc[8];
  #pragma unroll
  for (int i = 0; i < 8; ++i) acc[i] = (f32x4){0.f,0.f,0.f,0.f};

  int sar = t >> 2;
  int sab = t & 3;
  int sa_off = sar*32 + ((sab ^ ((sar>>1)&3))*8);

  for (int k0 = 0; k0 < K; k0 += 32){
    int grow = pmr[sar];              // original row of x
    float4 v0 = make_float4(0.f,0.f,0.f,0.f), v1 = v0;
    if (grow >= 0){
      v0 = *(const float4*)(Af + (size_t)grow*K + k0 + sab*8);
      v1 = *(const float4*)(Af + (size_t)grow*K + k0 + sab*8 + 4);
    }
    ushort tmp[8] = {f2bf(v0.x),f2bf(v0.y),f2bf(v0.z),f2bf(v0.w),
                     f2bf(v1.x),f2bf(v1.y),f2bf(v1.z),f2bf(v1.w)};
    *(uint4*)(&As[sa_off]) = *(const uint4*)tmp;
    #pragma unroll
    for (int i = 0; i < 2; ++i){
      int qq = t + i*256;
      int nrow = qq >> 2, bb = qq & 3;
      uint4 v = *(const uint4*)(BT + (size_t)nrow*K + k0 + bb*8);
      *(uint4*)(&Bs[nrow*32 + ((bb ^ ((nrow>>1)&3))*8)]) = v;
    }
    __syncthreads();
    short8 af = *(const short8*)(&As[(w*16+lr)*32 + ((lk ^ swz)*8)]);
    #pragma unroll
    for (int tn = 0; tn < 8; ++tn){
      short8 bfv = *(const short8*)(&Bs[(tn*16+lr)*32 + ((lk ^ swz)*8)]);
      acc[tn] = __builtin_amdgcn_mfma_f32_16x16x32_bf16(af, bfv, acc[tn], 0, 0, 0);
    }
    __syncthreads();
  }
  int orow = br + w*16 + lk*4;        // permuted layout, contiguous
  #pragma unroll
  for (int tn = 0; tn < 8; ++tn){
    #pragma unroll
    for (int j = 0; j < 4; ++j){
      float mine  = acc[tn][j];
      float other = __shfl(mine, l ^ 1);
      if (!(l & 1) && (orow + j) < n){
        uint pk = (uint)f2bf(mine) | ((uint)f2bf(other) << 16);
        ((uint*)Cb)[(size_t)(orow+j)*64 + tn*8 + (lr >> 1)] = pk;
      }
    }
  }
}

// ---------------- launch ----------------

extern "C" void kernel_launch(void* const* d_in, const int* in_sizes, int n_in,
                              void* d_out, int out_size, void* d_ws, size_t ws_size,
                              hipStream_t stream){
  const float* x        = (const float*)d_in[0];
  const int*   ei       = (const int*)  d_in[1];
  const float* lin0_w   = (const float*)d_in[2];
  const float* lin0_b   = (const float*)d_in[3];
  const float* conv_w   = (const float*)d_in[4];
  const float* bn_gamma = (const float*)d_in[5];
  const float* bn_beta  = (const float*)d_in[6];
  float* out = (float*)d_out;

  int N = in_sizes[0] / 256;
  int E = in_sizes[1] / 2;
  const int* row = ei;
  const int* col = ei + E;

  char* ws = (char*)d_ws;
  size_t p = 0;
  auto alloc = [&](size_t bytes)->char*{
    char* r = ws + p; p = (p + bytes + 255) & ~(size_t)255; return r;
  };
  int*    cnt    = (int*)   alloc((size_t)N*4);
  int*    off    = (int*)   alloc((size_t)(N+1)*4);
  int*    cursor = (int*)   alloc((size_t)N*4);
  float*  dinv   = (float*) alloc((size_t)N*4);
  int*    bsum   = (int*)   alloc(512*4);
  int*    dh     = (int*)   alloc(256*4);
  int*    perm   = (int*)   alloc((size_t)N*4);
  int*    iperm  = (int*)   alloc((size_t)N*4);
  uint2*  edge   = (uint2*) alloc((size_t)E*8);
  ushort* zb     = (ushort*)alloc((size_t)N*H*2);
  ushort* sb     = (ushort*)alloc((size_t)N*H*2);   // xw, then ping-pong z
  ushort* x0b    = (ushort*)alloc((size_t)N*H*2);
  ushort* lin0T  = (ushort*)alloc(128*256*2);
  ushort* WpT    = (ushort*)alloc(4*128*128*2);
  float*  stats  = (float*) alloc(RSTATS*256*4);
  float*  scsh   = (float*) alloc(2*128*4);

  float betas[4];
  for (int i = 0; i < 4; ++i) betas[i] = logf(0.5f/(float)(i+1) + 1.0f);
  float inv_n = 1.0f/(float)N;

  // ---- CSR build + degree-sort perm (descending; LDS-aggregated) ----
  hipMemsetAsync(cnt, 0, (size_t)N*4, stream);
  hipMemsetAsync(dh, 0, 256*4, stream);
  k_count<<<(E+255)/256, 256, 0, stream>>>(col, E, cnt);
  int nb1k = (N + 1023)/1024;
  k_dhist<<<nb1k, 1024, 0, stream>>>(cnt, dh, N);
  k_dscan<<<1, 256, 0, stream>>>(dh);
  k_dperm<<<nb1k, 1024, 0, stream>>>(cnt, dh, perm, iperm, N);
  k_scan1<<<nb1k, 1024, 0, stream>>>(cnt, off, bsum, dinv, N);
  k_scan2<<<1, 64, 0, stream>>>(bsum, nb1k);
  k_scan3<<<(N+255)/256, 256, 0, stream>>>(off, cursor, bsum, N, E);
  k_fill <<<(E+255)/256, 256, 0, stream>>>(row, col, E, dinv, iperm, cursor, edge);

  k_prepw<<<(128*256 + 4*128*128 + 255)/256, 256, 0, stream>>>(
      lin0_w, conv_w, lin0T, WpT, betas[0], betas[1], betas[2], betas[3]);

  int gemm_blocks = (N + 63)/64;
  int lay_blocks  = (N + 31)/32;
  int prop_blocks = (N + 15)/16;      // 16 quads (nodes) per 256-thread block

  // ---- input layer: xw = x @ lin0 (permuted rows); x0 = prop(xw)+b ----
  k_gemm0<<<gemm_blocks, 256, 0, stream>>>(x, lin0T, perm, sb, N);
  k_prop0<<<prop_blocks, 256, 0, stream>>>(sb, off, edge, dinv, lin0_b, perm, x0b, N);

  hipMemsetAsync(stats, 0, RSTATS*256*4, stream);   // once; k_bnfinal re-zeroes

  // ---- layer 0: zin=x0b (raw, == x0) -> zout=sb (raw z1), stats ----
  k_layer<false,true,false,true><<<lay_blocks, 256, 0, stream>>>(
      x0b, x0b, off, edge, dinv, WpT + 0*128*128, perm, nullptr, sb, stats, N);
  k_bnfinal<<<1, 128, 0, stream>>>(stats, bn_gamma + 0*H, bn_beta + 0*H, scsh, inv_n);

  // ---- layer 1: zin=sb (raw, BN in gather) -> zout=zb (raw z2), stats ----
  k_layer<true,true,false,false><<<lay_blocks, 256, 0, stream>>>(
      sb, x0b, off, edge, dinv, WpT + 1*128*128, perm, scsh, zb, stats, N);
  k_bnfinal<<<1, 128, 0, stream>>>(stats, bn_gamma + 1*H, bn_beta + 1*H, scsh, inv_n);

  // ---- layer 2: zin=zb (raw, BN in gather) -> zout=sb (raw z3), stats ----
  k_layer<true,true,false,false><<<lay_blocks, 256, 0, stream>>>(
      zb, x0b, off, edge, dinv, WpT + 2*128*128, perm, scsh, sb, stats, N);
  k_bnfinal<<<1, 128, 0, stream>>>(stats, bn_gamma + 2*H, bn_beta + 2*H, scsh, inv_n);

  // ---- layer 3: zin=sb (raw, BN in gather) -> out (f32, original rows) ----
  k_layer<true,false,true,false><<<lay_blocks, 256, 0, stream>>>(
      sb, x0b, off, edge, dinv, WpT + 3*128*128, perm, scsh, out, nullptr, N);
}

// Round 19
// 575.493 us; speedup vs baseline: 1.1842x; 1.0229x over previous
//
#include <hip/hip_runtime.h>
#include <hip/hip_bf16.h>
#include <math.h>

#define H 128
#define EPS_BN 1e-5f
#define RSTATS 16

typedef __attribute__((ext_vector_type(8))) short short8;
typedef __attribute__((ext_vector_type(4))) float f32x4;

__device__ __forceinline__ float bf2f(ushort u){
  union { float f; uint v; } x; x.v = ((uint)u) << 16; return x.f;
}
__device__ __forceinline__ ushort f2bf(float f){
  union { float f; uint v; } x; x.f = f;
  uint v = x.v;
  uint r = v + 0x7fff + ((v >> 16) & 1);   // RNE
  return (ushort)(r >> 16);
}

__device__ __forceinline__ void acc8(float* a, uint4 v, float wt){
  a[0] += wt*bf2f((ushort)(v.x & 0xffff)); a[1] += wt*bf2f((ushort)(v.x >> 16));
  a[2] += wt*bf2f((ushort)(v.y & 0xffff)); a[3] += wt*bf2f((ushort)(v.y >> 16));
  a[4] += wt*bf2f((ushort)(v.z & 0xffff)); a[5] += wt*bf2f((ushort)(v.z >> 16));
  a[6] += wt*bf2f((ushort)(v.w & 0xffff)); a[7] += wt*bf2f((ushort)(v.w >> 16));
}
// BN+ReLU applied to the loaded row before accumulation
__device__ __forceinline__ void acc8bn(float* a, uint4 v, float wt,
                                       const float* sc, const float* sh){
  float z[8] = { bf2f((ushort)(v.x & 0xffff)), bf2f((ushort)(v.x >> 16)),
                 bf2f((ushort)(v.y & 0xffff)), bf2f((ushort)(v.y >> 16)),
                 bf2f((ushort)(v.z & 0xffff)), bf2f((ushort)(v.z >> 16)),
                 bf2f((ushort)(v.w & 0xffff)), bf2f((ushort)(v.w >> 16)) };
  #pragma unroll
  for (int j = 0; j < 8; ++j){
    float y = fmaxf(fmaf(z[j], sc[j], sh[j]), 0.f);
    a[j] = fmaf(wt, y, a[j]);
  }
}

// ---------------- CSR build (simple single-pass) ----------------

__global__ void k_count(const int* __restrict__ col, int E, int* __restrict__ cnt){
  int i = blockIdx.x*blockDim.x + threadIdx.x;
  if (i < E){
    int c = __builtin_nontemporal_load(col + i);
    atomicAdd(&cnt[c], 1);
  }
}

__global__ void k_scan1(const int* __restrict__ cnt, int* __restrict__ off,
                        int* __restrict__ bsum, float* __restrict__ dinv, int n){
  __shared__ int s[1024];
  int t = threadIdx.x;
  int i = blockIdx.x*1024 + t;
  int v = (i < n) ? cnt[i] : 0;
  if (i < n) dinv[i] = rsqrtf((float)v + 1.0f);   // +1 self-loop
  s[t] = v; __syncthreads();
  for (int d = 1; d < 1024; d <<= 1){
    int x = (t >= d) ? s[t-d] : 0;
    __syncthreads();
    s[t] += x;
    __syncthreads();
  }
  if (i < n) off[i] = s[t] - v;
  if (t == 1023) bsum[blockIdx.x] = s[1023];
}

__global__ void k_scan2(int* bsum, int nb){
  int l = threadIdx.x;           // 64 threads, 1 block
  int carry = 0;
  for (int b0 = 0; b0 < nb; b0 += 64){
    int i = b0 + l;
    int orig = (i < nb) ? bsum[i] : 0;
    int v = orig;
    #pragma unroll
    for (int d = 1; d < 64; d <<= 1){
      int x = __shfl_up(v, d);
      if (l >= d) v += x;
    }
    if (i < nb) bsum[i] = carry + v - orig;   // exclusive
    carry += __shfl(v, 63);
  }
}

__global__ void k_scan3(int* __restrict__ off, int* __restrict__ cursor,
                        const int* __restrict__ bsum, int n, int Etot){
  int i = blockIdx.x*blockDim.x + threadIdx.x;
  if (i < n){ int o = off[i] + bsum[i >> 10]; off[i] = o; cursor[i] = o; }
  if (i == 0) off[n] = Etot;
}

// edge record = {permuted source row, weight}; NONTEMPORAL store (no-allocate)
__global__ void k_fill(const int* __restrict__ row, const int* __restrict__ col, int E,
                       const float* __restrict__ dinv, const int* __restrict__ iperm,
                       int* __restrict__ cursor, uint2* __restrict__ edge){
  int i = blockIdx.x*blockDim.x + threadIdx.x;
  if (i < E){
    int c = __builtin_nontemporal_load(col + i);
    int r = __builtin_nontemporal_load(row + i);
    int p = atomicAdd(&cursor[c], 1);
    unsigned long long v =
        ((unsigned long long)__float_as_uint(dinv[r]*dinv[c]) << 32) |
        (unsigned long long)(uint)iperm[r];
    __builtin_nontemporal_store(v, (unsigned long long*)(edge + p));
  }
}

// -------- degree-sort permutation (DESCENDING): LDS-aggregated counting sort --

__global__ __launch_bounds__(1024) void k_dhist(
    const int* __restrict__ cnt, int* __restrict__ dh, int n){
  __shared__ int lh[256];
  int t = threadIdx.x;
  if (t < 256) lh[t] = 0;
  __syncthreads();
  int i = blockIdx.x*1024 + t;
  if (i < n){
    int d = cnt[i]; if (d > 255) d = 255;
    atomicAdd(&lh[d], 1);
  }
  __syncthreads();
  if (t < 256 && lh[t]) atomicAdd(&dh[t], lh[t]);
}

__global__ void k_dscan(int* __restrict__ dh){   // 1 block, 256 thr; DESC offsets
  __shared__ int s[256];
  int t = threadIdx.x;
  int v = dh[255 - t];              // reversed order
  s[t] = v; __syncthreads();
  for (int d = 1; d < 256; d <<= 1){
    int x = (t >= d) ? s[t-d] : 0;
    __syncthreads();
    s[t] += x;
    __syncthreads();
  }
  dh[255 - t] = s[t] - v;   // bin d offset = count of nodes with degree > d
}

__global__ __launch_bounds__(1024) void k_dperm(
    const int* __restrict__ cnt, int* __restrict__ dh,
    int* __restrict__ perm, int* __restrict__ iperm, int n){
  __shared__ int lh[256];
  __shared__ int lbase[256];
  int t = threadIdx.x;
  if (t < 256) lh[t] = 0;
  __syncthreads();
  int i = blockIdx.x*1024 + t;
  int d = 0, li = 0;
  if (i < n){
    d = cnt[i]; if (d > 255) d = 255;
    li = atomicAdd(&lh[d], 1);
  }
  __syncthreads();
  if (t < 256){
    int c = lh[t];
    lbase[t] = c ? atomicAdd(&dh[t], c) : 0;
  }
  __syncthreads();
  if (i < n){
    int pos = lbase[d] + li;
    perm[pos] = i;
    iperm[i] = pos;
  }
}

// ---------------- weight prep: bf16, transposed, beta-folded ----------------

__global__ void k_prepw(const float* __restrict__ lin0_w, const float* __restrict__ conv_w,
                        ushort* __restrict__ lin0T, ushort* __restrict__ WpT,
                        float b0, float b1, float b2, float b3){
  int i = blockIdx.x*blockDim.x + threadIdx.x;
  if (i < 128*256){
    int nn = i >> 8, k = i & 255;
    lin0T[i] = f2bf(lin0_w[k*128 + nn]);
  } else if (i < 128*256 + 4*128*128){
    int j = i - 128*256;
    int ll = j >> 14, rc = j & 16383;
    int nn = rc >> 7, k = rc & 127;
    float beta = (ll==0)?b0:(ll==1)?b1:(ll==2)?b2:b3;
    float v = beta * conv_w[ll*16384 + k*128 + nn];
    if (k == nn) v += 1.0f - beta;
    WpT[j] = f2bf(v);
  }
}

// ---------------- gather cores: one quad (16 lanes) per node ----------------
// 8-wide unroll: 8 row-reads in flight per quad (deg~17 -> 2 main-loop trips).

__device__ __forceinline__ void gather_edges(
    float* a, const ushort* __restrict__ zin, const uint2* __restrict__ edge,
    int e0, int e1, int lr){
  int e = e0;
  for (; e + 7 < e1; e += 8){
    uint2 er0 = edge[e],   er1 = edge[e+1], er2 = edge[e+2], er3 = edge[e+3];
    uint2 er4 = edge[e+4], er5 = edge[e+5], er6 = edge[e+6], er7 = edge[e+7];
    uint4 v0 = *(const uint4*)(zin + (size_t)er0.x*H + lr*8);
    uint4 v1 = *(const uint4*)(zin + (size_t)er1.x*H + lr*8);
    uint4 v2 = *(const uint4*)(zin + (size_t)er2.x*H + lr*8);
    uint4 v3 = *(const uint4*)(zin + (size_t)er3.x*H + lr*8);
    uint4 v4 = *(const uint4*)(zin + (size_t)er4.x*H + lr*8);
    uint4 v5 = *(const uint4*)(zin + (size_t)er5.x*H + lr*8);
    uint4 v6 = *(const uint4*)(zin + (size_t)er6.x*H + lr*8);
    uint4 v7 = *(const uint4*)(zin + (size_t)er7.x*H + lr*8);
    acc8(a, v0, __uint_as_float(er0.y));
    acc8(a, v1, __uint_as_float(er1.y));
    acc8(a, v2, __uint_as_float(er2.y));
    acc8(a, v3, __uint_as_float(er3.y));
    acc8(a, v4, __uint_as_float(er4.y));
    acc8(a, v5, __uint_as_float(er5.y));
    acc8(a, v6, __uint_as_float(er6.y));
    acc8(a, v7, __uint_as_float(er7.y));
  }
  for (; e + 3 < e1; e += 4){
    uint2 er0 = edge[e], er1 = edge[e+1], er2 = edge[e+2], er3 = edge[e+3];
    uint4 v0 = *(const uint4*)(zin + (size_t)er0.x*H + lr*8);
    uint4 v1 = *(const uint4*)(zin + (size_t)er1.x*H + lr*8);
    uint4 v2 = *(const uint4*)(zin + (size_t)er2.x*H + lr*8);
    uint4 v3 = *(const uint4*)(zin + (size_t)er3.x*H + lr*8);
    acc8(a, v0, __uint_as_float(er0.y));
    acc8(a, v1, __uint_as_float(er1.y));
    acc8(a, v2, __uint_as_float(er2.y));
    acc8(a, v3, __uint_as_float(er3.y));
  }
  for (; e < e1; ++e){
    uint2 er = edge[e];
    uint4 v = *(const uint4*)(zin + (size_t)er.x*H + lr*8);
    acc8(a, v, __uint_as_float(er.y));
  }
}

__device__ __forceinline__ void gather_edges_bn(
    float* a, const ushort* __restrict__ zin, const uint2* __restrict__ edge,
    int e0, int e1, int lr, const float* sc, const float* sh){
  int e = e0;
  for (; e + 7 < e1; e += 8){
    uint2 er0 = edge[e],   er1 = edge[e+1], er2 = edge[e+2], er3 = edge[e+3];
    uint2 er4 = edge[e+4], er5 = edge[e+5], er6 = edge[e+6], er7 = edge[e+7];
    uint4 v0 = *(const uint4*)(zin + (size_t)er0.x*H + lr*8);
    uint4 v1 = *(const uint4*)(zin + (size_t)er1.x*H + lr*8);
    uint4 v2 = *(const uint4*)(zin + (size_t)er2.x*H + lr*8);
    uint4 v3 = *(const uint4*)(zin + (size_t)er3.x*H + lr*8);
    uint4 v4 = *(const uint4*)(zin + (size_t)er4.x*H + lr*8);
    uint4 v5 = *(const uint4*)(zin + (size_t)er5.x*H + lr*8);
    uint4 v6 = *(const uint4*)(zin + (size_t)er6.x*H + lr*8);
    uint4 v7 = *(const uint4*)(zin + (size_t)er7.x*H + lr*8);
    acc8bn(a, v0, __uint_as_float(er0.y), sc, sh);
    acc8bn(a, v1, __uint_as_float(er1.y), sc, sh);
    acc8bn(a, v2, __uint_as_float(er2.y), sc, sh);
    acc8bn(a, v3, __uint_as_float(er3.y), sc, sh);
    acc8bn(a, v4, __uint_as_float(er4.y), sc, sh);
    acc8bn(a, v5, __uint_as_float(er5.y), sc, sh);
    acc8bn(a, v6, __uint_as_float(er6.y), sc, sh);
    acc8bn(a, v7, __uint_as_float(er7.y), sc, sh);
  }
  for (; e + 3 < e1; e += 4){
    uint2 er0 = edge[e], er1 = edge[e+1], er2 = edge[e+2], er3 = edge[e+3];
    uint4 v0 = *(const uint4*)(zin + (size_t)er0.x*H + lr*8);
    uint4 v1 = *(const uint4*)(zin + (size_t)er1.x*H + lr*8);
    uint4 v2 = *(const uint4*)(zin + (size_t)er2.x*H + lr*8);
    uint4 v3 = *(const uint4*)(zin + (size_t)er3.x*H + lr*8);
    acc8bn(a, v0, __uint_as_float(er0.y), sc, sh);
    acc8bn(a, v1, __uint_as_float(er1.y), sc, sh);
    acc8bn(a, v2, __uint_as_float(er2.y), sc, sh);
    acc8bn(a, v3, __uint_as_float(er3.y), sc, sh);
  }
  for (; e < e1; ++e){
    uint2 er = edge[e];
    uint4 v = *(const uint4*)(zin + (size_t)er.x*H + lr*8);
    acc8bn(a, v, __uint_as_float(er.y), sc, sh);
  }
}

// ---------------- input-layer prop: x0 = agg(xw)+b ; permuted layout --------

__global__ __launch_bounds__(256) void k_prop0(
    const ushort* __restrict__ h, const int* __restrict__ off,
    const uint2* __restrict__ edge, const float* __restrict__ dinv,
    const float* __restrict__ bias, const int* __restrict__ perm,
    ushort* __restrict__ x0, int n){
  int pq = (blockIdx.x*blockDim.x + threadIdx.x) >> 4;   // permuted row
  if (pq >= n) return;
  int gq = perm[pq];                 // original node (off/dinv)
  int lr = threadIdx.x & 15;
  float a[8];
  #pragma unroll
  for (int j = 0; j < 8; ++j) a[j] = 0.f;
  float wc = dinv[gq]; wc *= wc;
  uint4 vs = *(const uint4*)(h + (size_t)pq*H + lr*8);   // self: permuted row
  gather_edges(a, h, edge, off[gq], off[gq+1], lr);
  acc8(a, vs, wc);
  float4 b0 = *(const float4*)(bias + lr*8);
  float4 b1 = *(const float4*)(bias + lr*8 + 4);
  uint4 pk;
  pk.x = (uint)f2bf(a[0]+b0.x) | ((uint)f2bf(a[1]+b0.y) << 16);
  pk.y = (uint)f2bf(a[2]+b0.z) | ((uint)f2bf(a[3]+b0.w) << 16);
  pk.z = (uint)f2bf(a[4]+b1.x) | ((uint)f2bf(a[5]+b1.y) << 16);
  pk.w = (uint)f2bf(a[6]+b1.z) | ((uint)f2bf(a[7]+b1.w) << 16);
  *(uint4*)(x0 + (size_t)pq*H + lr*8) = pk;              // contiguous write
}

// ---------------- fused layer: [BN+ReLU ->] prop -> MFMA GEMM -> z (+stats) --

template<bool BNIN, bool STATS, bool OUTF32, bool SAMEX0>
__global__ __launch_bounds__(256) void k_layer(
    const ushort* __restrict__ zin, const ushort* __restrict__ x0,
    const int* __restrict__ off, const uint2* __restrict__ edge,
    const float* __restrict__ dinv, const ushort* __restrict__ BT,
    const int* __restrict__ perm, const float* __restrict__ scsh,
    void* __restrict__ zout, float* __restrict__ stats, int n)
{
  __shared__ ushort Sm[32*128];   // swizzled s tile: row*128 + ((blk16^(row&15))*8)
  __shared__ int pm[32];
  int t = threadIdx.x;
  int w = t >> 6, l = t & 63;
  int lr = l & 15, q = l >> 4;
  int base = blockIdx.x * 32;
  if (t < 32) pm[t] = (base + t < n) ? perm[base + t] : -1;

  float sc[8], sh[8];
  if (BNIN){
    #pragma unroll
    for (int j = 0; j < 8; ++j){
      sc[j] = scsh[lr*8 + j];
      sh[j] = scsh[128 + lr*8 + j];
    }
  }
  __syncthreads();

  // ---- prop phase: quad-per-node, 2 nodes per quad ----
  #pragma unroll
  for (int g2 = 0; g2 < 2; ++g2){
    int row  = w*8 + g2*4 + q;
    int node = pm[row];             // original id (off/dinv only)
    int grow = base + row;          // permuted row (addresses)
    float a[8];
    #pragma unroll
    for (int j = 0; j < 8; ++j) a[j] = 0.f;
    uint4 pk = make_uint4(0u,0u,0u,0u);
    if (node >= 0){
      float wc = dinv[node]; wc *= wc;
      uint4 vs = *(const uint4*)(zin + (size_t)grow*H + lr*8);
      if (BNIN){
        gather_edges_bn(a, zin, edge, off[node], off[node+1], lr, sc, sh);
        acc8bn(a, vs, wc, sc, sh);
      } else {
        gather_edges(a, zin, edge, off[node], off[node+1], lr);
        acc8(a, vs, wc);
      }
      uint4 xv = SAMEX0 ? vs : *(const uint4*)(x0 + (size_t)grow*H + lr*8);
      float s0 = 0.9f*a[0] + 0.1f*bf2f((ushort)(xv.x & 0xffff));
      float s1 = 0.9f*a[1] + 0.1f*bf2f((ushort)(xv.x >> 16));
      float s2 = 0.9f*a[2] + 0.1f*bf2f((ushort)(xv.y & 0xffff));
      float s3 = 0.9f*a[3] + 0.1f*bf2f((ushort)(xv.y >> 16));
      float s4 = 0.9f*a[4] + 0.1f*bf2f((ushort)(xv.z & 0xffff));
      float s5 = 0.9f*a[5] + 0.1f*bf2f((ushort)(xv.z >> 16));
      float s6 = 0.9f*a[6] + 0.1f*bf2f((ushort)(xv.w & 0xffff));
      float s7 = 0.9f*a[7] + 0.1f*bf2f((ushort)(xv.w >> 16));
      pk.x = (uint)f2bf(s0) | ((uint)f2bf(s1) << 16);
      pk.y = (uint)f2bf(s2) | ((uint)f2bf(s3) << 16);
      pk.z = (uint)f2bf(s4) | ((uint)f2bf(s5) << 16);
      pk.w = (uint)f2bf(s6) | ((uint)f2bf(s7) << 16);
    }
    *(uint4*)(&Sm[row*128 + ((lr ^ (row & 15))*8)]) = pk;
  }

  // ---- B fragments (W'^T slice for this wave's 32 cols) ----
  short8 bfr[2][4];
  #pragma unroll
  for (int c = 0; c < 2; ++c)
    #pragma unroll
    for (int ks = 0; ks < 4; ++ks)
      bfr[c][ks] = *(const short8*)(BT + (size_t)(w*32 + c*16 + lr)*H + ks*32 + q*8);

  __syncthreads();

  // ---- GEMM phase: 32 rows x 32 cols per wave ----
  f32x4 acc[2][2];
  #pragma unroll
  for (int rt = 0; rt < 2; ++rt){
    acc[rt][0] = (f32x4){0.f,0.f,0.f,0.f};
    acc[rt][1] = (f32x4){0.f,0.f,0.f,0.f};
  }
  #pragma unroll
  for (int rt = 0; rt < 2; ++rt){
    int row = rt*16 + lr;
    #pragma unroll
    for (int ks = 0; ks < 4; ++ks){
      short8 af = *(const short8*)(&Sm[row*128 + (((ks*4 + q) ^ (row & 15))*8)]);
      acc[rt][0] = __builtin_amdgcn_mfma_f32_16x16x32_bf16(af, bfr[0][ks], acc[rt][0], 0,0,0);
      acc[rt][1] = __builtin_amdgcn_mfma_f32_16x16x32_bf16(af, bfr[1][ks], acc[rt][1], 0,0,0);
    }
  }

  // ---- epilogue: bf16 -> contiguous permuted rows; f32 -> original rows ----
  #pragma unroll
  for (int rt = 0; rt < 2; ++rt){
    #pragma unroll
    for (int c = 0; c < 2; ++c){
      #pragma unroll
      for (int j2 = 0; j2 < 4; ++j2){
        int rowl = rt*16 + q*4 + j2;
        float v = acc[rt][c][j2];
        if (OUTF32){
          int nodeo = pm[rowl];
          if (nodeo >= 0)
            ((float*)zout)[(size_t)nodeo*H + w*32 + c*16 + lr] = v;
        } else {
          int growl = base + rowl;
          float other = __shfl(v, l ^ 1);
          if (!(lr & 1) && growl < n){
            uint pk = (uint)f2bf(v) | ((uint)f2bf(other) << 16);
            ((uint*)zout)[(size_t)growl*64 + w*16 + c*8 + (lr >> 1)] = pk;
          }
        }
      }
    }
  }
  if (STATS){
    #pragma unroll
    for (int c = 0; c < 2; ++c){
      float sv = 0.f, sq = 0.f;
      #pragma unroll
      for (int rt = 0; rt < 2; ++rt)
        #pragma unroll
        for (int j2 = 0; j2 < 4; ++j2){
          float v = acc[rt][c][j2];   // invalid rows have s=0 -> acc=0
          sv += v; sq += v*v;
        }
      sv += __shfl(sv, l ^ 16); sv += __shfl(sv, l ^ 32);
      sq += __shfl(sq, l ^ 16); sq += __shfl(sq, l ^ 32);
      if (q == 0){
        float* st = stats + (size_t)(blockIdx.x & (RSTATS-1))*256;
        atomicAdd(&st[w*32 + c*16 + lr], sv);
        atomicAdd(&st[128 + w*32 + c*16 + lr], sq);
      }
    }
  }
}

// ---------------- BN finalize: stats replicas -> scale/shift; re-zero -------

__global__ void k_bnfinal(float* __restrict__ stats, const float* __restrict__ gamma,
                          const float* __restrict__ beta, float* __restrict__ scsh,
                          float inv_n){
  int f = threadIdx.x;   // 128
  float s = 0.f, s2 = 0.f;
  for (int r = 0; r < RSTATS; ++r){
    s  += stats[r*256 + f];
    s2 += stats[r*256 + 128 + f];
    stats[r*256 + f] = 0.f;          // re-zero for next layer
    stats[r*256 + 128 + f] = 0.f;
  }
  float mu  = s * inv_n;
  float var = s2 * inv_n - mu*mu;
  float sc  = rsqrtf(var + EPS_BN) * gamma[f];
  scsh[f]       = sc;
  scsh[128 + f] = beta[f] - mu*sc;
}

// ---------------- MFMA GEMM for input layer: xw = x(perm rows) @ lin0T^T ----

__global__ __launch_bounds__(256) void k_gemm0(
    const float* __restrict__ Af, const ushort* __restrict__ BT,
    const int* __restrict__ perm, ushort* __restrict__ Cb, int n){
  const int K = 256;
  __shared__ ushort As[64*32];
  __shared__ ushort Bs[128*32];
  __shared__ int pmr[64];
  int t = threadIdx.x;
  int br = blockIdx.x * 64;
  int w = t >> 6, l = t & 63;
  int lr = l & 15, lk = l >> 4;
  int swz = (lr >> 1) & 3;
  if (t < 64) pmr[t] = (br + t < n) ? perm[br + t] : -1;
  __syncthreads();

  f32x4 acc[8];
  #pragma unroll
  for (int i = 0; i < 8; ++i) acc[i] = (f32x4){0.f,0.f,0.f,0.f};

  int sar = t >> 2;
  int sab = t & 3;
  int sa_off = sar*32 + ((sab ^ ((sar>>1)&3))*8);

  for (int k0 = 0; k0 < K; k0 += 32){
    int grow = pmr[sar];              // original row of x
    float4 v0 = make_float4(0.f,0.f,0.f,0.f), v1 = v0;
    if (grow >= 0){
      v0 = *(const float4*)(Af + (size_t)grow*K + k0 + sab*8);
      v1 = *(const float4*)(Af + (size_t)grow*K + k0 + sab*8 + 4);
    }
    ushort tmp[8] = {f2bf(v0.x),f2bf(v0.y),f2bf(v0.z),f2bf(v0.w),
                     f2bf(v1.x),f2bf(v1.y),f2bf(v1.z),f2bf(v1.w)};
    *(uint4*)(&As[sa_off]) = *(const uint4*)tmp;
    #pragma unroll
    for (int i = 0; i < 2; ++i){
      int qq = t + i*256;
      int nrow = qq >> 2, bb = qq & 3;
      uint4 v = *(const uint4*)(BT + (size_t)nrow*K + k0 + bb*8);
      *(uint4*)(&Bs[nrow*32 + ((bb ^ ((nrow>>1)&3))*8)]) = v;
    }
    __syncthreads();
    short8 af = *(const short8*)(&As[(w*16+lr)*32 + ((lk ^ swz)*8)]);
    #pragma unroll
    for (int tn = 0; tn < 8; ++tn){
      short8 bfv = *(const short8*)(&Bs[(tn*16+lr)*32 + ((lk ^ swz)*8)]);
      acc[tn] = __builtin_amdgcn_mfma_f32_16x16x32_bf16(af, bfv, acc[tn], 0, 0, 0);
    }
    __syncthreads();
  }
  int orow = br + w*16 + lk*4;        // permuted layout, contiguous
  #pragma unroll
  for (int tn = 0; tn < 8; ++tn){
    #pragma unroll
    for (int j = 0; j < 4; ++j){
      float mine  = acc[tn][j];
      float other = __shfl(mine, l ^ 1);
      if (!(l & 1) && (orow + j) < n){
        uint pk = (uint)f2bf(mine) | ((uint)f2bf(other) << 16);
        ((uint*)Cb)[(size_t)(orow+j)*64 + tn*8 + (lr >> 1)] = pk;
      }
    }
  }
}

// ---------------- launch ----------------

extern "C" void kernel_launch(void* const* d_in, const int* in_sizes, int n_in,
                              void* d_out, int out_size, void* d_ws, size_t ws_size,
                              hipStream_t stream){
  const float* x        = (const float*)d_in[0];
  const int*   ei       = (const int*)  d_in[1];
  const float* lin0_w   = (const float*)d_in[2];
  const float* lin0_b   = (const float*)d_in[3];
  const float* conv_w   = (const float*)d_in[4];
  const float* bn_gamma = (const float*)d_in[5];
  const float* bn_beta  = (const float*)d_in[6];
  float* out = (float*)d_out;

  int N = in_sizes[0] / 256;
  int E = in_sizes[1] / 2;
  const int* row = ei;
  const int* col = ei + E;

  char* ws = (char*)d_ws;
  size_t p = 0;
  auto alloc = [&](size_t bytes)->char*{
    char* r = ws + p; p = (p + bytes + 255) & ~(size_t)255; return r;
  };
  int*    cnt    = (int*)   alloc((size_t)N*4);
  int*    off    = (int*)   alloc((size_t)(N+1)*4);
  int*    cursor = (int*)   alloc((size_t)N*4);
  float*  dinv   = (float*) alloc((size_t)N*4);
  int*    bsum   = (int*)   alloc(512*4);
  int*    dh     = (int*)   alloc(256*4);
  int*    perm   = (int*)   alloc((size_t)N*4);
  int*    iperm  = (int*)   alloc((size_t)N*4);
  uint2*  edge   = (uint2*) alloc((size_t)E*8);
  ushort* zb     = (ushort*)alloc((size_t)N*H*2);
  ushort* sb     = (ushort*)alloc((size_t)N*H*2);   // xw, then ping-pong z
  ushort* x0b    = (ushort*)alloc((size_t)N*H*2);
  ushort* lin0T  = (ushort*)alloc(128*256*2);
  ushort* WpT    = (ushort*)alloc(4*128*128*2);
  float*  stats  = (float*) alloc(RSTATS*256*4);
  float*  scsh   = (float*) alloc(2*128*4);

  float betas[4];
  for (int i = 0; i < 4; ++i) betas[i] = logf(0.5f/(float)(i+1) + 1.0f);
  float inv_n = 1.0f/(float)N;

  // ---- CSR build + degree-sort perm (descending; LDS-aggregated) ----
  hipMemsetAsync(cnt, 0, (size_t)N*4, stream);
  hipMemsetAsync(dh, 0, 256*4, stream);
  k_count<<<(E+255)/256, 256, 0, stream>>>(col, E, cnt);
  int nb1k = (N + 1023)/1024;
  k_dhist<<<nb1k, 1024, 0, stream>>>(cnt, dh, N);
  k_dscan<<<1, 256, 0, stream>>>(dh);
  k_dperm<<<nb1k, 1024, 0, stream>>>(cnt, dh, perm, iperm, N);
  k_scan1<<<nb1k, 1024, 0, stream>>>(cnt, off, bsum, dinv, N);
  k_scan2<<<1, 64, 0, stream>>>(bsum, nb1k);
  k_scan3<<<(N+255)/256, 256, 0, stream>>>(off, cursor, bsum, N, E);
  k_fill <<<(E+255)/256, 256, 0, stream>>>(row, col, E, dinv, iperm, cursor, edge);

  k_prepw<<<(128*256 + 4*128*128 + 255)/256, 256, 0, stream>>>(
      lin0_w, conv_w, lin0T, WpT, betas[0], betas[1], betas[2], betas[3]);

  int gemm_blocks = (N + 63)/64;
  int lay_blocks  = (N + 31)/32;
  int prop_blocks = (N + 15)/16;      // 16 quads (nodes) per 256-thread block

  // ---- input layer: xw = x @ lin0 (permuted rows); x0 = prop(xw)+b ----
  k_gemm0<<<gemm_blocks, 256, 0, stream>>>(x, lin0T, perm, sb, N);
  k_prop0<<<prop_blocks, 256, 0, stream>>>(sb, off, edge, dinv, lin0_b, perm, x0b, N);

  hipMemsetAsync(stats, 0, RSTATS*256*4, stream);   // once; k_bnfinal re-zeroes

  // ---- layer 0: zin=x0b (raw, == x0) -> zout=sb (raw z1), stats ----
  k_layer<false,true,false,true><<<lay_blocks, 256, 0, stream>>>(
      x0b, x0b, off, edge, dinv, WpT + 0*128*128, perm, nullptr, sb, stats, N);
  k_bnfinal<<<1, 128, 0, stream>>>(stats, bn_gamma + 0*H, bn_beta + 0*H, scsh, inv_n);

  // ---- layer 1: zin=sb (raw, BN in gather) -> zout=zb (raw z2), stats ----
  k_layer<true,true,false,false><<<lay_blocks, 256, 0, stream>>>(
      sb, x0b, off, edge, dinv, WpT + 1*128*128, perm, scsh, zb, stats, N);
  k_bnfinal<<<1, 128, 0, stream>>>(stats, bn_gamma + 1*H, bn_beta + 1*H, scsh, inv_n);

  // ---- layer 2: zin=zb (raw, BN in gather) -> zout=sb (raw z3), stats ----
  k_layer<true,true,false,false><<<lay_blocks, 256, 0, stream>>>(
      zb, x0b, off, edge, dinv, WpT + 2*128*128, perm, scsh, sb, stats, N);
  k_bnfinal<<<1, 128, 0, stream>>>(stats, bn_gamma + 2*H, bn_beta + 2*H, scsh, inv_n);

  // ---- layer 3: zin=sb (raw, BN in gather) -> out (f32, original rows) ----
  k_layer<true,false,true,false><<<lay_blocks, 256, 0, stream>>>(
      sb, x0b, off, edge, dinv, WpT + 3*128*128, perm, scsh, out, nullptr, N);
}